// Round 9
// baseline (1005.224 us; speedup 1.0000x reference)
//
#include <hip/hip_runtime.h>
#include <hip/hip_cooperative_groups.h>
#include <hip/hip_bf16.h>
#include <math.h>

namespace cg = cooperative_groups;

typedef __attribute__((ext_vector_type(8))) short bf16x8;
typedef __attribute__((ext_vector_type(8))) short short8;
typedef __attribute__((ext_vector_type(4))) float f32x4;

#define NBLK 512

__device__ __forceinline__ short f2bf(float f) {
    unsigned u = __float_as_uint(f);
    u += 0x7fffu + ((u >> 16) & 1u);
    return (short)(u >> 16);
}
__device__ __forceinline__ float bf2f(short s) {
    return __uint_as_float(((unsigned)(unsigned short)s) << 16);
}

__device__ __forceinline__ float bsum(float v, float* red) {
    int t = threadIdx.x;
    red[t] = v; __syncthreads();
    #pragma unroll
    for (int s = 128; s >= 1; s >>= 1) {
        if (t < s) red[t] += red[t + s];
        __syncthreads();
    }
    float r = red[0]; __syncthreads();
    return r;
}

__device__ __forceinline__ float bmax(float v, float* red) {
    int t = threadIdx.x;
    red[t] = v; __syncthreads();
    #pragma unroll
    for (int s = 128; s >= 1; s >>= 1) {
        if (t < s) red[t] = fmaxf(red[t], red[t + s]);
        __syncthreads();
    }
    float r = red[0]; __syncthreads();
    return r;
}

struct MegaArgs {
    const float* xt; const float* xn;
    const float* pjA[8]; const float* pjB[8]; const float* pjBias[8];
    const float* m1B[4]; const float* m1bias[4];
    const float* m2B[4]; const float* m2bias[4];
    const float* f1w; const float* f1b; const float* f2w; const float* f2b;
    const float* th[2];
    float* out;
    short* qk; short* S; short* a; short* z1; short* Hc;
    float* z2b; float* Cpartf; float* Cpart;
    float* entv; float* cmv; float* rmv; float* wv;
    float* Gpart; float* Pbuf; float* Hbuf;
};

// ---------------- 64x64 MFMA GEMM job (same body as proven gemm_b_k) --------
// EPI: 0 none, 1 +bias, 2 +bias+relu, 3 out = add + elu(v)
// WS: A(m,k) *= wsc[k] (fp32 !TRA path). SUMB: B += add during TRB staging.
template<typename TA, typename TB, typename TC, bool TRA, bool TRB, int EPI,
         bool WS, bool SUMB>
__device__ void gemm_job(short* As, short* Bs,
                         const TA* __restrict__ A, int lda,
                         const TB* __restrict__ B, int ldb,
                         const float* __restrict__ bias,
                         const float* __restrict__ add,
                         TC* __restrict__ C, int ldc,
                         int bm, int bn, int K, float scale,
                         const float* __restrict__ wsc)
{
    const int t = threadIdx.x;
    const int lane = t & 63;
    const int w = t >> 6, wm = w >> 1, wn = w & 1;
    const int l15 = lane & 15, l4 = lane >> 4;

    f32x4 acc[2][2];
    #pragma unroll
    for (int i = 0; i < 2; ++i)
        #pragma unroll
        for (int j = 0; j < 2; ++j)
            #pragma unroll
            for (int r = 0; r < 4; ++r) acc[i][j][r] = 0.f;

    for (int k0 = 0; k0 < K; k0 += 32) {
        if constexpr (!TRA) {
            if constexpr (sizeof(TA) == 4) {
                #pragma unroll
                for (int p = 0; p < 2; ++p) {
                    int row = (t >> 3) + p * 32;
                    int c4 = (t & 7) * 4;
                    float4 v = *reinterpret_cast<const float4*>(
                        A + (size_t)(bm + row) * lda + k0 + c4);
                    if constexpr (WS) {
                        v.x *= wsc[k0 + c4 + 0]; v.y *= wsc[k0 + c4 + 1];
                        v.z *= wsc[k0 + c4 + 2]; v.w *= wsc[k0 + c4 + 3];
                    }
                    short4 s4 = make_short4(f2bf(v.x), f2bf(v.y), f2bf(v.z), f2bf(v.w));
                    *reinterpret_cast<short4*>(&As[row * 40 + c4]) = s4;
                }
            } else {
                int row = t >> 2, c8 = (t & 3) * 8;
                short8 v = *reinterpret_cast<const short8*>(
                    A + (size_t)(bm + row) * lda + k0 + c8);
                *reinterpret_cast<short8*>(&As[row * 40 + c8]) = v;
            }
        } else {
            #pragma unroll
            for (int p = 0; p < 2; ++p) {
                int kk = (t >> 4) + p * 16;
                int m4 = (t & 15) * 4;
                const float4 v = *reinterpret_cast<const float4*>(
                    (const float*)A + (size_t)(k0 + kk) * lda + bm + m4);
                As[(m4 + 0) * 40 + kk] = f2bf(v.x);
                As[(m4 + 1) * 40 + kk] = f2bf(v.y);
                As[(m4 + 2) * 40 + kk] = f2bf(v.z);
                As[(m4 + 3) * 40 + kk] = f2bf(v.w);
            }
        }
        if constexpr (!TRB) {
            if constexpr (sizeof(TB) == 4) {
                #pragma unroll
                for (int p = 0; p < 2; ++p) {
                    int row = (t >> 3) + p * 32;
                    int c4 = (t & 7) * 4;
                    const float4 v = *reinterpret_cast<const float4*>(
                        B + (size_t)(bn + row) * ldb + k0 + c4);
                    short4 s4 = make_short4(f2bf(v.x), f2bf(v.y), f2bf(v.z), f2bf(v.w));
                    *reinterpret_cast<short4*>(&Bs[row * 40 + c4]) = s4;
                }
            } else {
                int row = t >> 2, c8 = (t & 3) * 8;
                short8 v = *reinterpret_cast<const short8*>(
                    B + (size_t)(bn + row) * ldb + k0 + c8);
                *reinterpret_cast<short8*>(&Bs[row * 40 + c8]) = v;
            }
        } else {
            #pragma unroll
            for (int p = 0; p < 2; ++p) {
                int kk = (t >> 4) + p * 16;
                int n4 = (t & 15) * 4;
                float4 v = *reinterpret_cast<const float4*>(
                    (const float*)B + (size_t)(k0 + kk) * ldb + bn + n4);
                if constexpr (SUMB) {
                    const float4 v2 = *reinterpret_cast<const float4*>(
                        add + (size_t)(k0 + kk) * ldb + bn + n4);
                    v.x += v2.x; v.y += v2.y; v.z += v2.z; v.w += v2.w;
                }
                Bs[(n4 + 0) * 40 + kk] = f2bf(v.x);
                Bs[(n4 + 1) * 40 + kk] = f2bf(v.y);
                Bs[(n4 + 2) * 40 + kk] = f2bf(v.z);
                Bs[(n4 + 3) * 40 + kk] = f2bf(v.w);
            }
        }
        __syncthreads();

        const bf16x8* Ap = reinterpret_cast<const bf16x8*>(As);
        const bf16x8* Bp = reinterpret_cast<const bf16x8*>(Bs);
        bf16x8 af[2], bfr[2];
        #pragma unroll
        for (int mi = 0; mi < 2; ++mi)
            af[mi] = Ap[(wm * 32 + mi * 16 + l15) * 5 + l4];
        #pragma unroll
        for (int ni = 0; ni < 2; ++ni)
            bfr[ni] = Bp[(wn * 32 + ni * 16 + l15) * 5 + l4];
        #pragma unroll
        for (int mi = 0; mi < 2; ++mi)
            #pragma unroll
            for (int ni = 0; ni < 2; ++ni)
                acc[mi][ni] = __builtin_amdgcn_mfma_f32_16x16x32_bf16(
                    af[mi], bfr[ni], acc[mi][ni], 0, 0, 0);
        __syncthreads();
    }

    #pragma unroll
    for (int mi = 0; mi < 2; ++mi) {
        #pragma unroll
        for (int ni = 0; ni < 2; ++ni) {
            int col = bn + wn * 32 + ni * 16 + l15;
            #pragma unroll
            for (int r = 0; r < 4; ++r) {
                int row = bm + wm * 32 + mi * 16 + l4 * 4 + r;
                float v = acc[mi][ni][r] * scale;
                if (EPI == 1) v += bias[col];
                if (EPI == 2) v = fmaxf(v + bias[col], 0.f);
                if (EPI == 3) {
                    float e = v > 0.f ? v : (__expf(v) - 1.f);
                    v = add[(size_t)row * ldc + col] + e;
                }
                if constexpr (sizeof(TC) == 4) C[(size_t)row * ldc + col] = v;
                else C[(size_t)row * ldc + col] = f2bf(v);
            }
        }
    }
}

// ---------------- the mega kernel ----------------
__global__ __launch_bounds__(256, 2) void mega_k(MegaArgs g)
{
    cg::grid_group grid = cg::this_grid();
    __shared__ __align__(16) short As[64 * 40];
    __shared__ __align__(16) short Bs[64 * 40];
    __shared__ float red[256];
    const int bid = blockIdx.x;
    const int t = threadIdx.x;

    // ======== S1: projections (8 z x 128 tiles), K=512 -> qk bf16 ========
    for (int job = bid; job < 1024; job += NBLK) {
        int z = job >> 7, tile = job & 127;
        gemm_job<float, float, short, false, false, 1, false, false>(
            As, Bs, g.pjA[z], 512, g.pjB[z], 512, g.pjBias[z], nullptr,
            g.qk + (size_t)z * 524288, 512,
            (tile >> 3) * 64, (tile & 7) * 64, 512, 1.f, nullptr);
    }
    grid.sync();

    // ======== S2: scores (8 z x 256 tiles), K=256 -> S bf16, scale 1/16 ====
    for (int job = bid; job < 2048; job += NBLK) {
        int z = job >> 8, tile = job & 255;
        int tg = z >> 1, h = z & 1;
        gemm_job<short, short, short, false, false, 0, false, false>(
            As, Bs, g.qk + (size_t)tg * 524288 + h * 256, 512,
            g.qk + (size_t)(4 + tg) * 524288 + h * 256, 512, nullptr, nullptr,
            g.S + ((size_t)z << 20), 1024,
            (tile >> 4) * 64, (tile & 15) * 64, 256, 0.0625f, nullptr);
    }
    grid.sync();

    // ======== S3: softmax + head-mean (4096 jobs) -> a bf16 ========
    for (int job = bid; job < 4096; job += NBLK) {
        int tag = job >> 10, row = job & 1023;
        const short* s0 = g.S + ((size_t)(tag * 2 + 0) << 20) + (size_t)row * 1024 + t * 4;
        const short* s1 = g.S + ((size_t)(tag * 2 + 1) << 20) + (size_t)row * 1024 + t * 4;
        short4 r0 = *reinterpret_cast<const short4*>(s0);
        short4 r1 = *reinterpret_cast<const short4*>(s1);
        float v0[4] = {bf2f(r0.x), bf2f(r0.y), bf2f(r0.z), bf2f(r0.w)};
        float v1[4] = {bf2f(r1.x), bf2f(r1.y), bf2f(r1.z), bf2f(r1.w)};
        float m0 = fmaxf(fmaxf(v0[0], v0[1]), fmaxf(v0[2], v0[3]));
        float m1 = fmaxf(fmaxf(v1[0], v1[1]), fmaxf(v1[2], v1[3]));
        m0 = bmax(m0, red);
        m1 = bmax(m1, red);
        float e0[4], e1[4], sum0 = 0.f, sum1 = 0.f;
        #pragma unroll
        for (int j = 0; j < 4; ++j) {
            e0[j] = __expf(v0[j] - m0); sum0 += e0[j];
            e1[j] = __expf(v1[j] - m1); sum1 += e1[j];
        }
        sum0 = bsum(sum0, red);
        sum1 = bsum(sum1, red);
        float i0 = 0.5f / sum0, i1 = 0.5f / sum1;
        short4 o;
        o.x = f2bf(e0[0] * i0 + e1[0] * i1);
        o.y = f2bf(e0[1] * i0 + e1[1] * i1);
        o.z = f2bf(e0[2] * i0 + e1[2] * i1);
        o.w = f2bf(e0[3] * i0 + e1[3] * i1);
        *reinterpret_cast<short4*>(g.a + ((size_t)tag << 20) + (size_t)row * 1024 + t * 4) = o;
    }
    grid.sync();

    // ======== S4: MLP1 (4 z x 64 tiles), K=1024, bias+relu -> z1 bf16 ======
    for (int job = bid; job < 256; job += NBLK) {
        int z = job >> 6, tile = job & 63;
        gemm_job<short, float, short, false, false, 2, false, false>(
            As, Bs, g.a + ((size_t)z << 20), 1024, g.m1B[z], 1024,
            g.m1bias[z], nullptr, g.z1 + (size_t)z * 262144, 256,
            (tile >> 2) * 64, (tile & 3) * 64, 1024, 1.f, nullptr);
    }
    grid.sync();

    // ======== S5: MLP2 (4 z x 64 tiles), K=256, bias -> z2b fp32 ========
    for (int job = bid; job < 256; job += NBLK) {
        int z = job >> 6, tile = job & 63;
        gemm_job<short, float, float, false, false, 1, false, false>(
            As, Bs, g.z1 + (size_t)z * 262144, 256, g.m2B[z], 256,
            g.m2bias[z], nullptr, g.z2b + (size_t)z * 262144, 256,
            (tile >> 2) * 64, (tile & 3) * 64, 256, 1.f, nullptr);
    }
    grid.sync();

    // ======== S6: norm_softmax x4 tags (1024 jobs) -> Hc bf16 ========
    for (int job = bid; job < 1024; job += NBLK) {
        int tag = job >> 8, j = job & 255;
        const float* Z = g.z2b + (size_t)tag * 262144;
        int joff = tag * 256;
        float x[4];
        #pragma unroll
        for (int i = 0; i < 4; ++i) x[i] = Z[(size_t)(t + i * 256) * 256 + j];
        float mean = bsum(x[0] + x[1] + x[2] + x[3], red) * (1.f / 1024.f);
        float ss = 0.f;
        #pragma unroll
        for (int i = 0; i < 4; ++i) { float d = x[i] - mean; ss += d * d; }
        float var = bsum(ss, red) * (1.f / 1023.f);
        float inv = 1.f / (sqrtf(var) + 1e-6f);
        float v[4], mx = -3.4e38f;
        #pragma unroll
        for (int i = 0; i < 4; ++i) { v[i] = (x[i] - mean) * inv; mx = fmaxf(mx, v[i]); }
        mx = bmax(mx, red);
        float e[4], es = 0.f;
        #pragma unroll
        for (int i = 0; i < 4; ++i) { e[i] = __expf(v[i] - mx); es += e[i]; }
        es = bsum(es, red);
        float invs = 1.f / es;
        #pragma unroll
        for (int i = 0; i < 4; ++i)
            g.Hc[(size_t)(t + i * 256) * 1024 + joff + j] = f2bf(e[i] * invs);
    }
    grid.sync();

    // ======== S7: fusion MLP1 split-K (4 z x 64 tiles) -> Cpartf fp32 ======
    for (int job = bid; job < 256; job += NBLK) {
        int z = job >> 6, tile = job & 63;
        gemm_job<short, float, float, false, false, 0, false, false>(
            As, Bs, g.Hc + z * 256, 1024, g.f1w + z * 256, 1024,
            nullptr, nullptr, g.Cpartf + (size_t)z * 262144, 256,
            (tile >> 2) * 64, (tile & 3) * 64, 256, 1.f, nullptr);
    }
    grid.sync();

    // ======== S8: fusion reduce -> z1f bf16 (z1 slot 0) ========
    for (int job = bid; job < 1024; job += NBLK) {
        int i = job * 256 + t;
        float s = g.f1b[i & 255];
        #pragma unroll
        for (int z = 0; z < 4; ++z) s += g.Cpartf[(size_t)z * 262144 + i];
        g.z1[i] = f2bf(fmaxf(s, 0.f));
    }
    grid.sync();

    // ======== S9: fusion MLP2 (64 tiles), K=256, bias -> z2f fp32 ========
    for (int job = bid; job < 64; job += NBLK) {
        gemm_job<short, float, float, false, false, 1, false, false>(
            As, Bs, g.z1, 256, g.f2w, 256, g.f2b, nullptr, g.z2b, 256,
            (job >> 2) * 64, (job & 3) * 64, 256, 1.f, nullptr);
    }
    grid.sync();

    // ======== S10: final norm_softmax (256 jobs) -> Hbuf fp32 + out H ======
    for (int job = bid; job < 256; job += NBLK) {
        int j = job;
        float x[4];
        #pragma unroll
        for (int i = 0; i < 4; ++i) x[i] = g.z2b[(size_t)(t + i * 256) * 256 + j];
        float mean = bsum(x[0] + x[1] + x[2] + x[3], red) * (1.f / 1024.f);
        float ss = 0.f;
        #pragma unroll
        for (int i = 0; i < 4; ++i) { float d = x[i] - mean; ss += d * d; }
        float var = bsum(ss, red) * (1.f / 1023.f);
        float inv = 1.f / (sqrtf(var) + 1e-6f);
        float v[4], mx = -3.4e38f;
        #pragma unroll
        for (int i = 0; i < 4; ++i) { v[i] = (x[i] - mean) * inv; mx = fmaxf(mx, v[i]); }
        mx = bmax(mx, red);
        float e[4], es = 0.f;
        #pragma unroll
        for (int i = 0; i < 4; ++i) { e[i] = __expf(v[i] - mx); es += e[i]; }
        es = bsum(es, red);
        float invs = 1.f / es;
        #pragma unroll
        for (int i = 0; i < 4; ++i) {
            float o = e[i] * invs;
            g.Hbuf[(size_t)(t + i * 256) * 256 + j] = o;
            g.out[1048576 + (size_t)(t + i * 256) * 256 + j] = o;
        }
    }
    grid.sync();

    // ======== S11 (fat): jsd_part (1024 jobs) || G-GEMM (128 jobs) ========
    for (int job = bid; job < 1152; job += NBLK) {
        if (job < 1024) {
            float (*hj)[33] = (float(*)[33])As;
            float (*hk)[33] = (float(*)[33])Bs;
            const int tx = t & 15, ty = t >> 4;
            const int k0 = (job & 7) * 32, j0 = ((job >> 3) & 7) * 32;
            const int slab = job >> 6, nbase = slab * 64;
            float acc[2][2] = {};
            for (int c = 0; c < 8; ++c) {
                int n0 = nbase + c * 8;
                int nl = t >> 5, cc = t & 31;
                hj[nl][cc] = g.Hbuf[(size_t)(n0 + nl) * 256 + j0 + cc];
                hk[nl][cc] = g.Hbuf[(size_t)(n0 + nl) * 256 + k0 + cc];
                __syncthreads();
                #pragma unroll
                for (int nn = 0; nn < 8; ++nn) {
                    float a0 = hj[nn][ty * 2], a1 = hj[nn][ty * 2 + 1];
                    float b0 = hk[nn][tx * 2], b1 = hk[nn][tx * 2 + 1];
                    acc[0][0] += a0 * __logf(0.5f * (a0 + b0));
                    acc[0][1] += a0 * __logf(0.5f * (a0 + b1));
                    acc[1][0] += a1 * __logf(0.5f * (a1 + b0));
                    acc[1][1] += a1 * __logf(0.5f * (a1 + b1));
                }
                __syncthreads();
            }
            float* Cp = g.Cpart + (size_t)slab * 65536;
            #pragma unroll
            for (int i = 0; i < 2; ++i)
                #pragma unroll
                for (int jj = 0; jj < 2; ++jj)
                    Cp[(size_t)(j0 + ty * 2 + i) * 256 + k0 + tx * 2 + jj] = acc[i][jj];
        } else {
            int gg = job - 1024;
            int z = gg >> 5, tile = gg & 31;
            int chain = z >> 1, slab = z & 1;
            const float* xb = chain ? g.xn : g.xt;
            gemm_job<float, float, float, true, true, 0, false, false>(
                As, Bs, g.Hbuf + (size_t)slab * 131072, 256,
                xb + (size_t)slab * 262144, 512, nullptr, nullptr,
                g.Gpart + (size_t)z * 131072, 512,
                (tile >> 3) * 64, (tile & 7) * 64, 512, 1.f, nullptr);
        }
    }
    grid.sync();

    // ======== S12: rc (256 jobs) ========
    for (int job = bid; job < 256; job += NBLK) {
        const int k = job, j = t;
        float cm = 0.f, rm = 0.f;
        #pragma unroll
        for (int s = 0; s < 16; ++s) {
            cm += g.Cpart[(size_t)s * 65536 + (size_t)j * 256 + k];
            rm += g.Cpart[(size_t)s * 65536 + (size_t)k * 256 + j];
        }
        if (j == k) g.entv[k] = cm;
        cm = bsum(cm, red);
        rm = bsum(rm, red);
        if (j == 0) { g.cmv[k] = cm; g.rmv[k] = rm; }
    }
    grid.sync();

    // ======== S13: jmw (block 0 only) ========
    if (bid == 0) {
        const int k = t;
        float e = g.entv[k];
        float esum = bsum(e, red);
        float jm = 0.5f * (esum * (1.f / 256.f) + e - (g.cmv[k] + g.rmv[k]) * (1.f / 256.f));
        float mean = bsum(jm, red) * (1.f / 256.f);
        float d = jm - mean;
        float var = bsum(d * d, red) * (1.f / 255.f);
        float v = d / (sqrtf(var) + 1e-6f);
        float mx = bmax(v, red);
        float ex = __expf(v - mx);
        float s = bsum(ex, red);
        g.wv[k] = ex / s;
    }
    grid.sync();

    // ======== S14: P = (H*w)(G0+G1) (2 c x 128 tiles), K=256 ========
    for (int job = bid; job < 256; job += NBLK) {
        int c = job >> 7, tile = job & 127;
        gemm_job<float, float, float, false, true, 0, true, true>(
            As, Bs, g.Hbuf, 256, g.Gpart + (size_t)(c * 2) * 131072, 512,
            nullptr, g.Gpart + (size_t)(c * 2 + 1) * 131072,
            g.Pbuf + (size_t)c * 524288, 512,
            (tile >> 3) * 64, (tile & 7) * 64, 256, 1.f, g.wv);
    }
    grid.sync();

    // ======== S15: out = x + elu(P theta) (2 c x 128 tiles), K=512 ========
    for (int job = bid; job < 256; job += NBLK) {
        int c = job >> 7, tile = job & 127;
        const float* xb = c ? g.xn : g.xt;
        gemm_job<float, float, float, false, true, 3, false, false>(
            As, Bs, g.Pbuf + (size_t)c * 524288, 512, g.th[c], 512,
            nullptr, xb, g.out + (size_t)c * 524288, 512,
            (tile >> 3) * 64, (tile & 7) * 64, 512, 1.f, nullptr);
    }
}

// ---------------- launch ----------------
extern "C" void kernel_launch(void* const* d_in, const int* in_sizes, int n_in,
                              void* d_out, int out_size, void* d_ws, size_t ws_size,
                              hipStream_t stream) {
    const float* xt = (const float*)d_in[0];
    const float* xn = (const float*)d_in[1];
    float* ws = (float*)d_ws;

    MegaArgs m{};
    m.xt = xt; m.xn = xn;
    m.f1w = (const float*)d_in[34]; m.f1b = (const float*)d_in[35];
    m.f2w = (const float*)d_in[36]; m.f2b = (const float*)d_in[37];
    m.th[0] = (const float*)d_in[38]; m.th[1] = (const float*)d_in[39];
    m.out = (float*)d_out;

    const float* qsrc[4]  = {xt, xn, xt, xn};
    const float* kvsrc[4] = {xt, xn, xn, xt};
    const int    base[4]  = {2, 10, 18, 26};
    for (int tg = 0; tg < 4; ++tg) {
        m.pjA[tg] = qsrc[tg];
        m.pjB[tg] = (const float*)d_in[base[tg] + 0];
        m.pjBias[tg] = (const float*)d_in[base[tg] + 2];
        m.pjA[4 + tg] = kvsrc[tg];
        m.pjB[4 + tg] = (const float*)d_in[base[tg] + 1];
        m.pjBias[4 + tg] = (const float*)d_in[base[tg] + 3];
        m.m1B[tg] = (const float*)d_in[base[tg] + 4];
        m.m1bias[tg] = (const float*)d_in[base[tg] + 5];
        m.m2B[tg] = (const float*)d_in[base[tg] + 6];
        m.m2bias[tg] = (const float*)d_in[base[tg] + 7];
    }

    // workspace layout (floats) — identical aliasing plan to the proven r6 one
    m.qk = (short*)ws;                       // [0..2097152): qk -> a -> Hc
    m.a  = (short*)ws;
    m.Hc = (short*)ws;
    m.S      = (short*)(ws + 2097152);       // [2097152..6291456): S 16MB
    m.Cpartf = ws + 2097152;                 //   (S dead) 4 x 262144
    m.Cpart  = ws + 2097152;                 //   (Cpartf dead) 16 x 65536
    m.entv   = ws + 3145728;
    m.cmv    = m.entv + 256;
    m.rmv    = m.cmv + 256;
    m.wv     = m.rmv + 256;
    m.Gpart  = ws + 3407872;                 // 4 x 131072
    m.z1     = (short*)(ws + 4194304);       // 4 x 262144 halves
    m.z2b    = ws + 4718592;                 // 4 x 262144 fl
    m.Pbuf   = ws + 4194304;                 // 2 x 524288 fl (z1/z2 dead)
    m.Hbuf   = ws + 6291456;                 // 262144 fl (peak 26.2 MB)

    void* params[] = { (void*)&m };
    hipLaunchCooperativeKernel((const void*)mega_k, dim3(NBLK), dim3(256),
                               params, 0, stream);
}

// Round 10
// 218.337 us; speedup vs baseline: 4.6040x; 4.6040x over previous
//
#include <hip/hip_runtime.h>
#include <hip/hip_bf16.h>
#include <math.h>

typedef __attribute__((ext_vector_type(8))) short bf16x8;
typedef __attribute__((ext_vector_type(8))) short short8;
typedef __attribute__((ext_vector_type(4))) float f32x4;

__device__ __forceinline__ short f2bf(float f) {
    unsigned u = __float_as_uint(f);
    u += 0x7fffu + ((u >> 16) & 1u);
    return (short)(u >> 16);
}
__device__ __forceinline__ float bf2f(short s) {
    return __uint_as_float(((unsigned)(unsigned short)s) << 16);
}

// ---------------- block reduction helpers (blockDim.x == 256) ----------------
__device__ __forceinline__ float bsum(float v, float* red) {
    int t = threadIdx.x;
    red[t] = v; __syncthreads();
    #pragma unroll
    for (int s = 128; s >= 1; s >>= 1) {
        if (t < s) red[t] += red[t + s];
        __syncthreads();
    }
    float r = red[0]; __syncthreads();
    return r;
}

__device__ __forceinline__ float bmax(float v, float* red) {
    int t = threadIdx.x;
    red[t] = v; __syncthreads();
    #pragma unroll
    for (int s = 128; s >= 1; s >>= 1) {
        if (t < s) red[t] = fmaxf(red[t], red[t + s]);
        __syncthreads();
    }
    float r = red[0]; __syncthreads();
    return r;
}

struct Batch8 {
    const void* A[8];
    const void* B[8];
    const float* bias[8];
    const float* add[8];
    void* C[8];
};

// ---------------- BIG 128x128 MFMA GEMM (proj / scores) ----------------
template<typename TA, typename TB, int EPI>
__global__ __launch_bounds__(256) void gemm_big_k(Batch8 bp, int lda, int ldb, int ldc,
                                                  int K, float scale)
{
    __shared__ __align__(16) short As[128 * 40];
    __shared__ __align__(16) short Bs[128 * 40];
    const int t = threadIdx.x;
    const int lane = t & 63;
    const int w = t >> 6, wm = w >> 1, wn = w & 1;
    const int bm = blockIdx.y * 128, bn = blockIdx.x * 128;
    const int l15 = lane & 15, l4 = lane >> 4;
    const TA* __restrict__ A = (const TA*)bp.A[blockIdx.z];
    const TB* __restrict__ B = (const TB*)bp.B[blockIdx.z];

    f32x4 acc[4][4];
    #pragma unroll
    for (int i = 0; i < 4; ++i)
        #pragma unroll
        for (int j = 0; j < 4; ++j)
            #pragma unroll
            for (int r = 0; r < 4; ++r) acc[i][j][r] = 0.f;

    for (int k0 = 0; k0 < K; k0 += 32) {
        if constexpr (sizeof(TA) == 4) {
            #pragma unroll
            for (int p = 0; p < 4; ++p) {
                int row = (t >> 3) + p * 32;
                int c4 = (t & 7) * 4;
                const float4 v = *reinterpret_cast<const float4*>(
                    A + (size_t)(bm + row) * lda + k0 + c4);
                short4 s4 = make_short4(f2bf(v.x), f2bf(v.y), f2bf(v.z), f2bf(v.w));
                *reinterpret_cast<short4*>(&As[row * 40 + c4]) = s4;
            }
        } else {
            #pragma unroll
            for (int p = 0; p < 2; ++p) {
                int row = (t >> 2) + p * 64;
                int c8 = (t & 3) * 8;
                short8 v = *reinterpret_cast<const short8*>(
                    A + (size_t)(bm + row) * lda + k0 + c8);
                *reinterpret_cast<short8*>(&As[row * 40 + c8]) = v;
            }
        }
        if constexpr (sizeof(TB) == 4) {
            #pragma unroll
            for (int p = 0; p < 4; ++p) {
                int row = (t >> 3) + p * 32;
                int c4 = (t & 7) * 4;
                const float4 v = *reinterpret_cast<const float4*>(
                    B + (size_t)(bn + row) * ldb + k0 + c4);
                short4 s4 = make_short4(f2bf(v.x), f2bf(v.y), f2bf(v.z), f2bf(v.w));
                *reinterpret_cast<short4*>(&Bs[row * 40 + c4]) = s4;
            }
        } else {
            #pragma unroll
            for (int p = 0; p < 2; ++p) {
                int row = (t >> 2) + p * 64;
                int c8 = (t & 3) * 8;
                short8 v = *reinterpret_cast<const short8*>(
                    B + (size_t)(bn + row) * ldb + k0 + c8);
                *reinterpret_cast<short8*>(&Bs[row * 40 + c8]) = v;
            }
        }
        __syncthreads();

        const bf16x8* Ap = reinterpret_cast<const bf16x8*>(As);
        const bf16x8* Bp = reinterpret_cast<const bf16x8*>(Bs);
        bf16x8 af[4], bfr[4];
        #pragma unroll
        for (int mi = 0; mi < 4; ++mi)
            af[mi] = Ap[(wm * 64 + mi * 16 + l15) * 5 + l4];
        #pragma unroll
        for (int ni = 0; ni < 4; ++ni)
            bfr[ni] = Bp[(wn * 64 + ni * 16 + l15) * 5 + l4];
        #pragma unroll
        for (int mi = 0; mi < 4; ++mi)
            #pragma unroll
            for (int ni = 0; ni < 4; ++ni)
                acc[mi][ni] = __builtin_amdgcn_mfma_f32_16x16x32_bf16(
                    af[mi], bfr[ni], acc[mi][ni], 0, 0, 0);
        __syncthreads();
    }

    const float* bias = bp.bias[blockIdx.z];
    short* __restrict__ C = (short*)bp.C[blockIdx.z];
    #pragma unroll
    for (int mi = 0; mi < 4; ++mi) {
        #pragma unroll
        for (int ni = 0; ni < 4; ++ni) {
            int col = bn + wn * 64 + ni * 16 + l15;
            #pragma unroll
            for (int r = 0; r < 4; ++r) {
                int row = bm + wm * 64 + mi * 16 + l4 * 4 + r;
                float v = acc[mi][ni][r] * scale;
                if (EPI == 1) v += bias[col];
                C[(size_t)row * ldc + col] = f2bf(v);
            }
        }
    }
}

// ---------------- 64x64 batched MFMA GEMM ----------------
// EPI: 0 none, 1 +bias, 2 +bias+relu, 3 out = add + elu(v)
// WS: A(m,k) *= wsc[k] during staging. SUMB: B-operand = B + add (TRB fp32 path).
template<typename TA, typename TB, typename TC, bool TRA, bool TRB, int EPI,
         bool WS = false, bool SUMB = false>
__global__ __launch_bounds__(256) void gemm_b_k(Batch8 bp, int lda, int ldb, int ldc,
                                                int K, float scale,
                                                const float* __restrict__ wsc = nullptr)
{
    __shared__ __align__(16) short As[64 * 40];
    __shared__ __align__(16) short Bs[64 * 40];
    const int t = threadIdx.x;
    const int lane = t & 63;
    const int w = t >> 6, wm = w >> 1, wn = w & 1;
    const int bm = blockIdx.y * 64, bn = blockIdx.x * 64;
    const int l15 = lane & 15, l4 = lane >> 4;
    const TA* __restrict__ A = (const TA*)bp.A[blockIdx.z];
    const TB* __restrict__ B = (const TB*)bp.B[blockIdx.z];

    f32x4 acc[2][2];
    #pragma unroll
    for (int i = 0; i < 2; ++i)
        #pragma unroll
        for (int j = 0; j < 2; ++j)
            #pragma unroll
            for (int r = 0; r < 4; ++r) acc[i][j][r] = 0.f;

    for (int k0 = 0; k0 < K; k0 += 32) {
        if constexpr (!TRA) {
            if constexpr (sizeof(TA) == 4) {
                #pragma unroll
                for (int p = 0; p < 2; ++p) {
                    int row = (t >> 3) + p * 32;
                    int c4 = (t & 7) * 4;
                    float4 v = *reinterpret_cast<const float4*>(
                        A + (size_t)(bm + row) * lda + k0 + c4);
                    if constexpr (WS) {
                        v.x *= wsc[k0 + c4 + 0]; v.y *= wsc[k0 + c4 + 1];
                        v.z *= wsc[k0 + c4 + 2]; v.w *= wsc[k0 + c4 + 3];
                    }
                    short4 s4 = make_short4(f2bf(v.x), f2bf(v.y), f2bf(v.z), f2bf(v.w));
                    *reinterpret_cast<short4*>(&As[row * 40 + c4]) = s4;
                }
            } else {
                int row = t >> 2, c8 = (t & 3) * 8;
                short8 v = *reinterpret_cast<const short8*>(
                    A + (size_t)(bm + row) * lda + k0 + c8);
                *reinterpret_cast<short8*>(&As[row * 40 + c8]) = v;
            }
        } else {
            #pragma unroll
            for (int p = 0; p < 2; ++p) {
                int kk = (t >> 4) + p * 16;
                int m4 = (t & 15) * 4;
                const float4 v = *reinterpret_cast<const float4*>(
                    (const float*)A + (size_t)(k0 + kk) * lda + bm + m4);
                As[(m4 + 0) * 40 + kk] = f2bf(v.x);
                As[(m4 + 1) * 40 + kk] = f2bf(v.y);
                As[(m4 + 2) * 40 + kk] = f2bf(v.z);
                As[(m4 + 3) * 40 + kk] = f2bf(v.w);
            }
        }
        if constexpr (!TRB) {
            if constexpr (sizeof(TB) == 4) {
                #pragma unroll
                for (int p = 0; p < 2; ++p) {
                    int row = (t >> 3) + p * 32;
                    int c4 = (t & 7) * 4;
                    const float4 v = *reinterpret_cast<const float4*>(
                        B + (size_t)(bn + row) * ldb + k0 + c4);
                    short4 s4 = make_short4(f2bf(v.x), f2bf(v.y), f2bf(v.z), f2bf(v.w));
                    *reinterpret_cast<short4*>(&Bs[row * 40 + c4]) = s4;
                }
            } else {
                int row = t >> 2, c8 = (t & 3) * 8;
                short8 v = *reinterpret_cast<const short8*>(
                    B + (size_t)(bn + row) * ldb + k0 + c8);
                *reinterpret_cast<short8*>(&Bs[row * 40 + c8]) = v;
            }
        } else {
            #pragma unroll
            for (int p = 0; p < 2; ++p) {
                int kk = (t >> 4) + p * 16;
                int n4 = (t & 15) * 4;
                float4 v = *reinterpret_cast<const float4*>(
                    (const float*)B + (size_t)(k0 + kk) * ldb + bn + n4);
                if constexpr (SUMB) {
                    const float4 v2 = *reinterpret_cast<const float4*>(
                        (const float*)bp.add[blockIdx.z] + (size_t)(k0 + kk) * ldb + bn + n4);
                    v.x += v2.x; v.y += v2.y; v.z += v2.z; v.w += v2.w;
                }
                Bs[(n4 + 0) * 40 + kk] = f2bf(v.x);
                Bs[(n4 + 1) * 40 + kk] = f2bf(v.y);
                Bs[(n4 + 2) * 40 + kk] = f2bf(v.z);
                Bs[(n4 + 3) * 40 + kk] = f2bf(v.w);
            }
        }
        __syncthreads();

        const bf16x8* Ap = reinterpret_cast<const bf16x8*>(As);
        const bf16x8* Bp = reinterpret_cast<const bf16x8*>(Bs);
        bf16x8 af[2], bfr[2];
        #pragma unroll
        for (int mi = 0; mi < 2; ++mi)
            af[mi] = Ap[(wm * 32 + mi * 16 + l15) * 5 + l4];
        #pragma unroll
        for (int ni = 0; ni < 2; ++ni)
            bfr[ni] = Bp[(wn * 32 + ni * 16 + l15) * 5 + l4];
        #pragma unroll
        for (int mi = 0; mi < 2; ++mi)
            #pragma unroll
            for (int ni = 0; ni < 2; ++ni)
                acc[mi][ni] = __builtin_amdgcn_mfma_f32_16x16x32_bf16(
                    af[mi], bfr[ni], acc[mi][ni], 0, 0, 0);
        __syncthreads();
    }

    const float* bias = bp.bias[blockIdx.z];
    const float* add = bp.add[blockIdx.z];
    TC* __restrict__ C = (TC*)bp.C[blockIdx.z];
    #pragma unroll
    for (int mi = 0; mi < 2; ++mi) {
        #pragma unroll
        for (int ni = 0; ni < 2; ++ni) {
            int col = bn + wn * 32 + ni * 16 + l15;
            #pragma unroll
            for (int r = 0; r < 4; ++r) {
                int row = bm + wm * 32 + mi * 16 + l4 * 4 + r;
                float v = acc[mi][ni][r] * scale;
                if (EPI == 1) v += bias[col];
                if (EPI == 2) v = fmaxf(v + bias[col], 0.f);
                if (EPI == 3) {
                    float e = v > 0.f ? v : (__expf(v) - 1.f);
                    v = add[(size_t)row * ldc + col] + e;
                }
                if constexpr (sizeof(TC) == 4) C[(size_t)row * ldc + col] = v;
                else C[(size_t)row * ldc + col] = f2bf(v);
            }
        }
    }
}

// ---------------- attention softmax + head-mean (bf16 in/out), all 4 tags ----
__global__ __launch_bounds__(256) void softmax_mean_b(const short* __restrict__ S,
                                                      short* __restrict__ a)
{
    __shared__ float red[256];
    const int g = blockIdx.x, t = threadIdx.x;
    const int tag = g >> 10, row = g & 1023;
    const short* s0 = S + ((size_t)(tag * 2 + 0) << 20) + (size_t)row * 1024 + t * 4;
    const short* s1 = S + ((size_t)(tag * 2 + 1) << 20) + (size_t)row * 1024 + t * 4;

    short4 r0 = *reinterpret_cast<const short4*>(s0);
    short4 r1 = *reinterpret_cast<const short4*>(s1);
    float v0[4] = {bf2f(r0.x), bf2f(r0.y), bf2f(r0.z), bf2f(r0.w)};
    float v1[4] = {bf2f(r1.x), bf2f(r1.y), bf2f(r1.z), bf2f(r1.w)};

    float m0 = fmaxf(fmaxf(v0[0], v0[1]), fmaxf(v0[2], v0[3]));
    float m1 = fmaxf(fmaxf(v1[0], v1[1]), fmaxf(v1[2], v1[3]));
    m0 = bmax(m0, red);
    m1 = bmax(m1, red);

    float e0[4], e1[4], sum0 = 0.f, sum1 = 0.f;
    #pragma unroll
    for (int j = 0; j < 4; ++j) {
        e0[j] = __expf(v0[j] - m0); sum0 += e0[j];
        e1[j] = __expf(v1[j] - m1); sum1 += e1[j];
    }
    sum0 = bsum(sum0, red);
    sum1 = bsum(sum1, red);
    float i0 = 0.5f / sum0, i1 = 0.5f / sum1;

    short4 o;
    o.x = f2bf(e0[0] * i0 + e1[0] * i1);
    o.y = f2bf(e0[1] * i0 + e1[1] * i1);
    o.z = f2bf(e0[2] * i0 + e1[2] * i1);
    o.w = f2bf(e0[3] * i0 + e1[3] * i1);
    *reinterpret_cast<short4*>(a + ((size_t)tag << 20) + (size_t)row * 1024 + t * 4) = o;
}

// ---------------- MLP1 split-K reduce: z1[tag] = bf16(relu(p0+p1+b)) --------
struct Ptr4 { const float* p[4]; };
__global__ __launch_bounds__(256) void mlp1_red_k(const float* __restrict__ zpart,
                                                  Ptr4 bias,
                                                  short* __restrict__ z1)
{
    int i = blockIdx.x * 256 + threadIdx.x;          // over 4*262144
    int tag = i >> 18, idx = i & 262143, col = i & 255;
    float s = bias.p[tag][col]
            + zpart[(size_t)(tag * 2 + 0) * 262144 + idx]
            + zpart[(size_t)(tag * 2 + 1) * 262144 + idx];
    z1[i] = f2bf(fmaxf(s, 0.f));
}

// ---------------- column standardize (ddof=1) + column softmax, batched ------
template<typename TOUT>
__global__ __launch_bounds__(256) void norm_softmax_b(const float* __restrict__ Zbase,
                                                      int zstride,
                                                      TOUT* __restrict__ Hout, int ldh,
                                                      int joffmul,
                                                      float* __restrict__ out2)
{
    __shared__ float red[256];
    const int j = blockIdx.x, t = threadIdx.x;
    const float* Z = Zbase + (size_t)blockIdx.y * zstride;
    const int joff = blockIdx.y * joffmul;

    float x[4];
    #pragma unroll
    for (int i = 0; i < 4; ++i) x[i] = Z[(size_t)(t + i * 256) * 256 + j];

    float s = x[0] + x[1] + x[2] + x[3];
    float mean = bsum(s, red) * (1.f / 1024.f);

    float ss = 0.f;
    #pragma unroll
    for (int i = 0; i < 4; ++i) { float d = x[i] - mean; ss += d * d; }
    float var = bsum(ss, red) * (1.f / 1023.f);
    float inv = 1.f / (sqrtf(var) + 1e-6f);

    float v[4];
    float mx = -3.4e38f;
    #pragma unroll
    for (int i = 0; i < 4; ++i) { v[i] = (x[i] - mean) * inv; mx = fmaxf(mx, v[i]); }
    mx = bmax(mx, red);

    float e[4], es = 0.f;
    #pragma unroll
    for (int i = 0; i < 4; ++i) { e[i] = __expf(v[i] - mx); es += e[i]; }
    es = bsum(es, red);
    float invs = 1.f / es;

    #pragma unroll
    for (int i = 0; i < 4; ++i) {
        float o = e[i] * invs;
        if constexpr (sizeof(TOUT) == 4)
            Hout[(size_t)(t + i * 256) * ldh + joff + j] = o;
        else
            Hout[(size_t)(t + i * 256) * ldh + joff + j] = f2bf(o);
        if (out2) out2[(size_t)(t + i * 256) * 256 + joff + j] = o;
    }
}

// ---------------- fusion split-K reduce: z1f = bf16(relu(sum_s + b)) ---------
__global__ __launch_bounds__(256) void freduce_k(const float* __restrict__ Cpartf,
                                                 const float* __restrict__ b,
                                                 short* __restrict__ z1f)
{
    int i = blockIdx.x * 256 + threadIdx.x;
    float s = b[i & 255];
    #pragma unroll
    for (int z = 0; z < 4; ++z) s += Cpartf[(size_t)z * 262144 + i];
    z1f[i] = f2bf(fmaxf(s, 0.f));
}

// ---------------- fused: jsd_part (jobs 0..1023) || G-GEMM (jobs 1024..1151) --
// jsd: Cpart[s][j][k] = sum_{n in slab s(64)} H[n,j]*log(0.5*(H[n,j]+H[n,k]))
// G:   Gpart[z] (z = chain*2+slab) = H[slab]^T @ X_chain[slab]  [256 x 512]
__global__ __launch_bounds__(256) void jsdg_k(const float* __restrict__ H,
                                              float* __restrict__ Cpart,
                                              const float* __restrict__ xt,
                                              const float* __restrict__ xn,
                                              float* __restrict__ Gpart)
{
    __shared__ __align__(16) short As[64 * 40];
    __shared__ __align__(16) short Bs[64 * 40];
    const int t = threadIdx.x;
    const int job = blockIdx.x;

    if (job < 1024) {
        float (*hj)[33] = (float(*)[33])As;
        float (*hk)[33] = (float(*)[33])Bs;
        const int tx = t & 15, ty = t >> 4;
        const int k0 = (job & 7) * 32, j0 = ((job >> 3) & 7) * 32;
        const int slab = job >> 6, nbase = slab * 64;
        float acc[2][2] = {};
        for (int c = 0; c < 8; ++c) {
            int n0 = nbase + c * 8;
            int nl = t >> 5, cc = t & 31;
            hj[nl][cc] = H[(size_t)(n0 + nl) * 256 + j0 + cc];
            hk[nl][cc] = H[(size_t)(n0 + nl) * 256 + k0 + cc];
            __syncthreads();
            #pragma unroll
            for (int nn = 0; nn < 8; ++nn) {
                float a0 = hj[nn][ty * 2], a1 = hj[nn][ty * 2 + 1];
                float b0 = hk[nn][tx * 2], b1 = hk[nn][tx * 2 + 1];
                acc[0][0] += a0 * __logf(0.5f * (a0 + b0));
                acc[0][1] += a0 * __logf(0.5f * (a0 + b1));
                acc[1][0] += a1 * __logf(0.5f * (a1 + b0));
                acc[1][1] += a1 * __logf(0.5f * (a1 + b1));
            }
            __syncthreads();
        }
        float* Cp = Cpart + (size_t)slab * 65536;
        #pragma unroll
        for (int i = 0; i < 2; ++i)
            #pragma unroll
            for (int jj = 0; jj < 2; ++jj)
                Cp[(size_t)(j0 + ty * 2 + i) * 256 + k0 + tx * 2 + jj] = acc[i][jj];
    } else {
        // G-GEMM job (TRA=true, TRB=true, fp32): same body as proven gemm_b_k
        const int gg = job - 1024;
        const int z = gg >> 5, tile = gg & 31;
        const int chain = z >> 1, slab = z & 1;
        const float* A = H + (size_t)slab * 131072;              // K-major, lda=256
        const float* B = (chain ? xn : xt) + (size_t)slab * 262144; // K-major, ldb=512
        float* C = Gpart + (size_t)z * 131072;
        const int bm = (tile >> 3) * 64, bn = (tile & 7) * 64;
        const int lane = t & 63;
        const int w = t >> 6, wm = w >> 1, wn = w & 1;
        const int l15 = lane & 15, l4 = lane >> 4;

        f32x4 acc[2][2];
        #pragma unroll
        for (int i = 0; i < 2; ++i)
            #pragma unroll
            for (int j = 0; j < 2; ++j)
                #pragma unroll
                for (int r = 0; r < 4; ++r) acc[i][j][r] = 0.f;

        for (int k0 = 0; k0 < 512; k0 += 32) {
            #pragma unroll
            for (int p = 0; p < 2; ++p) {
                int kk = (t >> 4) + p * 16;
                int m4 = (t & 15) * 4;
                const float4 v = *reinterpret_cast<const float4*>(
                    A + (size_t)(k0 + kk) * 256 + bm + m4);
                As[(m4 + 0) * 40 + kk] = f2bf(v.x);
                As[(m4 + 1) * 40 + kk] = f2bf(v.y);
                As[(m4 + 2) * 40 + kk] = f2bf(v.z);
                As[(m4 + 3) * 40 + kk] = f2bf(v.w);
            }
            #pragma unroll
            for (int p = 0; p < 2; ++p) {
                int kk = (t >> 4) + p * 16;
                int n4 = (t & 15) * 4;
                const float4 v = *reinterpret_cast<const float4*>(
                    B + (size_t)(k0 + kk) * 512 + bn + n4);
                Bs[(n4 + 0) * 40 + kk] = f2bf(v.x);
                Bs[(n4 + 1) * 40 + kk] = f2bf(v.y);
                Bs[(n4 + 2) * 40 + kk] = f2bf(v.z);
                Bs[(n4 + 3) * 40 + kk] = f2bf(v.w);
            }
            __syncthreads();

            const bf16x8* Ap = reinterpret_cast<const bf16x8*>(As);
            const bf16x8* Bp = reinterpret_cast<const bf16x8*>(Bs);
            bf16x8 af[2], bfr[2];
            #pragma unroll
            for (int mi = 0; mi < 2; ++mi)
                af[mi] = Ap[(wm * 32 + mi * 16 + l15) * 5 + l4];
            #pragma unroll
            for (int ni = 0; ni < 2; ++ni)
                bfr[ni] = Bp[(wn * 32 + ni * 16 + l15) * 5 + l4];
            #pragma unroll
            for (int mi = 0; mi < 2; ++mi)
                #pragma unroll
                for (int ni = 0; ni < 2; ++ni)
                    acc[mi][ni] = __builtin_amdgcn_mfma_f32_16x16x32_bf16(
                        af[mi], bfr[ni], acc[mi][ni], 0, 0, 0);
            __syncthreads();
        }

        #pragma unroll
        for (int mi = 0; mi < 2; ++mi)
            #pragma unroll
            for (int ni = 0; ni < 2; ++ni) {
                int col = bn + wn * 32 + ni * 16 + l15;
                #pragma unroll
                for (int r = 0; r < 4; ++r) {
                    int row = bm + wm * 32 + mi * 16 + l4 * 4 + r;
                    C[(size_t)row * 512 + col] = acc[mi][ni][r];
                }
            }
    }
}

// ---------------- per-k row/col sums over 16 slabs; ent[k] = diag(C) --------
__global__ __launch_bounds__(256) void rc_k(const float* __restrict__ Cpart,
                                            float* __restrict__ cmv,
                                            float* __restrict__ rmv,
                                            float* __restrict__ entv)
{
    __shared__ float red[256];
    const int k = blockIdx.x, j = threadIdx.x;
    float cm = 0.f, rm = 0.f;
    #pragma unroll
    for (int s = 0; s < 16; ++s) {
        cm += Cpart[(size_t)s * 65536 + (size_t)j * 256 + k];
        rm += Cpart[(size_t)s * 65536 + (size_t)k * 256 + j];
    }
    if (j == k) entv[k] = cm;
    cm = bsum(cm, red);
    rm = bsum(rm, red);
    if (j == 0) { cmv[k] = cm; rmv[k] = rm; }
}

// ---------------- jm -> standardize -> softmax -> w ----------------
__global__ __launch_bounds__(256) void jmw_k(const float* __restrict__ cmv,
                                             const float* __restrict__ rmv,
                                             const float* __restrict__ ent,
                                             float* __restrict__ w)
{
    __shared__ float red[256];
    const int k = threadIdx.x;
    float e = ent[k];
    float esum = bsum(e, red);

    float jm = 0.5f * (esum * (1.f / 256.f) + e - (cmv[k] + rmv[k]) * (1.f / 256.f));

    float mean = bsum(jm, red) * (1.f / 256.f);
    float d = jm - mean;
    float var = bsum(d * d, red) * (1.f / 255.f);
    float v = d / (sqrtf(var) + 1e-6f);

    float mx = bmax(v, red);
    float ex = __expf(v - mx);
    float s = bsum(ex, red);
    w[k] = ex / s;
}

// ---------------- launch ----------------
extern "C" void kernel_launch(void* const* d_in, const int* in_sizes, int n_in,
                              void* d_out, int out_size, void* d_ws, size_t ws_size,
                              hipStream_t stream) {
    const float* x_time = (const float*)d_in[0];
    const float* x_news = (const float*)d_in[1];
    const float* f1w = (const float*)d_in[34];
    const float* f1b = (const float*)d_in[35];
    const float* f2w = (const float*)d_in[36];
    const float* f2b = (const float*)d_in[37];
    const float* theta_t = (const float*)d_in[38];
    const float* theta_n = (const float*)d_in[39];
    float* out = (float*)d_out;

    float* ws = (float*)d_ws;
    // region 0 [0 .. 2,097,152 fl): qk (8x524288 halves) -> a (4x1M halves) -> Hc
    short* s_qk = (short*)ws;
    short* s_a  = (short*)ws;                    // aliases qk (qk dead after scores)
    short* s_Hc = (short*)ws;                    // aliases a  (a dead after MLP1)
    // region 1 [2,097,152 .. 6,291,456 fl): S (8x1M halves) -> everything later
    short* s_S    = (short*)(ws + 2097152);      // 8 x 1048576 halves (16 MB)
    float* zpart  = ws + 2097152;                // 8 x 262144 fl (MLP1 split-K)
    short* s_z1   = (short*)(ws + 4194304);      // 4 x 262144 halves
    float* z2b    = ws + 4718592;                // 4 x 262144 fl
    float* Cpartf = ws + 2097152;                // 4 x 262144 fl (fusion, zpart dead)
    short* z1f    = s_z1;                        // slot 0 (z1 dead after MLP2)
    float* z2f    = z2b;                         // slot 0 (z2b dead after Hc)
    float* Cpart  = ws + 2097152;                // 16 x 65536 fl (jsd)
    float* entv   = ws + 3145728;                // smalls
    float* cmv    = entv + 256;
    float* rmv    = cmv + 256;
    float* wv     = rmv + 256;
    float* Gpart  = ws + 3407872;                // 4 x 131072 fl
    float* Pbuf   = ws + 4194304;                // 2 x 524288 fl (z1/z2b dead)
    // persistent:
    float* Hbuf   = ws + 6291456;                // 262144 fl  (peak 26.2 MB)

    const float* qsrc[4]  = {x_time, x_news, x_time, x_news};
    const float* kvsrc[4] = {x_time, x_news, x_news, x_time};
    const int    base[4]  = {2, 10, 18, 26};

    Batch8 bp{};

    // ======== projections: z=8 {q_t,q_n,q_tn,q_nt,k_t,k_n,k_tn,k_nt} ========
    for (int tg = 0; tg < 4; ++tg) {
        bp.A[tg] = qsrc[tg];      bp.B[tg] = d_in[base[tg] + 0];
        bp.bias[tg] = (const float*)d_in[base[tg] + 2];
        bp.C[tg] = s_qk + (size_t)tg * 524288;
        bp.A[4 + tg] = kvsrc[tg]; bp.B[4 + tg] = d_in[base[tg] + 1];
        bp.bias[4 + tg] = (const float*)d_in[base[tg] + 3];
        bp.C[4 + tg] = s_qk + (size_t)(4 + tg) * 524288;
    }
    gemm_big_k<float, float, 1>
        <<<dim3(4, 8, 8), 256, 0, stream>>>(bp, 512, 512, 512, 512, 1.f);

    // ======== scores: z=8 (tag,head), S bf16, scale 1/16 ========
    for (int i = 0; i < 8; ++i) {
        int tg = i >> 1, h = i & 1;
        bp.A[i] = s_qk + (size_t)tg * 524288 + h * 256;
        bp.B[i] = s_qk + (size_t)(4 + tg) * 524288 + h * 256;
        bp.bias[i] = nullptr;
        bp.C[i] = s_S + ((size_t)i << 20);
    }
    gemm_big_k<short, short, 0>
        <<<dim3(8, 8, 8), 256, 0, stream>>>(bp, 512, 512, 1024, 256, 0.0625f);

    // ======== softmax + head mean -> a (bf16), all tags ========
    softmax_mean_b<<<4096, 256, 0, stream>>>(s_S, s_a);

    // ======== incidence MLP1: split-K z=8 (tag,half) ========
    for (int i = 0; i < 8; ++i) {
        int tg = i >> 1, hf = i & 1;
        bp.A[i] = s_a + ((size_t)tg << 20) + hf * 512;
        bp.B[i] = (const float*)d_in[base[tg] + 4] + hf * 512;
        bp.bias[i] = nullptr;
        bp.C[i] = zpart + (size_t)i * 262144;
    }
    gemm_b_k<short, float, float, false, false, 0>
        <<<dim3(4, 16, 8), 256, 0, stream>>>(bp, 1024, 1024, 256, 512, 1.f);
    Ptr4 b1{{(const float*)d_in[base[0] + 5], (const float*)d_in[base[1] + 5],
             (const float*)d_in[base[2] + 5], (const float*)d_in[base[3] + 5]}};
    mlp1_red_k<<<4096, 256, 0, stream>>>(zpart, b1, s_z1);

    // ======== incidence MLP2 z=4 ========
    for (int tg = 0; tg < 4; ++tg) {
        bp.A[tg] = s_z1 + (size_t)tg * 262144;
        bp.B[tg] = d_in[base[tg] + 6];
        bp.bias[tg] = (const float*)d_in[base[tg] + 7];
        bp.C[tg] = z2b + (size_t)tg * 262144;
    }
    gemm_b_k<short, float, float, false, false, 1>
        <<<dim3(4, 16, 4), 256, 0, stream>>>(bp, 256, 256, 256, 256, 1.f);

    // norm_softmax over 4 tags -> Hcat (bf16)
    norm_softmax_b<short><<<dim3(256, 4), 256, 0, stream>>>(z2b, 262144, s_Hc, 1024, 256, nullptr);

    // ======== fusion MLP (split-K z=4) + norm_softmax -> Hbuf (+out H) ========
    for (int z = 0; z < 4; ++z) {
        bp.A[z] = s_Hc + z * 256;
        bp.B[z] = f1w + z * 256;
        bp.bias[z] = nullptr;
        bp.C[z] = Cpartf + (size_t)z * 262144;
    }
    gemm_b_k<short, float, float, false, false, 0>
        <<<dim3(4, 16, 4), 256, 0, stream>>>(bp, 1024, 1024, 256, 256, 1.f);
    freduce_k<<<1024, 256, 0, stream>>>(Cpartf, f1b, z1f);

    bp.A[0] = z1f; bp.B[0] = f2w; bp.bias[0] = f2b; bp.C[0] = z2f;
    gemm_b_k<short, float, float, false, false, 1>
        <<<dim3(4, 16, 1), 256, 0, stream>>>(bp, 256, 256, 256, 256, 1.f);
    norm_softmax_b<float><<<dim3(256, 1), 256, 0, stream>>>(z2f, 0, Hbuf, 256, 0,
                                                            out + 1048576);

    // ======== JSD || G-GEMM (fused, independent jobs) ========
    jsdg_k<<<1152, 256, 0, stream>>>(Hbuf, Cpart, x_time, x_news, Gpart);
    rc_k<<<256, 256, 0, stream>>>(Cpart, cmv, rmv, entv);
    jmw_k<<<1, 256, 0, stream>>>(cmv, rmv, entv, wv);

    // ======== P = (H*w)(G0+G1) (SUMB), out = x + elu(P theta) ========
    const float* xc[2] = {x_time, x_news};
    const float* th[2] = {theta_t, theta_n};
    for (int c = 0; c < 2; ++c) {
        bp.A[c] = Hbuf;                            // WS applies w[k]
        bp.B[c] = Gpart + (size_t)(c * 2 + 0) * 131072;
        bp.add[c] = Gpart + (size_t)(c * 2 + 1) * 131072;   // SUMB second half
        bp.bias[c] = nullptr;
        bp.C[c] = Pbuf + (size_t)c * 524288;
    }
    gemm_b_k<float, float, float, false, true, 0, true, true>
        <<<dim3(8, 16, 2), 256, 0, stream>>>(bp, 256, 512, 512, 256, 1.f, wv);

    for (int c = 0; c < 2; ++c) {
        bp.A[c] = Pbuf + (size_t)c * 524288;
        bp.B[c] = th[c];
        bp.bias[c] = nullptr;
        bp.add[c] = xc[c];
        bp.C[c] = out + (size_t)c * 524288;
    }
    gemm_b_k<float, float, float, false, true, 3>
        <<<dim3(8, 16, 2), 256, 0, stream>>>(bp, 512, 512, 512, 512, 1.f);
}

// Round 11
// 214.736 us; speedup vs baseline: 4.6812x; 1.0168x over previous
//
#include <hip/hip_runtime.h>
#include <hip/hip_bf16.h>
#include <math.h>

typedef __attribute__((ext_vector_type(8))) short bf16x8;
typedef __attribute__((ext_vector_type(8))) short short8;
typedef __attribute__((ext_vector_type(4))) float f32x4;

__device__ __forceinline__ short f2bf(float f) {
    unsigned u = __float_as_uint(f);
    u += 0x7fffu + ((u >> 16) & 1u);
    return (short)(u >> 16);
}
__device__ __forceinline__ float bf2f(short s) {
    return __uint_as_float(((unsigned)(unsigned short)s) << 16);
}

// ---------------- block reduction helpers (blockDim.x == 256) ----------------
__device__ __forceinline__ float bsum(float v, float* red) {
    int t = threadIdx.x;
    red[t] = v; __syncthreads();
    #pragma unroll
    for (int s = 128; s >= 1; s >>= 1) {
        if (t < s) red[t] += red[t + s];
        __syncthreads();
    }
    float r = red[0]; __syncthreads();
    return r;
}

__device__ __forceinline__ float bmax(float v, float* red) {
    int t = threadIdx.x;
    red[t] = v; __syncthreads();
    #pragma unroll
    for (int s = 128; s >= 1; s >>= 1) {
        if (t < s) red[t] = fmaxf(red[t], red[t + s]);
        __syncthreads();
    }
    float r = red[0]; __syncthreads();
    return r;
}

struct Batch8 {
    const void* A[8];
    const void* B[8];
    const float* bias[8];
    const float* biasA[8];
    const float* add[8];
    void* C[8];
};

// ---------------- BIG 128x128 MFMA GEMM (proj / scores) ----------------
template<typename TA, typename TB, int EPI>
__global__ __launch_bounds__(256) void gemm_big_k(Batch8 bp, int lda, int ldb, int ldc,
                                                  int K, float scale)
{
    __shared__ __align__(16) short As[128 * 40];
    __shared__ __align__(16) short Bs[128 * 40];
    const int t = threadIdx.x;
    const int lane = t & 63;
    const int w = t >> 6, wm = w >> 1, wn = w & 1;
    const int bm = blockIdx.y * 128, bn = blockIdx.x * 128;
    const int l15 = lane & 15, l4 = lane >> 4;
    const TA* __restrict__ A = (const TA*)bp.A[blockIdx.z];
    const TB* __restrict__ B = (const TB*)bp.B[blockIdx.z];

    f32x4 acc[4][4];
    #pragma unroll
    for (int i = 0; i < 4; ++i)
        #pragma unroll
        for (int j = 0; j < 4; ++j)
            #pragma unroll
            for (int r = 0; r < 4; ++r) acc[i][j][r] = 0.f;

    for (int k0 = 0; k0 < K; k0 += 32) {
        if constexpr (sizeof(TA) == 4) {
            #pragma unroll
            for (int p = 0; p < 4; ++p) {
                int row = (t >> 3) + p * 32;
                int c4 = (t & 7) * 4;
                const float4 v = *reinterpret_cast<const float4*>(
                    A + (size_t)(bm + row) * lda + k0 + c4);
                short4 s4 = make_short4(f2bf(v.x), f2bf(v.y), f2bf(v.z), f2bf(v.w));
                *reinterpret_cast<short4*>(&As[row * 40 + c4]) = s4;
            }
        } else {
            #pragma unroll
            for (int p = 0; p < 2; ++p) {
                int row = (t >> 2) + p * 64;
                int c8 = (t & 3) * 8;
                short8 v = *reinterpret_cast<const short8*>(
                    A + (size_t)(bm + row) * lda + k0 + c8);
                *reinterpret_cast<short8*>(&As[row * 40 + c8]) = v;
            }
        }
        if constexpr (sizeof(TB) == 4) {
            #pragma unroll
            for (int p = 0; p < 4; ++p) {
                int row = (t >> 3) + p * 32;
                int c4 = (t & 7) * 4;
                const float4 v = *reinterpret_cast<const float4*>(
                    B + (size_t)(bn + row) * ldb + k0 + c4);
                short4 s4 = make_short4(f2bf(v.x), f2bf(v.y), f2bf(v.z), f2bf(v.w));
                *reinterpret_cast<short4*>(&Bs[row * 40 + c4]) = s4;
            }
        } else {
            #pragma unroll
            for (int p = 0; p < 2; ++p) {
                int row = (t >> 2) + p * 64;
                int c8 = (t & 3) * 8;
                short8 v = *reinterpret_cast<const short8*>(
                    B + (size_t)(bn + row) * ldb + k0 + c8);
                *reinterpret_cast<short8*>(&Bs[row * 40 + c8]) = v;
            }
        }
        __syncthreads();

        const bf16x8* Ap = reinterpret_cast<const bf16x8*>(As);
        const bf16x8* Bp = reinterpret_cast<const bf16x8*>(Bs);
        bf16x8 af[4], bfr[4];
        #pragma unroll
        for (int mi = 0; mi < 4; ++mi)
            af[mi] = Ap[(wm * 64 + mi * 16 + l15) * 5 + l4];
        #pragma unroll
        for (int ni = 0; ni < 4; ++ni)
            bfr[ni] = Bp[(wn * 64 + ni * 16 + l15) * 5 + l4];
        #pragma unroll
        for (int mi = 0; mi < 4; ++mi)
            #pragma unroll
            for (int ni = 0; ni < 4; ++ni)
                acc[mi][ni] = __builtin_amdgcn_mfma_f32_16x16x32_bf16(
                    af[mi], bfr[ni], acc[mi][ni], 0, 0, 0);
        __syncthreads();
    }

    const float* bias = bp.bias[blockIdx.z];
    short* __restrict__ C = (short*)bp.C[blockIdx.z];
    #pragma unroll
    for (int mi = 0; mi < 4; ++mi) {
        #pragma unroll
        for (int ni = 0; ni < 4; ++ni) {
            int col = bn + wn * 64 + ni * 16 + l15;
            #pragma unroll
            for (int r = 0; r < 4; ++r) {
                int row = bm + wm * 64 + mi * 16 + l4 * 4 + r;
                float v = acc[mi][ni][r] * scale;
                if (EPI == 1) v += bias[col];
                C[(size_t)row * ldc + col] = f2bf(v);
            }
        }
    }
}

// ---------------- 64x64 batched MFMA GEMM ----------------
// EPI: 0 none, 1 +bias, 2 +bias+relu, 3 out = add + elu(v)
// WS: A(m,k) *= wsc[k]. SUMB: B += add (TRB fp32). APART(N): A-operand =
//   relu(sum_{j<N} Apart[j] + biasA[k]) with slab stride 262144 fl (fp32).
template<typename TA, typename TB, typename TC, bool TRA, bool TRB, int EPI,
         bool WS = false, bool SUMB = false, int APART = 0>
__global__ __launch_bounds__(256) void gemm_b_k(Batch8 bp, int lda, int ldb, int ldc,
                                                int K, float scale,
                                                const float* __restrict__ wsc = nullptr)
{
    __shared__ __align__(16) short As[64 * 40];
    __shared__ __align__(16) short Bs[64 * 40];
    const int t = threadIdx.x;
    const int lane = t & 63;
    const int w = t >> 6, wm = w >> 1, wn = w & 1;
    const int bm = blockIdx.y * 64, bn = blockIdx.x * 64;
    const int l15 = lane & 15, l4 = lane >> 4;
    const TA* __restrict__ A = (const TA*)bp.A[blockIdx.z];
    const TB* __restrict__ B = (const TB*)bp.B[blockIdx.z];

    f32x4 acc[2][2];
    #pragma unroll
    for (int i = 0; i < 2; ++i)
        #pragma unroll
        for (int j = 0; j < 2; ++j)
            #pragma unroll
            for (int r = 0; r < 4; ++r) acc[i][j][r] = 0.f;

    for (int k0 = 0; k0 < K; k0 += 32) {
        if constexpr (APART > 0) {
            const float* ba = bp.biasA[blockIdx.z];
            #pragma unroll
            for (int p = 0; p < 2; ++p) {
                int row = (t >> 3) + p * 32;
                int c4 = (t & 7) * 4;
                const float* basep = (const float*)A + (size_t)(bm + row) * lda + k0 + c4;
                float4 v = *reinterpret_cast<const float4*>(basep);
                #pragma unroll
                for (int j = 1; j < APART; ++j) {
                    const float4 v2 = *reinterpret_cast<const float4*>(basep + (size_t)j * 262144);
                    v.x += v2.x; v.y += v2.y; v.z += v2.z; v.w += v2.w;
                }
                v.x = fmaxf(v.x + ba[k0 + c4 + 0], 0.f);
                v.y = fmaxf(v.y + ba[k0 + c4 + 1], 0.f);
                v.z = fmaxf(v.z + ba[k0 + c4 + 2], 0.f);
                v.w = fmaxf(v.w + ba[k0 + c4 + 3], 0.f);
                short4 s4 = make_short4(f2bf(v.x), f2bf(v.y), f2bf(v.z), f2bf(v.w));
                *reinterpret_cast<short4*>(&As[row * 40 + c4]) = s4;
            }
        } else if constexpr (!TRA) {
            if constexpr (sizeof(TA) == 4) {
                #pragma unroll
                for (int p = 0; p < 2; ++p) {
                    int row = (t >> 3) + p * 32;
                    int c4 = (t & 7) * 4;
                    float4 v = *reinterpret_cast<const float4*>(
                        A + (size_t)(bm + row) * lda + k0 + c4);
                    if constexpr (WS) {
                        v.x *= wsc[k0 + c4 + 0]; v.y *= wsc[k0 + c4 + 1];
                        v.z *= wsc[k0 + c4 + 2]; v.w *= wsc[k0 + c4 + 3];
                    }
                    short4 s4 = make_short4(f2bf(v.x), f2bf(v.y), f2bf(v.z), f2bf(v.w));
                    *reinterpret_cast<short4*>(&As[row * 40 + c4]) = s4;
                }
            } else {
                int row = t >> 2, c8 = (t & 3) * 8;
                short8 v = *reinterpret_cast<const short8*>(
                    A + (size_t)(bm + row) * lda + k0 + c8);
                *reinterpret_cast<short8*>(&As[row * 40 + c8]) = v;
            }
        } else {
            #pragma unroll
            for (int p = 0; p < 2; ++p) {
                int kk = (t >> 4) + p * 16;
                int m4 = (t & 15) * 4;
                const float4 v = *reinterpret_cast<const float4*>(
                    (const float*)A + (size_t)(k0 + kk) * lda + bm + m4);
                As[(m4 + 0) * 40 + kk] = f2bf(v.x);
                As[(m4 + 1) * 40 + kk] = f2bf(v.y);
                As[(m4 + 2) * 40 + kk] = f2bf(v.z);
                As[(m4 + 3) * 40 + kk] = f2bf(v.w);
            }
        }
        if constexpr (!TRB) {
            if constexpr (sizeof(TB) == 4) {
                #pragma unroll
                for (int p = 0; p < 2; ++p) {
                    int row = (t >> 3) + p * 32;
                    int c4 = (t & 7) * 4;
                    const float4 v = *reinterpret_cast<const float4*>(
                        B + (size_t)(bn + row) * ldb + k0 + c4);
                    short4 s4 = make_short4(f2bf(v.x), f2bf(v.y), f2bf(v.z), f2bf(v.w));
                    *reinterpret_cast<short4*>(&Bs[row * 40 + c4]) = s4;
                }
            } else {
                int row = t >> 2, c8 = (t & 3) * 8;
                short8 v = *reinterpret_cast<const short8*>(
                    B + (size_t)(bn + row) * ldb + k0 + c8);
                *reinterpret_cast<short8*>(&Bs[row * 40 + c8]) = v;
            }
        } else {
            #pragma unroll
            for (int p = 0; p < 2; ++p) {
                int kk = (t >> 4) + p * 16;
                int n4 = (t & 15) * 4;
                float4 v = *reinterpret_cast<const float4*>(
                    (const float*)B + (size_t)(k0 + kk) * ldb + bn + n4);
                if constexpr (SUMB) {
                    const float4 v2 = *reinterpret_cast<const float4*>(
                        (const float*)bp.add[blockIdx.z] + (size_t)(k0 + kk) * ldb + bn + n4);
                    v.x += v2.x; v.y += v2.y; v.z += v2.z; v.w += v2.w;
                }
                Bs[(n4 + 0) * 40 + kk] = f2bf(v.x);
                Bs[(n4 + 1) * 40 + kk] = f2bf(v.y);
                Bs[(n4 + 2) * 40 + kk] = f2bf(v.z);
                Bs[(n4 + 3) * 40 + kk] = f2bf(v.w);
            }
        }
        __syncthreads();

        const bf16x8* Ap = reinterpret_cast<const bf16x8*>(As);
        const bf16x8* Bp = reinterpret_cast<const bf16x8*>(Bs);
        bf16x8 af[2], bfr[2];
        #pragma unroll
        for (int mi = 0; mi < 2; ++mi)
            af[mi] = Ap[(wm * 32 + mi * 16 + l15) * 5 + l4];
        #pragma unroll
        for (int ni = 0; ni < 2; ++ni)
            bfr[ni] = Bp[(wn * 32 + ni * 16 + l15) * 5 + l4];
        #pragma unroll
        for (int mi = 0; mi < 2; ++mi)
            #pragma unroll
            for (int ni = 0; ni < 2; ++ni)
                acc[mi][ni] = __builtin_amdgcn_mfma_f32_16x16x32_bf16(
                    af[mi], bfr[ni], acc[mi][ni], 0, 0, 0);
        __syncthreads();
    }

    const float* bias = bp.bias[blockIdx.z];
    const float* add = bp.add[blockIdx.z];
    TC* __restrict__ C = (TC*)bp.C[blockIdx.z];
    #pragma unroll
    for (int mi = 0; mi < 2; ++mi) {
        #pragma unroll
        for (int ni = 0; ni < 2; ++ni) {
            int col = bn + wn * 32 + ni * 16 + l15;
            #pragma unroll
            for (int r = 0; r < 4; ++r) {
                int row = bm + wm * 32 + mi * 16 + l4 * 4 + r;
                float v = acc[mi][ni][r] * scale;
                if (EPI == 1) v += bias[col];
                if (EPI == 2) v = fmaxf(v + bias[col], 0.f);
                if (EPI == 3) {
                    float e = v > 0.f ? v : (__expf(v) - 1.f);
                    v = add[(size_t)row * ldc + col] + e;
                }
                if constexpr (sizeof(TC) == 4) C[(size_t)row * ldc + col] = v;
                else C[(size_t)row * ldc + col] = f2bf(v);
            }
        }
    }
}

// ---------------- P-GEMM with inline jmw: w from (cmv,rmv,entv), then --------
// P[c] = (H * w) @ (Gpart[2c] + Gpart[2c+1])^T   [1024 x 512], K=256
__global__ __launch_bounds__(256) void pgemm_k(const float* __restrict__ H,
                                               const float* __restrict__ Gpart,
                                               const float* __restrict__ cmv,
                                               const float* __restrict__ rmv,
                                               const float* __restrict__ entv,
                                               float* __restrict__ Pbuf)
{
    __shared__ __align__(16) short As[64 * 40];
    __shared__ __align__(16) short Bs[64 * 40];
    __shared__ float red[256];
    __shared__ float swv[256];
    const int t = threadIdx.x;

    // ---- jmw preamble (redundant per block, deterministic) ----
    {
        const int k = t;
        float e = entv[k];
        float esum = bsum(e, red);
        float jm = 0.5f * (esum * (1.f / 256.f) + e - (cmv[k] + rmv[k]) * (1.f / 256.f));
        float mean = bsum(jm, red) * (1.f / 256.f);
        float d = jm - mean;
        float var = bsum(d * d, red) * (1.f / 255.f);
        float v = d / (sqrtf(var) + 1e-6f);
        float mx = bmax(v, red);
        float ex = __expf(v - mx);
        float s = bsum(ex, red);
        swv[k] = ex / s;
        __syncthreads();
    }

    const int c = blockIdx.z;
    const int bm = blockIdx.y * 64, bn = blockIdx.x * 64;
    const int lane = t & 63;
    const int w = t >> 6, wm = w >> 1, wn = w & 1;
    const int l15 = lane & 15, l4 = lane >> 4;
    const float* __restrict__ B0 = Gpart + (size_t)(c * 2 + 0) * 131072;
    const float* __restrict__ B1 = Gpart + (size_t)(c * 2 + 1) * 131072;
    float* __restrict__ C = Pbuf + (size_t)c * 524288;

    f32x4 acc[2][2];
    #pragma unroll
    for (int i = 0; i < 2; ++i)
        #pragma unroll
        for (int j = 0; j < 2; ++j)
            #pragma unroll
            for (int r = 0; r < 4; ++r) acc[i][j][r] = 0.f;

    for (int k0 = 0; k0 < 256; k0 += 32) {
        #pragma unroll
        for (int p = 0; p < 2; ++p) {
            int row = (t >> 3) + p * 32;
            int c4 = (t & 7) * 4;
            float4 v = *reinterpret_cast<const float4*>(
                H + (size_t)(bm + row) * 256 + k0 + c4);
            v.x *= swv[k0 + c4 + 0]; v.y *= swv[k0 + c4 + 1];
            v.z *= swv[k0 + c4 + 2]; v.w *= swv[k0 + c4 + 3];
            short4 s4 = make_short4(f2bf(v.x), f2bf(v.y), f2bf(v.z), f2bf(v.w));
            *reinterpret_cast<short4*>(&As[row * 40 + c4]) = s4;
        }
        #pragma unroll
        for (int p = 0; p < 2; ++p) {
            int kk = (t >> 4) + p * 16;
            int n4 = (t & 15) * 4;
            float4 v = *reinterpret_cast<const float4*>(
                B0 + (size_t)(k0 + kk) * 512 + bn + n4);
            const float4 v2 = *reinterpret_cast<const float4*>(
                B1 + (size_t)(k0 + kk) * 512 + bn + n4);
            v.x += v2.x; v.y += v2.y; v.z += v2.z; v.w += v2.w;
            Bs[(n4 + 0) * 40 + kk] = f2bf(v.x);
            Bs[(n4 + 1) * 40 + kk] = f2bf(v.y);
            Bs[(n4 + 2) * 40 + kk] = f2bf(v.z);
            Bs[(n4 + 3) * 40 + kk] = f2bf(v.w);
        }
        __syncthreads();

        const bf16x8* Ap = reinterpret_cast<const bf16x8*>(As);
        const bf16x8* Bp = reinterpret_cast<const bf16x8*>(Bs);
        bf16x8 af[2], bfr[2];
        #pragma unroll
        for (int mi = 0; mi < 2; ++mi)
            af[mi] = Ap[(wm * 32 + mi * 16 + l15) * 5 + l4];
        #pragma unroll
        for (int ni = 0; ni < 2; ++ni)
            bfr[ni] = Bp[(wn * 32 + ni * 16 + l15) * 5 + l4];
        #pragma unroll
        for (int mi = 0; mi < 2; ++mi)
            #pragma unroll
            for (int ni = 0; ni < 2; ++ni)
                acc[mi][ni] = __builtin_amdgcn_mfma_f32_16x16x32_bf16(
                    af[mi], bfr[ni], acc[mi][ni], 0, 0, 0);
        __syncthreads();
    }

    #pragma unroll
    for (int mi = 0; mi < 2; ++mi)
        #pragma unroll
        for (int ni = 0; ni < 2; ++ni) {
            int col = bn + wn * 32 + ni * 16 + l15;
            #pragma unroll
            for (int r = 0; r < 4; ++r) {
                int row = bm + wm * 32 + mi * 16 + l4 * 4 + r;
                C[(size_t)row * 512 + col] = acc[mi][ni][r];
            }
        }
}

// ---------------- attention softmax + head-mean (bf16 in/out), all 4 tags ----
__global__ __launch_bounds__(256) void softmax_mean_b(const short* __restrict__ S,
                                                      short* __restrict__ a)
{
    __shared__ float red[256];
    const int g = blockIdx.x, t = threadIdx.x;
    const int tag = g >> 10, row = g & 1023;
    const short* s0 = S + ((size_t)(tag * 2 + 0) << 20) + (size_t)row * 1024 + t * 4;
    const short* s1 = S + ((size_t)(tag * 2 + 1) << 20) + (size_t)row * 1024 + t * 4;

    short4 r0 = *reinterpret_cast<const short4*>(s0);
    short4 r1 = *reinterpret_cast<const short4*>(s1);
    float v0[4] = {bf2f(r0.x), bf2f(r0.y), bf2f(r0.z), bf2f(r0.w)};
    float v1[4] = {bf2f(r1.x), bf2f(r1.y), bf2f(r1.z), bf2f(r1.w)};

    float m0 = fmaxf(fmaxf(v0[0], v0[1]), fmaxf(v0[2], v0[3]));
    float m1 = fmaxf(fmaxf(v1[0], v1[1]), fmaxf(v1[2], v1[3]));
    m0 = bmax(m0, red);
    m1 = bmax(m1, red);

    float e0[4], e1[4], sum0 = 0.f, sum1 = 0.f;
    #pragma unroll
    for (int j = 0; j < 4; ++j) {
        e0[j] = __expf(v0[j] - m0); sum0 += e0[j];
        e1[j] = __expf(v1[j] - m1); sum1 += e1[j];
    }
    sum0 = bsum(sum0, red);
    sum1 = bsum(sum1, red);
    float i0 = 0.5f / sum0, i1 = 0.5f / sum1;

    short4 o;
    o.x = f2bf(e0[0] * i0 + e1[0] * i1);
    o.y = f2bf(e0[1] * i0 + e1[1] * i1);
    o.z = f2bf(e0[2] * i0 + e1[2] * i1);
    o.w = f2bf(e0[3] * i0 + e1[3] * i1);
    *reinterpret_cast<short4*>(a + ((size_t)tag << 20) + (size_t)row * 1024 + t * 4) = o;
}

// ---------------- column standardize (ddof=1) + column softmax, batched ------
template<typename TOUT>
__global__ __launch_bounds__(256) void norm_softmax_b(const float* __restrict__ Zbase,
                                                      int zstride,
                                                      TOUT* __restrict__ Hout, int ldh,
                                                      int joffmul,
                                                      float* __restrict__ out2)
{
    __shared__ float red[256];
    const int j = blockIdx.x, t = threadIdx.x;
    const float* Z = Zbase + (size_t)blockIdx.y * zstride;
    const int joff = blockIdx.y * joffmul;

    float x[4];
    #pragma unroll
    for (int i = 0; i < 4; ++i) x[i] = Z[(size_t)(t + i * 256) * 256 + j];

    float s = x[0] + x[1] + x[2] + x[3];
    float mean = bsum(s, red) * (1.f / 1024.f);

    float ss = 0.f;
    #pragma unroll
    for (int i = 0; i < 4; ++i) { float d = x[i] - mean; ss += d * d; }
    float var = bsum(ss, red) * (1.f / 1023.f);
    float inv = 1.f / (sqrtf(var) + 1e-6f);

    float v[4];
    float mx = -3.4e38f;
    #pragma unroll
    for (int i = 0; i < 4; ++i) { v[i] = (x[i] - mean) * inv; mx = fmaxf(mx, v[i]); }
    mx = bmax(mx, red);

    float e[4], es = 0.f;
    #pragma unroll
    for (int i = 0; i < 4; ++i) { e[i] = __expf(v[i] - mx); es += e[i]; }
    es = bsum(es, red);
    float invs = 1.f / es;

    #pragma unroll
    for (int i = 0; i < 4; ++i) {
        float o = e[i] * invs;
        if constexpr (sizeof(TOUT) == 4)
            Hout[(size_t)(t + i * 256) * ldh + joff + j] = o;
        else
            Hout[(size_t)(t + i * 256) * ldh + joff + j] = f2bf(o);
        if (out2) out2[(size_t)(t + i * 256) * 256 + joff + j] = o;
    }
}

// ---------------- fused: jsd_part (jobs 0..1023) || G-GEMM (jobs 1024..1151) --
__global__ __launch_bounds__(256) void jsdg_k(const float* __restrict__ H,
                                              float* __restrict__ Cpart,
                                              const float* __restrict__ xt,
                                              const float* __restrict__ xn,
                                              float* __restrict__ Gpart)
{
    __shared__ __align__(16) short As[64 * 40];
    __shared__ __align__(16) short Bs[64 * 40];
    const int t = threadIdx.x;
    const int job = blockIdx.x;

    if (job < 1024) {
        float (*hj)[33] = (float(*)[33])As;
        float (*hk)[33] = (float(*)[33])Bs;
        const int tx = t & 15, ty = t >> 4;
        const int k0 = (job & 7) * 32, j0 = ((job >> 3) & 7) * 32;
        const int slab = job >> 6, nbase = slab * 64;
        float acc[2][2] = {};
        for (int c = 0; c < 8; ++c) {
            int n0 = nbase + c * 8;
            int nl = t >> 5, cc = t & 31;
            hj[nl][cc] = H[(size_t)(n0 + nl) * 256 + j0 + cc];
            hk[nl][cc] = H[(size_t)(n0 + nl) * 256 + k0 + cc];
            __syncthreads();
            #pragma unroll
            for (int nn = 0; nn < 8; ++nn) {
                float a0 = hj[nn][ty * 2], a1 = hj[nn][ty * 2 + 1];
                float b0 = hk[nn][tx * 2], b1 = hk[nn][tx * 2 + 1];
                acc[0][0] += a0 * __logf(0.5f * (a0 + b0));
                acc[0][1] += a0 * __logf(0.5f * (a0 + b1));
                acc[1][0] += a1 * __logf(0.5f * (a1 + b0));
                acc[1][1] += a1 * __logf(0.5f * (a1 + b1));
            }
            __syncthreads();
        }
        float* Cp = Cpart + (size_t)slab * 65536;
        #pragma unroll
        for (int i = 0; i < 2; ++i)
            #pragma unroll
            for (int jj = 0; jj < 2; ++jj)
                Cp[(size_t)(j0 + ty * 2 + i) * 256 + k0 + tx * 2 + jj] = acc[i][jj];
    } else {
        const int gg = job - 1024;
        const int z = gg >> 5, tile = gg & 31;
        const int chain = z >> 1, slab = z & 1;
        const float* A = H + (size_t)slab * 131072;
        const float* B = (chain ? xn : xt) + (size_t)slab * 262144;
        float* C = Gpart + (size_t)z * 131072;
        const int bm = (tile >> 3) * 64, bn = (tile & 7) * 64;
        const int lane = t & 63;
        const int w = t >> 6, wm = w >> 1, wn = w & 1;
        const int l15 = lane & 15, l4 = lane >> 4;

        f32x4 acc[2][2];
        #pragma unroll
        for (int i = 0; i < 2; ++i)
            #pragma unroll
            for (int j = 0; j < 2; ++j)
                #pragma unroll
                for (int r = 0; r < 4; ++r) acc[i][j][r] = 0.f;

        for (int k0 = 0; k0 < 512; k0 += 32) {
            #pragma unroll
            for (int p = 0; p < 2; ++p) {
                int kk = (t >> 4) + p * 16;
                int m4 = (t & 15) * 4;
                const float4 v = *reinterpret_cast<const float4*>(
                    A + (size_t)(k0 + kk) * 256 + bm + m4);
                As[(m4 + 0) * 40 + kk] = f2bf(v.x);
                As[(m4 + 1) * 40 + kk] = f2bf(v.y);
                As[(m4 + 2) * 40 + kk] = f2bf(v.z);
                As[(m4 + 3) * 40 + kk] = f2bf(v.w);
            }
            #pragma unroll
            for (int p = 0; p < 2; ++p) {
                int kk = (t >> 4) + p * 16;
                int n4 = (t & 15) * 4;
                const float4 v = *reinterpret_cast<const float4*>(
                    B + (size_t)(k0 + kk) * 512 + bn + n4);
                Bs[(n4 + 0) * 40 + kk] = f2bf(v.x);
                Bs[(n4 + 1) * 40 + kk] = f2bf(v.y);
                Bs[(n4 + 2) * 40 + kk] = f2bf(v.z);
                Bs[(n4 + 3) * 40 + kk] = f2bf(v.w);
            }
            __syncthreads();

            const bf16x8* Ap = reinterpret_cast<const bf16x8*>(As);
            const bf16x8* Bp = reinterpret_cast<const bf16x8*>(Bs);
            bf16x8 af[2], bfr[2];
            #pragma unroll
            for (int mi = 0; mi < 2; ++mi)
                af[mi] = Ap[(wm * 32 + mi * 16 + l15) * 5 + l4];
            #pragma unroll
            for (int ni = 0; ni < 2; ++ni)
                bfr[ni] = Bp[(wn * 32 + ni * 16 + l15) * 5 + l4];
            #pragma unroll
            for (int mi = 0; mi < 2; ++mi)
                #pragma unroll
                for (int ni = 0; ni < 2; ++ni)
                    acc[mi][ni] = __builtin_amdgcn_mfma_f32_16x16x32_bf16(
                        af[mi], bfr[ni], acc[mi][ni], 0, 0, 0);
            __syncthreads();
        }

        #pragma unroll
        for (int mi = 0; mi < 2; ++mi)
            #pragma unroll
            for (int ni = 0; ni < 2; ++ni) {
                int col = bn + wn * 32 + ni * 16 + l15;
                #pragma unroll
                for (int r = 0; r < 4; ++r) {
                    int row = bm + wm * 32 + mi * 16 + l4 * 4 + r;
                    C[(size_t)row * 512 + col] = acc[mi][ni][r];
                }
            }
    }
}

// ---------------- per-k row/col sums over 16 slabs; ent[k] = diag(C) --------
__global__ __launch_bounds__(256) void rc_k(const float* __restrict__ Cpart,
                                            float* __restrict__ cmv,
                                            float* __restrict__ rmv,
                                            float* __restrict__ entv)
{
    __shared__ float red[256];
    const int k = blockIdx.x, j = threadIdx.x;
    float cm = 0.f, rm = 0.f;
    #pragma unroll
    for (int s = 0; s < 16; ++s) {
        cm += Cpart[(size_t)s * 65536 + (size_t)j * 256 + k];
        rm += Cpart[(size_t)s * 65536 + (size_t)k * 256 + j];
    }
    if (j == k) entv[k] = cm;
    cm = bsum(cm, red);
    rm = bsum(rm, red);
    if (j == 0) { cmv[k] = cm; rmv[k] = rm; }
}

// ---------------- launch ----------------
extern "C" void kernel_launch(void* const* d_in, const int* in_sizes, int n_in,
                              void* d_out, int out_size, void* d_ws, size_t ws_size,
                              hipStream_t stream) {
    const float* x_time = (const float*)d_in[0];
    const float* x_news = (const float*)d_in[1];
    const float* f1w = (const float*)d_in[34];
    const float* f1b = (const float*)d_in[35];
    const float* f2w = (const float*)d_in[36];
    const float* f2b = (const float*)d_in[37];
    const float* theta_t = (const float*)d_in[38];
    const float* theta_n = (const float*)d_in[39];
    float* out = (float*)d_out;

    float* ws = (float*)d_ws;
    // region 0 [0 .. 2,097,152 fl): qk (8x524288 halves) -> a (4x1M halves) -> Hc
    short* s_qk = (short*)ws;
    short* s_a  = (short*)ws;
    short* s_Hc = (short*)ws;
    // region 1 [2,097,152 .. 6,291,456 fl): S (8x1M halves) -> later scratch
    short* s_S    = (short*)(ws + 2097152);      // 8 x 1048576 halves (16 MB)
    float* zpart  = ws + 2097152;                // 8 x 262144 fl (MLP1 split-K)
    float* z2b    = ws + 4718592;                // 4 x 262144 fl
    float* Cpartf = ws + 2097152;                // 4 x 262144 fl (zpart dead)
    float* z2f    = z2b;                         // slot 0
    float* Cpart  = ws + 2097152;                // 16 x 65536 fl (jsd)
    float* entv   = ws + 3145728;
    float* cmv    = entv + 256;
    float* rmv    = cmv + 256;
    float* Gpart  = ws + 3407872;                // 4 x 131072 fl
    float* Pbuf   = ws + 4194304;                // 2 x 524288 fl
    float* Hbuf   = ws + 6291456;                // 262144 fl (peak 26.2 MB)

    const float* qsrc[4]  = {x_time, x_news, x_time, x_news};
    const float* kvsrc[4] = {x_time, x_news, x_news, x_time};
    const int    base[4]  = {2, 10, 18, 26};

    Batch8 bp{};

    // ======== projections: z=8 {q_t,q_n,q_tn,q_nt,k_t,k_n,k_tn,k_nt} ========
    for (int tg = 0; tg < 4; ++tg) {
        bp.A[tg] = qsrc[tg];      bp.B[tg] = d_in[base[tg] + 0];
        bp.bias[tg] = (const float*)d_in[base[tg] + 2];
        bp.C[tg] = s_qk + (size_t)tg * 524288;
        bp.A[4 + tg] = kvsrc[tg]; bp.B[4 + tg] = d_in[base[tg] + 1];
        bp.bias[4 + tg] = (const float*)d_in[base[tg] + 3];
        bp.C[4 + tg] = s_qk + (size_t)(4 + tg) * 524288;
    }
    gemm_big_k<float, float, 1>
        <<<dim3(4, 8, 8), 256, 0, stream>>>(bp, 512, 512, 512, 512, 1.f);

    // ======== scores: z=8 (tag,head), S bf16, scale 1/16 ========
    for (int i = 0; i < 8; ++i) {
        int tg = i >> 1, h = i & 1;
        bp.A[i] = s_qk + (size_t)tg * 524288 + h * 256;
        bp.B[i] = s_qk + (size_t)(4 + tg) * 524288 + h * 256;
        bp.bias[i] = nullptr;
        bp.C[i] = s_S + ((size_t)i << 20);
    }
    gemm_big_k<short, short, 0>
        <<<dim3(8, 8, 8), 256, 0, stream>>>(bp, 512, 512, 1024, 256, 0.0625f);

    // ======== softmax + head mean -> a (bf16), all tags ========
    softmax_mean_b<<<4096, 256, 0, stream>>>(s_S, s_a);

    // ======== incidence MLP1: split-K z=8 (tag,half) -> zpart fp32 ========
    for (int i = 0; i < 8; ++i) {
        int tg = i >> 1, hf = i & 1;
        bp.A[i] = s_a + ((size_t)tg << 20) + hf * 512;
        bp.B[i] = (const float*)d_in[base[tg] + 4] + hf * 512;
        bp.bias[i] = nullptr;
        bp.C[i] = zpart + (size_t)i * 262144;
    }
    gemm_b_k<short, float, float, false, false, 0>
        <<<dim3(4, 16, 8), 256, 0, stream>>>(bp, 1024, 1024, 256, 512, 1.f);

    // ======== incidence MLP2 z=4 (A = relu(zpart0+zpart1+m1bias), APART=2) ===
    for (int tg = 0; tg < 4; ++tg) {
        bp.A[tg] = zpart + (size_t)tg * 2 * 262144;
        bp.biasA[tg] = (const float*)d_in[base[tg] + 5];
        bp.B[tg] = d_in[base[tg] + 6];
        bp.bias[tg] = (const float*)d_in[base[tg] + 7];
        bp.C[tg] = z2b + (size_t)tg * 262144;
    }
    gemm_b_k<float, float, float, false, false, 1, false, false, 2>
        <<<dim3(4, 16, 4), 256, 0, stream>>>(bp, 256, 256, 256, 256, 1.f);

    // norm_softmax over 4 tags -> Hcat (bf16)
    norm_softmax_b<short><<<dim3(256, 4), 256, 0, stream>>>(z2b, 262144, s_Hc, 1024, 256, nullptr);

    // ======== fusion MLP1 split-K z=4 -> Cpartf fp32 ========
    for (int z = 0; z < 4; ++z) {
        bp.A[z] = s_Hc + z * 256;
        bp.B[z] = f1w + z * 256;
        bp.bias[z] = nullptr;
        bp.C[z] = Cpartf + (size_t)z * 262144;
    }
    gemm_b_k<short, float, float, false, false, 0>
        <<<dim3(4, 16, 4), 256, 0, stream>>>(bp, 1024, 1024, 256, 256, 1.f);

    // ======== fusion MLP2 (A = relu(sum4 Cpartf + f1b), APART=4) ========
    bp.A[0] = Cpartf; bp.biasA[0] = f1b; bp.B[0] = f2w; bp.bias[0] = f2b; bp.C[0] = z2f;
    gemm_b_k<float, float, float, false, false, 1, false, false, 4>
        <<<dim3(4, 16, 1), 256, 0, stream>>>(bp, 256, 256, 256, 256, 1.f);
    norm_softmax_b<float><<<dim3(256, 1), 256, 0, stream>>>(z2f, 0, Hbuf, 256, 0,
                                                            out + 1048576);

    // ======== JSD || G-GEMM (fused) ========
    jsdg_k<<<1152, 256, 0, stream>>>(Hbuf, Cpart, x_time, x_news, Gpart);
    rc_k<<<256, 256, 0, stream>>>(Cpart, cmv, rmv, entv);

    // ======== P = (H*w)(G0+G1) with inline jmw ========
    pgemm_k<<<dim3(8, 16, 2), 256, 0, stream>>>(Hbuf, Gpart, cmv, rmv, entv, Pbuf);

    // ======== out = x + elu(P theta) ========
    const float* xc[2] = {x_time, x_news};
    const float* th[2] = {theta_t, theta_n};
    for (int c = 0; c < 2; ++c) {
        bp.A[c] = Pbuf + (size_t)c * 524288;
        bp.B[c] = th[c];
        bp.bias[c] = nullptr;
        bp.add[c] = xc[c];
        bp.C[c] = out + (size_t)c * 524288;
    }
    gemm_b_k<float, float, float, false, true, 3>
        <<<dim3(8, 16, 2), 256, 0, stream>>>(bp, 512, 512, 512, 512, 1.f);
}

// Round 12
// 191.713 us; speedup vs baseline: 5.2434x; 1.1201x over previous
//
#include <hip/hip_runtime.h>
#include <hip/hip_bf16.h>
#include <math.h>

typedef __attribute__((ext_vector_type(8))) short bf16x8;
typedef __attribute__((ext_vector_type(8))) short short8;
typedef __attribute__((ext_vector_type(4))) float f32x4;

__device__ __forceinline__ short f2bf(float f) {
    unsigned u = __float_as_uint(f);
    u += 0x7fffu + ((u >> 16) & 1u);
    return (short)(u >> 16);
}
__device__ __forceinline__ float bf2f(short s) {
    return __uint_as_float(((unsigned)(unsigned short)s) << 16);
}

// ---------------- block reduction helpers (blockDim.x == 256) ----------------
__device__ __forceinline__ float bsum(float v, float* red) {
    int t = threadIdx.x;
    red[t] = v; __syncthreads();
    #pragma unroll
    for (int s = 128; s >= 1; s >>= 1) {
        if (t < s) red[t] += red[t + s];
        __syncthreads();
    }
    float r = red[0]; __syncthreads();
    return r;
}

__device__ __forceinline__ float bmax(float v, float* red) {
    int t = threadIdx.x;
    red[t] = v; __syncthreads();
    #pragma unroll
    for (int s = 128; s >= 1; s >>= 1) {
        if (t < s) red[t] = fmaxf(red[t], red[t + s]);
        __syncthreads();
    }
    float r = red[0]; __syncthreads();
    return r;
}

struct Batch8 {
    const void* A[8];
    const void* B[8];
    const float* bias[8];
    const float* biasA[8];
    const float* add[8];
    void* C[8];
};

// ---------------- BIG 128x128 MFMA GEMM, double-buffered pipeline ----------
template<typename TA, typename TB, int EPI>
__global__ __launch_bounds__(256) void gemm_big_k(Batch8 bp, int lda, int ldb, int ldc,
                                                  int K, float scale)
{
    __shared__ __align__(16) short AsB[2][128 * 40];
    __shared__ __align__(16) short BsB[2][128 * 40];
    const int t = threadIdx.x;
    const int lane = t & 63;
    const int w = t >> 6, wm = w >> 1, wn = w & 1;
    const int bm = blockIdx.y * 128, bn = blockIdx.x * 128;
    const int l15 = lane & 15, l4 = lane >> 4;
    const TA* __restrict__ A = (const TA*)bp.A[blockIdx.z];
    const TB* __restrict__ B = (const TB*)bp.B[blockIdx.z];

    f32x4 acc[4][4];
    #pragma unroll
    for (int i = 0; i < 4; ++i)
        #pragma unroll
        for (int j = 0; j < 4; ++j)
            #pragma unroll
            for (int r = 0; r < 4; ++r) acc[i][j][r] = 0.f;

    float4 rA[4]; short8 rA16[2];
    float4 rB[4]; short8 rB16[2];

    auto loadA = [&](int k0) {
        if constexpr (sizeof(TA) == 4) {
            #pragma unroll
            for (int p = 0; p < 4; ++p) {
                int row = (t >> 3) + p * 32, c4 = (t & 7) * 4;
                rA[p] = *reinterpret_cast<const float4*>(
                    A + (size_t)(bm + row) * lda + k0 + c4);
            }
        } else {
            #pragma unroll
            for (int p = 0; p < 2; ++p) {
                int row = (t >> 2) + p * 64, c8 = (t & 3) * 8;
                rA16[p] = *reinterpret_cast<const short8*>(
                    A + (size_t)(bm + row) * lda + k0 + c8);
            }
        }
    };
    auto writeA = [&](short* As) {
        if constexpr (sizeof(TA) == 4) {
            #pragma unroll
            for (int p = 0; p < 4; ++p) {
                int row = (t >> 3) + p * 32, c4 = (t & 7) * 4;
                short4 s4 = make_short4(f2bf(rA[p].x), f2bf(rA[p].y),
                                        f2bf(rA[p].z), f2bf(rA[p].w));
                *reinterpret_cast<short4*>(&As[row * 40 + c4]) = s4;
            }
        } else {
            #pragma unroll
            for (int p = 0; p < 2; ++p) {
                int row = (t >> 2) + p * 64, c8 = (t & 3) * 8;
                *reinterpret_cast<short8*>(&As[row * 40 + c8]) = rA16[p];
            }
        }
    };
    auto loadB = [&](int k0) {
        if constexpr (sizeof(TB) == 4) {
            #pragma unroll
            for (int p = 0; p < 4; ++p) {
                int row = (t >> 3) + p * 32, c4 = (t & 7) * 4;
                rB[p] = *reinterpret_cast<const float4*>(
                    B + (size_t)(bn + row) * ldb + k0 + c4);
            }
        } else {
            #pragma unroll
            for (int p = 0; p < 2; ++p) {
                int row = (t >> 2) + p * 64, c8 = (t & 3) * 8;
                rB16[p] = *reinterpret_cast<const short8*>(
                    B + (size_t)(bn + row) * ldb + k0 + c8);
            }
        }
    };
    auto writeB = [&](short* Bs) {
        if constexpr (sizeof(TB) == 4) {
            #pragma unroll
            for (int p = 0; p < 4; ++p) {
                int row = (t >> 3) + p * 32, c4 = (t & 7) * 4;
                short4 s4 = make_short4(f2bf(rB[p].x), f2bf(rB[p].y),
                                        f2bf(rB[p].z), f2bf(rB[p].w));
                *reinterpret_cast<short4*>(&Bs[row * 40 + c4]) = s4;
            }
        } else {
            #pragma unroll
            for (int p = 0; p < 2; ++p) {
                int row = (t >> 2) + p * 64, c8 = (t & 3) * 8;
                *reinterpret_cast<short8*>(&Bs[row * 40 + c8]) = rB16[p];
            }
        }
    };

    const int NS = K >> 5;
    loadA(0); loadB(0);
    writeA(AsB[0]); writeB(BsB[0]);
    loadA(32); loadB(32);
    __syncthreads();

    for (int s = 0; s < NS; ++s) {
        const bf16x8* Ap = reinterpret_cast<const bf16x8*>(AsB[s & 1]);
        const bf16x8* Bp = reinterpret_cast<const bf16x8*>(BsB[s & 1]);
        bf16x8 af[4], bfr[4];
        #pragma unroll
        for (int mi = 0; mi < 4; ++mi)
            af[mi] = Ap[(wm * 64 + mi * 16 + l15) * 5 + l4];
        #pragma unroll
        for (int ni = 0; ni < 4; ++ni)
            bfr[ni] = Bp[(wn * 64 + ni * 16 + l15) * 5 + l4];
        if (s + 1 < NS) { writeA(AsB[(s + 1) & 1]); writeB(BsB[(s + 1) & 1]); }
        #pragma unroll
        for (int mi = 0; mi < 4; ++mi)
            #pragma unroll
            for (int ni = 0; ni < 4; ++ni)
                acc[mi][ni] = __builtin_amdgcn_mfma_f32_16x16x32_bf16(
                    af[mi], bfr[ni], acc[mi][ni], 0, 0, 0);
        if (s + 2 < NS) { loadA((s + 2) * 32); loadB((s + 2) * 32); }
        __syncthreads();
    }

    const float* bias = bp.bias[blockIdx.z];
    short* __restrict__ C = (short*)bp.C[blockIdx.z];
    #pragma unroll
    for (int mi = 0; mi < 4; ++mi) {
        #pragma unroll
        for (int ni = 0; ni < 4; ++ni) {
            int col = bn + wn * 64 + ni * 16 + l15;
            #pragma unroll
            for (int r = 0; r < 4; ++r) {
                int row = bm + wm * 64 + mi * 16 + l4 * 4 + r;
                float v = acc[mi][ni][r] * scale;
                if (EPI == 1) v += bias[col];
                C[(size_t)row * ldc + col] = f2bf(v);
            }
        }
    }
}

// ---------------- 64x64 batched MFMA GEMM, double-buffered pipeline ----------
// EPI: 0 none, 1 +bias, 2 +bias+relu, 3 out = add + elu(v)
// WS: A *= wsc[k]. SUMB: B += add (TRB fp32). APART(N): A = relu(sum Apart + biasA).
template<typename TA, typename TB, typename TC, bool TRA, bool TRB, int EPI,
         bool WS = false, bool SUMB = false, int APART = 0>
__global__ __launch_bounds__(256) void gemm_b_k(Batch8 bp, int lda, int ldb, int ldc,
                                                int K, float scale,
                                                const float* __restrict__ wsc = nullptr)
{
    __shared__ __align__(16) short AsB[2][64 * 40];
    __shared__ __align__(16) short BsB[2][64 * 40];
    const int t = threadIdx.x;
    const int lane = t & 63;
    const int w = t >> 6, wm = w >> 1, wn = w & 1;
    const int bm = blockIdx.y * 64, bn = blockIdx.x * 64;
    const int l15 = lane & 15, l4 = lane >> 4;
    const TA* __restrict__ A = (const TA*)bp.A[blockIdx.z];
    const TB* __restrict__ B = (const TB*)bp.B[blockIdx.z];

    f32x4 acc[2][2];
    #pragma unroll
    for (int i = 0; i < 2; ++i)
        #pragma unroll
        for (int j = 0; j < 2; ++j)
            #pragma unroll
            for (int r = 0; r < 4; ++r) acc[i][j][r] = 0.f;

    float4 rA[2][APART > 0 ? APART : 1];
    short8 rA16;
    float4 rB[2], rB2[2];
    short8 rB16;

    auto loadA = [&](int k0) {
        if constexpr (APART > 0) {
            #pragma unroll
            for (int p = 0; p < 2; ++p) {
                int row = (t >> 3) + p * 32, c4 = (t & 7) * 4;
                const float* basep = (const float*)A + (size_t)(bm + row) * lda + k0 + c4;
                #pragma unroll
                for (int j = 0; j < APART; ++j)
                    rA[p][j] = *reinterpret_cast<const float4*>(basep + (size_t)j * 262144);
            }
        } else if constexpr (!TRA) {
            if constexpr (sizeof(TA) == 4) {
                #pragma unroll
                for (int p = 0; p < 2; ++p) {
                    int row = (t >> 3) + p * 32, c4 = (t & 7) * 4;
                    rA[p][0] = *reinterpret_cast<const float4*>(
                        A + (size_t)(bm + row) * lda + k0 + c4);
                }
            } else {
                rA16 = *reinterpret_cast<const short8*>(
                    A + (size_t)(bm + (t >> 2)) * lda + k0 + (t & 3) * 8);
            }
        } else {
            #pragma unroll
            for (int p = 0; p < 2; ++p) {
                int kk = (t >> 4) + p * 16, m4 = (t & 15) * 4;
                rA[p][0] = *reinterpret_cast<const float4*>(
                    (const float*)A + (size_t)(k0 + kk) * lda + bm + m4);
            }
        }
    };
    auto writeA = [&](int k0, short* As) {
        if constexpr (APART > 0) {
            const float* ba = bp.biasA[blockIdx.z];
            #pragma unroll
            for (int p = 0; p < 2; ++p) {
                int row = (t >> 3) + p * 32, c4 = (t & 7) * 4;
                float4 v = rA[p][0];
                #pragma unroll
                for (int j = 1; j < APART; ++j) {
                    v.x += rA[p][j].x; v.y += rA[p][j].y;
                    v.z += rA[p][j].z; v.w += rA[p][j].w;
                }
                v.x = fmaxf(v.x + ba[k0 + c4 + 0], 0.f);
                v.y = fmaxf(v.y + ba[k0 + c4 + 1], 0.f);
                v.z = fmaxf(v.z + ba[k0 + c4 + 2], 0.f);
                v.w = fmaxf(v.w + ba[k0 + c4 + 3], 0.f);
                short4 s4 = make_short4(f2bf(v.x), f2bf(v.y), f2bf(v.z), f2bf(v.w));
                *reinterpret_cast<short4*>(&As[row * 40 + c4]) = s4;
            }
        } else if constexpr (!TRA) {
            if constexpr (sizeof(TA) == 4) {
                #pragma unroll
                for (int p = 0; p < 2; ++p) {
                    int row = (t >> 3) + p * 32, c4 = (t & 7) * 4;
                    float4 v = rA[p][0];
                    if constexpr (WS) {
                        v.x *= wsc[k0 + c4 + 0]; v.y *= wsc[k0 + c4 + 1];
                        v.z *= wsc[k0 + c4 + 2]; v.w *= wsc[k0 + c4 + 3];
                    }
                    short4 s4 = make_short4(f2bf(v.x), f2bf(v.y), f2bf(v.z), f2bf(v.w));
                    *reinterpret_cast<short4*>(&As[row * 40 + c4]) = s4;
                }
            } else {
                *reinterpret_cast<short8*>(&As[(t >> 2) * 40 + (t & 3) * 8]) = rA16;
            }
        } else {
            #pragma unroll
            for (int p = 0; p < 2; ++p) {
                int kk = (t >> 4) + p * 16, m4 = (t & 15) * 4;
                As[(m4 + 0) * 40 + kk] = f2bf(rA[p][0].x);
                As[(m4 + 1) * 40 + kk] = f2bf(rA[p][0].y);
                As[(m4 + 2) * 40 + kk] = f2bf(rA[p][0].z);
                As[(m4 + 3) * 40 + kk] = f2bf(rA[p][0].w);
            }
        }
    };
    auto loadB = [&](int k0) {
        if constexpr (!TRB) {
            if constexpr (sizeof(TB) == 4) {
                #pragma unroll
                for (int p = 0; p < 2; ++p) {
                    int row = (t >> 3) + p * 32, c4 = (t & 7) * 4;
                    rB[p] = *reinterpret_cast<const float4*>(
                        B + (size_t)(bn + row) * ldb + k0 + c4);
                }
            } else {
                rB16 = *reinterpret_cast<const short8*>(
                    B + (size_t)(bn + (t >> 2)) * ldb + k0 + (t & 3) * 8);
            }
        } else {
            #pragma unroll
            for (int p = 0; p < 2; ++p) {
                int kk = (t >> 4) + p * 16, n4 = (t & 15) * 4;
                rB[p] = *reinterpret_cast<const float4*>(
                    (const float*)B + (size_t)(k0 + kk) * ldb + bn + n4);
                if constexpr (SUMB)
                    rB2[p] = *reinterpret_cast<const float4*>(
                        (const float*)bp.add[blockIdx.z] + (size_t)(k0 + kk) * ldb + bn + n4);
            }
        }
    };
    auto writeB = [&](short* Bs) {
        if constexpr (!TRB) {
            if constexpr (sizeof(TB) == 4) {
                #pragma unroll
                for (int p = 0; p < 2; ++p) {
                    int row = (t >> 3) + p * 32, c4 = (t & 7) * 4;
                    short4 s4 = make_short4(f2bf(rB[p].x), f2bf(rB[p].y),
                                            f2bf(rB[p].z), f2bf(rB[p].w));
                    *reinterpret_cast<short4*>(&Bs[row * 40 + c4]) = s4;
                }
            } else {
                *reinterpret_cast<short8*>(&Bs[(t >> 2) * 40 + (t & 3) * 8]) = rB16;
            }
        } else {
            #pragma unroll
            for (int p = 0; p < 2; ++p) {
                int kk = (t >> 4) + p * 16, n4 = (t & 15) * 4;
                float4 v = rB[p];
                if constexpr (SUMB) {
                    v.x += rB2[p].x; v.y += rB2[p].y; v.z += rB2[p].z; v.w += rB2[p].w;
                }
                Bs[(n4 + 0) * 40 + kk] = f2bf(v.x);
                Bs[(n4 + 1) * 40 + kk] = f2bf(v.y);
                Bs[(n4 + 2) * 40 + kk] = f2bf(v.z);
                Bs[(n4 + 3) * 40 + kk] = f2bf(v.w);
            }
        }
    };

    const int NS = K >> 5;
    loadA(0); loadB(0);
    writeA(0, AsB[0]); writeB(BsB[0]);
    loadA(32); loadB(32);
    __syncthreads();

    for (int s = 0; s < NS; ++s) {
        const bf16x8* Ap = reinterpret_cast<const bf16x8*>(AsB[s & 1]);
        const bf16x8* Bp = reinterpret_cast<const bf16x8*>(BsB[s & 1]);
        bf16x8 af[2], bfr[2];
        #pragma unroll
        for (int mi = 0; mi < 2; ++mi)
            af[mi] = Ap[(wm * 32 + mi * 16 + l15) * 5 + l4];
        #pragma unroll
        for (int ni = 0; ni < 2; ++ni)
            bfr[ni] = Bp[(wn * 32 + ni * 16 + l15) * 5 + l4];
        if (s + 1 < NS) { writeA((s + 1) * 32, AsB[(s + 1) & 1]); writeB(BsB[(s + 1) & 1]); }
        #pragma unroll
        for (int mi = 0; mi < 2; ++mi)
            #pragma unroll
            for (int ni = 0; ni < 2; ++ni)
                acc[mi][ni] = __builtin_amdgcn_mfma_f32_16x16x32_bf16(
                    af[mi], bfr[ni], acc[mi][ni], 0, 0, 0);
        if (s + 2 < NS) { loadA((s + 2) * 32); loadB((s + 2) * 32); }
        __syncthreads();
    }

    const float* bias = bp.bias[blockIdx.z];
    const float* add = bp.add[blockIdx.z];
    TC* __restrict__ C = (TC*)bp.C[blockIdx.z];
    #pragma unroll
    for (int mi = 0; mi < 2; ++mi) {
        #pragma unroll
        for (int ni = 0; ni < 2; ++ni) {
            int col = bn + wn * 32 + ni * 16 + l15;
            #pragma unroll
            for (int r = 0; r < 4; ++r) {
                int row = bm + wm * 32 + mi * 16 + l4 * 4 + r;
                float v = acc[mi][ni][r] * scale;
                if (EPI == 1) v += bias[col];
                if (EPI == 2) v = fmaxf(v + bias[col], 0.f);
                if (EPI == 3) {
                    float e = v > 0.f ? v : (__expf(v) - 1.f);
                    v = add[(size_t)row * ldc + col] + e;
                }
                if constexpr (sizeof(TC) == 4) C[(size_t)row * ldc + col] = v;
                else C[(size_t)row * ldc + col] = f2bf(v);
            }
        }
    }
}

// ---------------- P-GEMM with inline jmw, pipelined ----------------
__global__ __launch_bounds__(256) void pgemm_k(const float* __restrict__ H,
                                               const float* __restrict__ Gpart,
                                               const float* __restrict__ cmv,
                                               const float* __restrict__ rmv,
                                               const float* __restrict__ entv,
                                               float* __restrict__ Pbuf)
{
    __shared__ __align__(16) short AsB[2][64 * 40];
    __shared__ __align__(16) short BsB[2][64 * 40];
    __shared__ float red[256];
    __shared__ float swv[256];
    const int t = threadIdx.x;

    {
        const int k = t;
        float e = entv[k];
        float esum = bsum(e, red);
        float jm = 0.5f * (esum * (1.f / 256.f) + e - (cmv[k] + rmv[k]) * (1.f / 256.f));
        float mean = bsum(jm, red) * (1.f / 256.f);
        float d = jm - mean;
        float var = bsum(d * d, red) * (1.f / 255.f);
        float v = d / (sqrtf(var) + 1e-6f);
        float mx = bmax(v, red);
        float ex = __expf(v - mx);
        float s = bsum(ex, red);
        swv[k] = ex / s;
        __syncthreads();
    }

    const int c = blockIdx.z;
    const int bm = blockIdx.y * 64, bn = blockIdx.x * 64;
    const int lane = t & 63;
    const int w = t >> 6, wm = w >> 1, wn = w & 1;
    const int l15 = lane & 15, l4 = lane >> 4;
    const float* __restrict__ B0 = Gpart + (size_t)(c * 2 + 0) * 131072;
    const float* __restrict__ B1 = Gpart + (size_t)(c * 2 + 1) * 131072;
    float* __restrict__ C = Pbuf + (size_t)c * 524288;

    f32x4 acc[2][2];
    #pragma unroll
    for (int i = 0; i < 2; ++i)
        #pragma unroll
        for (int j = 0; j < 2; ++j)
            #pragma unroll
            for (int r = 0; r < 4; ++r) acc[i][j][r] = 0.f;

    float4 rA[2], rB[2], rB2[2];
    auto loadA = [&](int k0) {
        #pragma unroll
        for (int p = 0; p < 2; ++p) {
            int row = (t >> 3) + p * 32, c4 = (t & 7) * 4;
            rA[p] = *reinterpret_cast<const float4*>(
                H + (size_t)(bm + row) * 256 + k0 + c4);
        }
    };
    auto writeA = [&](int k0, short* As) {
        #pragma unroll
        for (int p = 0; p < 2; ++p) {
            int row = (t >> 3) + p * 32, c4 = (t & 7) * 4;
            float4 v = rA[p];
            v.x *= swv[k0 + c4 + 0]; v.y *= swv[k0 + c4 + 1];
            v.z *= swv[k0 + c4 + 2]; v.w *= swv[k0 + c4 + 3];
            short4 s4 = make_short4(f2bf(v.x), f2bf(v.y), f2bf(v.z), f2bf(v.w));
            *reinterpret_cast<short4*>(&As[row * 40 + c4]) = s4;
        }
    };
    auto loadB = [&](int k0) {
        #pragma unroll
        for (int p = 0; p < 2; ++p) {
            int kk = (t >> 4) + p * 16, n4 = (t & 15) * 4;
            rB[p]  = *reinterpret_cast<const float4*>(B0 + (size_t)(k0 + kk) * 512 + bn + n4);
            rB2[p] = *reinterpret_cast<const float4*>(B1 + (size_t)(k0 + kk) * 512 + bn + n4);
        }
    };
    auto writeB = [&](short* Bs) {
        #pragma unroll
        for (int p = 0; p < 2; ++p) {
            int kk = (t >> 4) + p * 16, n4 = (t & 15) * 4;
            float4 v = rB[p];
            v.x += rB2[p].x; v.y += rB2[p].y; v.z += rB2[p].z; v.w += rB2[p].w;
            Bs[(n4 + 0) * 40 + kk] = f2bf(v.x);
            Bs[(n4 + 1) * 40 + kk] = f2bf(v.y);
            Bs[(n4 + 2) * 40 + kk] = f2bf(v.z);
            Bs[(n4 + 3) * 40 + kk] = f2bf(v.w);
        }
    };

    const int NS = 8;
    loadA(0); loadB(0);
    writeA(0, AsB[0]); writeB(BsB[0]);
    loadA(32); loadB(32);
    __syncthreads();

    for (int s = 0; s < NS; ++s) {
        const bf16x8* Ap = reinterpret_cast<const bf16x8*>(AsB[s & 1]);
        const bf16x8* Bp = reinterpret_cast<const bf16x8*>(BsB[s & 1]);
        bf16x8 af[2], bfr[2];
        #pragma unroll
        for (int mi = 0; mi < 2; ++mi)
            af[mi] = Ap[(wm * 32 + mi * 16 + l15) * 5 + l4];
        #pragma unroll
        for (int ni = 0; ni < 2; ++ni)
            bfr[ni] = Bp[(wn * 32 + ni * 16 + l15) * 5 + l4];
        if (s + 1 < NS) { writeA((s + 1) * 32, AsB[(s + 1) & 1]); writeB(BsB[(s + 1) & 1]); }
        #pragma unroll
        for (int mi = 0; mi < 2; ++mi)
            #pragma unroll
            for (int ni = 0; ni < 2; ++ni)
                acc[mi][ni] = __builtin_amdgcn_mfma_f32_16x16x32_bf16(
                    af[mi], bfr[ni], acc[mi][ni], 0, 0, 0);
        if (s + 2 < NS) { loadA((s + 2) * 32); loadB((s + 2) * 32); }
        __syncthreads();
    }

    #pragma unroll
    for (int mi = 0; mi < 2; ++mi)
        #pragma unroll
        for (int ni = 0; ni < 2; ++ni) {
            int col = bn + wn * 32 + ni * 16 + l15;
            #pragma unroll
            for (int r = 0; r < 4; ++r) {
                int row = bm + wm * 32 + mi * 16 + l4 * 4 + r;
                C[(size_t)row * 512 + col] = acc[mi][ni][r];
            }
        }
}

// ---------------- attention softmax + head-mean (bf16 in/out), all 4 tags ----
__global__ __launch_bounds__(256) void softmax_mean_b(const short* __restrict__ S,
                                                      short* __restrict__ a)
{
    __shared__ float red[256];
    const int g = blockIdx.x, t = threadIdx.x;
    const int tag = g >> 10, row = g & 1023;
    const short* s0 = S + ((size_t)(tag * 2 + 0) << 20) + (size_t)row * 1024 + t * 4;
    const short* s1 = S + ((size_t)(tag * 2 + 1) << 20) + (size_t)row * 1024 + t * 4;

    short4 r0 = *reinterpret_cast<const short4*>(s0);
    short4 r1 = *reinterpret_cast<const short4*>(s1);
    float v0[4] = {bf2f(r0.x), bf2f(r0.y), bf2f(r0.z), bf2f(r0.w)};
    float v1[4] = {bf2f(r1.x), bf2f(r1.y), bf2f(r1.z), bf2f(r1.w)};

    float m0 = fmaxf(fmaxf(v0[0], v0[1]), fmaxf(v0[2], v0[3]));
    float m1 = fmaxf(fmaxf(v1[0], v1[1]), fmaxf(v1[2], v1[3]));
    m0 = bmax(m0, red);
    m1 = bmax(m1, red);

    float e0[4], e1[4], sum0 = 0.f, sum1 = 0.f;
    #pragma unroll
    for (int j = 0; j < 4; ++j) {
        e0[j] = __expf(v0[j] - m0); sum0 += e0[j];
        e1[j] = __expf(v1[j] - m1); sum1 += e1[j];
    }
    sum0 = bsum(sum0, red);
    sum1 = bsum(sum1, red);
    float i0 = 0.5f / sum0, i1 = 0.5f / sum1;

    short4 o;
    o.x = f2bf(e0[0] * i0 + e1[0] * i1);
    o.y = f2bf(e0[1] * i0 + e1[1] * i1);
    o.z = f2bf(e0[2] * i0 + e1[2] * i1);
    o.w = f2bf(e0[3] * i0 + e1[3] * i1);
    *reinterpret_cast<short4*>(a + ((size_t)tag << 20) + (size_t)row * 1024 + t * 4) = o;
}

// ---------------- column standardize (ddof=1) + column softmax, batched ------
template<typename TOUT>
__global__ __launch_bounds__(256) void norm_softmax_b(const float* __restrict__ Zbase,
                                                      int zstride,
                                                      TOUT* __restrict__ Hout, int ldh,
                                                      int joffmul,
                                                      float* __restrict__ out2)
{
    __shared__ float red[256];
    const int j = blockIdx.x, t = threadIdx.x;
    const float* Z = Zbase + (size_t)blockIdx.y * zstride;
    const int joff = blockIdx.y * joffmul;

    float x[4];
    #pragma unroll
    for (int i = 0; i < 4; ++i) x[i] = Z[(size_t)(t + i * 256) * 256 + j];

    float s = x[0] + x[1] + x[2] + x[3];
    float mean = bsum(s, red) * (1.f / 1024.f);

    float ss = 0.f;
    #pragma unroll
    for (int i = 0; i < 4; ++i) { float d = x[i] - mean; ss += d * d; }
    float var = bsum(ss, red) * (1.f / 1023.f);
    float inv = 1.f / (sqrtf(var) + 1e-6f);

    float v[4];
    float mx = -3.4e38f;
    #pragma unroll
    for (int i = 0; i < 4; ++i) { v[i] = (x[i] - mean) * inv; mx = fmaxf(mx, v[i]); }
    mx = bmax(mx, red);

    float e[4], es = 0.f;
    #pragma unroll
    for (int i = 0; i < 4; ++i) { e[i] = __expf(v[i] - mx); es += e[i]; }
    es = bsum(es, red);
    float invs = 1.f / es;

    #pragma unroll
    for (int i = 0; i < 4; ++i) {
        float o = e[i] * invs;
        if constexpr (sizeof(TOUT) == 4)
            Hout[(size_t)(t + i * 256) * ldh + joff + j] = o;
        else
            Hout[(size_t)(t + i * 256) * ldh + joff + j] = f2bf(o);
        if (out2) out2[(size_t)(t + i * 256) * 256 + joff + j] = o;
    }
}

// ---------------- fused: jsd_part (jobs 0..1023) || G-GEMM (jobs 1024..1151) --
__global__ __launch_bounds__(256) void jsdg_k(const float* __restrict__ H,
                                              float* __restrict__ Cpart,
                                              const float* __restrict__ xt,
                                              const float* __restrict__ xn,
                                              float* __restrict__ Gpart)
{
    __shared__ __align__(16) short As[64 * 40];
    __shared__ __align__(16) short Bs[64 * 40];
    const int t = threadIdx.x;
    const int job = blockIdx.x;

    if (job < 1024) {
        float (*hj)[33] = (float(*)[33])As;
        float (*hk)[33] = (float(*)[33])Bs;
        const int tx = t & 15, ty = t >> 4;
        const int k0 = (job & 7) * 32, j0 = ((job >> 3) & 7) * 32;
        const int slab = job >> 6, nbase = slab * 64;
        float acc[2][2] = {};
        for (int c = 0; c < 8; ++c) {
            int n0 = nbase + c * 8;
            int nl = t >> 5, cc = t & 31;
            hj[nl][cc] = H[(size_t)(n0 + nl) * 256 + j0 + cc];
            hk[nl][cc] = H[(size_t)(n0 + nl) * 256 + k0 + cc];
            __syncthreads();
            #pragma unroll
            for (int nn = 0; nn < 8; ++nn) {
                float a0 = hj[nn][ty * 2], a1 = hj[nn][ty * 2 + 1];
                float b0 = hk[nn][tx * 2], b1 = hk[nn][tx * 2 + 1];
                acc[0][0] += a0 * __logf(0.5f * (a0 + b0));
                acc[0][1] += a0 * __logf(0.5f * (a0 + b1));
                acc[1][0] += a1 * __logf(0.5f * (a1 + b0));
                acc[1][1] += a1 * __logf(0.5f * (a1 + b1));
            }
            __syncthreads();
        }
        float* Cp = Cpart + (size_t)slab * 65536;
        #pragma unroll
        for (int i = 0; i < 2; ++i)
            #pragma unroll
            for (int jj = 0; jj < 2; ++jj)
                Cp[(size_t)(j0 + ty * 2 + i) * 256 + k0 + tx * 2 + jj] = acc[i][jj];
    } else {
        const int gg = job - 1024;
        const int z = gg >> 5, tile = gg & 31;
        const int chain = z >> 1, slab = z & 1;
        const float* A = H + (size_t)slab * 131072;
        const float* B = (chain ? xn : xt) + (size_t)slab * 262144;
        float* C = Gpart + (size_t)z * 131072;
        const int bm = (tile >> 3) * 64, bn = (tile & 7) * 64;
        const int lane = t & 63;
        const int w = t >> 6, wm = w >> 1, wn = w & 1;
        const int l15 = lane & 15, l4 = lane >> 4;

        f32x4 acc[2][2];
        #pragma unroll
        for (int i = 0; i < 2; ++i)
            #pragma unroll
            for (int j = 0; j < 2; ++j)
                #pragma unroll
                for (int r = 0; r < 4; ++r) acc[i][j][r] = 0.f;

        for (int k0 = 0; k0 < 512; k0 += 32) {
            #pragma unroll
            for (int p = 0; p < 2; ++p) {
                int kk = (t >> 4) + p * 16;
                int m4 = (t & 15) * 4;
                const float4 v = *reinterpret_cast<const float4*>(
                    A + (size_t)(k0 + kk) * 256 + bm + m4);
                As[(m4 + 0) * 40 + kk] = f2bf(v.x);
                As[(m4 + 1) * 40 + kk] = f2bf(v.y);
                As[(m4 + 2) * 40 + kk] = f2bf(v.z);
                As[(m4 + 3) * 40 + kk] = f2bf(v.w);
            }
            #pragma unroll
            for (int p = 0; p < 2; ++p) {
                int kk = (t >> 4) + p * 16;
                int n4 = (t & 15) * 4;
                const float4 v = *reinterpret_cast<const float4*>(
                    B + (size_t)(k0 + kk) * 512 + bn + n4);
                Bs[(n4 + 0) * 40 + kk] = f2bf(v.x);
                Bs[(n4 + 1) * 40 + kk] = f2bf(v.y);
                Bs[(n4 + 2) * 40 + kk] = f2bf(v.z);
                Bs[(n4 + 3) * 40 + kk] = f2bf(v.w);
            }
            __syncthreads();

            const bf16x8* Ap = reinterpret_cast<const bf16x8*>(As);
            const bf16x8* Bp = reinterpret_cast<const bf16x8*>(Bs);
            bf16x8 af[2], bfr[2];
            #pragma unroll
            for (int mi = 0; mi < 2; ++mi)
                af[mi] = Ap[(wm * 32 + mi * 16 + l15) * 5 + l4];
            #pragma unroll
            for (int ni = 0; ni < 2; ++ni)
                bfr[ni] = Bp[(wn * 32 + ni * 16 + l15) * 5 + l4];
            #pragma unroll
            for (int mi = 0; mi < 2; ++mi)
                #pragma unroll
                for (int ni = 0; ni < 2; ++ni)
                    acc[mi][ni] = __builtin_amdgcn_mfma_f32_16x16x32_bf16(
                        af[mi], bfr[ni], acc[mi][ni], 0, 0, 0);
            __syncthreads();
        }

        #pragma unroll
        for (int mi = 0; mi < 2; ++mi)
            #pragma unroll
            for (int ni = 0; ni < 2; ++ni) {
                int col = bn + wn * 32 + ni * 16 + l15;
                #pragma unroll
                for (int r = 0; r < 4; ++r) {
                    int row = bm + wm * 32 + mi * 16 + l4 * 4 + r;
                    C[(size_t)row * 512 + col] = acc[mi][ni][r];
                }
            }
    }
}

// ---------------- per-k row/col sums over 16 slabs; ent[k] = diag(C) --------
__global__ __launch_bounds__(256) void rc_k(const float* __restrict__ Cpart,
                                            float* __restrict__ cmv,
                                            float* __restrict__ rmv,
                                            float* __restrict__ entv)
{
    __shared__ float red[256];
    const int k = blockIdx.x, j = threadIdx.x;
    float cm = 0.f, rm = 0.f;
    #pragma unroll
    for (int s = 0; s < 16; ++s) {
        cm += Cpart[(size_t)s * 65536 + (size_t)j * 256 + k];
        rm += Cpart[(size_t)s * 65536 + (size_t)k * 256 + j];
    }
    if (j == k) entv[k] = cm;
    cm = bsum(cm, red);
    rm = bsum(rm, red);
    if (j == 0) { cmv[k] = cm; rmv[k] = rm; }
}

// ---------------- launch ----------------
extern "C" void kernel_launch(void* const* d_in, const int* in_sizes, int n_in,
                              void* d_out, int out_size, void* d_ws, size_t ws_size,
                              hipStream_t stream) {
    const float* x_time = (const float*)d_in[0];
    const float* x_news = (const float*)d_in[1];
    const float* f1w = (const float*)d_in[34];
    const float* f1b = (const float*)d_in[35];
    const float* f2w = (const float*)d_in[36];
    const float* f2b = (const float*)d_in[37];
    const float* theta_t = (const float*)d_in[38];
    const float* theta_n = (const float*)d_in[39];
    float* out = (float*)d_out;

    float* ws = (float*)d_ws;
    short* s_qk = (short*)ws;
    short* s_a  = (short*)ws;
    short* s_Hc = (short*)ws;
    short* s_S    = (short*)(ws + 2097152);
    float* zpart  = ws + 2097152;
    float* z2b    = ws + 4718592;
    float* Cpartf = ws + 2097152;
    float* z2f    = z2b;
    float* Cpart  = ws + 2097152;
    float* entv   = ws + 3145728;
    float* cmv    = entv + 256;
    float* rmv    = cmv + 256;
    float* Gpart  = ws + 3407872;
    float* Pbuf   = ws + 4194304;
    float* Hbuf   = ws + 6291456;

    const float* qsrc[4]  = {x_time, x_news, x_time, x_news};
    const float* kvsrc[4] = {x_time, x_news, x_news, x_time};
    const int    base[4]  = {2, 10, 18, 26};

    Batch8 bp{};

    // ======== projections: z=8 ========
    for (int tg = 0; tg < 4; ++tg) {
        bp.A[tg] = qsrc[tg];      bp.B[tg] = d_in[base[tg] + 0];
        bp.bias[tg] = (const float*)d_in[base[tg] + 2];
        bp.C[tg] = s_qk + (size_t)tg * 524288;
        bp.A[4 + tg] = kvsrc[tg]; bp.B[4 + tg] = d_in[base[tg] + 1];
        bp.bias[4 + tg] = (const float*)d_in[base[tg] + 3];
        bp.C[4 + tg] = s_qk + (size_t)(4 + tg) * 524288;
    }
    gemm_big_k<float, float, 1>
        <<<dim3(4, 8, 8), 256, 0, stream>>>(bp, 512, 512, 512, 512, 1.f);

    // ======== scores: z=8, scale 1/16 ========
    for (int i = 0; i < 8; ++i) {
        int tg = i >> 1, h = i & 1;
        bp.A[i] = s_qk + (size_t)tg * 524288 + h * 256;
        bp.B[i] = s_qk + (size_t)(4 + tg) * 524288 + h * 256;
        bp.bias[i] = nullptr;
        bp.C[i] = s_S + ((size_t)i << 20);
    }
    gemm_big_k<short, short, 0>
        <<<dim3(8, 8, 8), 256, 0, stream>>>(bp, 512, 512, 1024, 256, 0.0625f);

    // ======== softmax + head mean -> a ========
    softmax_mean_b<<<4096, 256, 0, stream>>>(s_S, s_a);

    // ======== incidence MLP1: split-K z=8 -> zpart fp32 ========
    for (int i = 0; i < 8; ++i) {
        int tg = i >> 1, hf = i & 1;
        bp.A[i] = s_a + ((size_t)tg << 20) + hf * 512;
        bp.B[i] = (const float*)d_in[base[tg] + 4] + hf * 512;
        bp.bias[i] = nullptr;
        bp.C[i] = zpart + (size_t)i * 262144;
    }
    gemm_b_k<short, float, float, false, false, 0>
        <<<dim3(4, 16, 8), 256, 0, stream>>>(bp, 1024, 1024, 256, 512, 1.f);

    // ======== incidence MLP2 z=4 (APART=2) ========
    for (int tg = 0; tg < 4; ++tg) {
        bp.A[tg] = zpart + (size_t)tg * 2 * 262144;
        bp.biasA[tg] = (const float*)d_in[base[tg] + 5];
        bp.B[tg] = d_in[base[tg] + 6];
        bp.bias[tg] = (const float*)d_in[base[tg] + 7];
        bp.C[tg] = z2b + (size_t)tg * 262144;
    }
    gemm_b_k<float, float, float, false, false, 1, false, false, 2>
        <<<dim3(4, 16, 4), 256, 0, stream>>>(bp, 256, 256, 256, 256, 1.f);

    // norm_softmax over 4 tags -> Hcat (bf16)
    norm_softmax_b<short><<<dim3(256, 4), 256, 0, stream>>>(z2b, 262144, s_Hc, 1024, 256, nullptr);

    // ======== fusion MLP1 split-K z=4 -> Cpartf ========
    for (int z = 0; z < 4; ++z) {
        bp.A[z] = s_Hc + z * 256;
        bp.B[z] = f1w + z * 256;
        bp.bias[z] = nullptr;
        bp.C[z] = Cpartf + (size_t)z * 262144;
    }
    gemm_b_k<short, float, float, false, false, 0>
        <<<dim3(4, 16, 4), 256, 0, stream>>>(bp, 1024, 1024, 256, 256, 1.f);

    // ======== fusion MLP2 (APART=4) ========
    bp.A[0] = Cpartf; bp.biasA[0] = f1b; bp.B[0] = f2w; bp.bias[0] = f2b; bp.C[0] = z2f;
    gemm_b_k<float, float, float, false, false, 1, false, false, 4>
        <<<dim3(4, 16, 1), 256, 0, stream>>>(bp, 256, 256, 256, 256, 1.f);
    norm_softmax_b<float><<<dim3(256, 1), 256, 0, stream>>>(z2f, 0, Hbuf, 256, 0,
                                                            out + 1048576);

    // ======== JSD || G-GEMM (fused) ========
    jsdg_k<<<1152, 256, 0, stream>>>(Hbuf, Cpart, x_time, x_news, Gpart);
    rc_k<<<256, 256, 0, stream>>>(Cpart, cmv, rmv, entv);

    // ======== P = (H*w)(G0+G1) with inline jmw ========
    pgemm_k<<<dim3(8, 16, 2), 256, 0, stream>>>(Hbuf, Gpart, cmv, rmv, entv, Pbuf);

    // ======== out = x + elu(P theta) ========
    const float* xc[2] = {x_time, x_news};
    const float* th[2] = {theta_t, theta_n};
    for (int c = 0; c < 2; ++c) {
        bp.A[c] = Pbuf + (size_t)c * 524288;
        bp.B[c] = th[c];
        bp.bias[c] = nullptr;
        bp.add[c] = xc[c];
        bp.C[c] = out + (size_t)c * 524288;
    }
    gemm_b_k<float, float, float, false, true, 3>
        <<<dim3(8, 16, 2), 256, 0, stream>>>(bp, 512, 512, 512, 512, 1.f);
}

// Round 13
// 182.438 us; speedup vs baseline: 5.5100x; 1.0508x over previous
//
#include <hip/hip_runtime.h>
#include <hip/hip_bf16.h>
#include <math.h>

typedef __attribute__((ext_vector_type(8))) short bf16x8;
typedef __attribute__((ext_vector_type(8))) short short8;
typedef __attribute__((ext_vector_type(4))) float f32x4;

__device__ __forceinline__ short f2bf(float f) {
    unsigned u = __float_as_uint(f);
    u += 0x7fffu + ((u >> 16) & 1u);
    return (short)(u >> 16);
}
__device__ __forceinline__ float bf2f(short s) {
    return __uint_as_float(((unsigned)(unsigned short)s) << 16);
}

// ---------------- fast reductions: wave shfl + 4-entry LDS combine ----------
__device__ __forceinline__ float wsum(float v) {
    #pragma unroll
    for (int off = 32; off >= 1; off >>= 1) v += __shfl_xor(v, off);
    return v;
}
__device__ __forceinline__ float wmax(float v) {
    #pragma unroll
    for (int off = 32; off >= 1; off >>= 1) v = fmaxf(v, __shfl_xor(v, off));
    return v;
}
// blockDim.x == 256 (4 waves). red4: shared float[4] scratch.
__device__ __forceinline__ float bsum1(float v, float* red4) {
    v = wsum(v);
    if ((threadIdx.x & 63) == 0) red4[threadIdx.x >> 6] = v;
    __syncthreads();
    float r = red4[0] + red4[1] + red4[2] + red4[3];
    __syncthreads();
    return r;
}
__device__ __forceinline__ float bmax1(float v, float* red4) {
    v = wmax(v);
    if ((threadIdx.x & 63) == 0) red4[threadIdx.x >> 6] = v;
    __syncthreads();
    float r = fmaxf(fmaxf(red4[0], red4[1]), fmaxf(red4[2], red4[3]));
    __syncthreads();
    return r;
}
__device__ __forceinline__ void bsum2(float& a, float& b, float (*red)[4]) {
    a = wsum(a); b = wsum(b);
    int wv = threadIdx.x >> 6;
    if ((threadIdx.x & 63) == 0) { red[0][wv] = a; red[1][wv] = b; }
    __syncthreads();
    a = red[0][0] + red[0][1] + red[0][2] + red[0][3];
    b = red[1][0] + red[1][1] + red[1][2] + red[1][3];
    __syncthreads();
}
__device__ __forceinline__ void bmax2(float& a, float& b, float (*red)[4]) {
    a = wmax(a); b = wmax(b);
    int wv = threadIdx.x >> 6;
    if ((threadIdx.x & 63) == 0) { red[0][wv] = a; red[1][wv] = b; }
    __syncthreads();
    a = fmaxf(fmaxf(red[0][0], red[0][1]), fmaxf(red[0][2], red[0][3]));
    b = fmaxf(fmaxf(red[1][0], red[1][1]), fmaxf(red[1][2], red[1][3]));
    __syncthreads();
}

struct Batch8 {
    const void* A[8];
    const void* B[8];
    const float* bias[8];
    const float* biasA[8];
    const float* add[8];
    void* C[8];
};

// ---------------- BIG 128x128 MFMA GEMM, double-buffered pipeline ----------
template<typename TA, typename TB, int EPI>
__global__ __launch_bounds__(256) void gemm_big_k(Batch8 bp, int lda, int ldb, int ldc,
                                                  int K, float scale)
{
    __shared__ __align__(16) short AsB[2][128 * 40];
    __shared__ __align__(16) short BsB[2][128 * 40];
    const int t = threadIdx.x;
    const int lane = t & 63;
    const int w = t >> 6, wm = w >> 1, wn = w & 1;
    const int bm = blockIdx.y * 128, bn = blockIdx.x * 128;
    const int l15 = lane & 15, l4 = lane >> 4;
    const TA* __restrict__ A = (const TA*)bp.A[blockIdx.z];
    const TB* __restrict__ B = (const TB*)bp.B[blockIdx.z];

    f32x4 acc[4][4];
    #pragma unroll
    for (int i = 0; i < 4; ++i)
        #pragma unroll
        for (int j = 0; j < 4; ++j)
            #pragma unroll
            for (int r = 0; r < 4; ++r) acc[i][j][r] = 0.f;

    float4 rA[4]; short8 rA16[2];
    float4 rB[4]; short8 rB16[2];

    auto loadA = [&](int k0) {
        if constexpr (sizeof(TA) == 4) {
            #pragma unroll
            for (int p = 0; p < 4; ++p) {
                int row = (t >> 3) + p * 32, c4 = (t & 7) * 4;
                rA[p] = *reinterpret_cast<const float4*>(
                    A + (size_t)(bm + row) * lda + k0 + c4);
            }
        } else {
            #pragma unroll
            for (int p = 0; p < 2; ++p) {
                int row = (t >> 2) + p * 64, c8 = (t & 3) * 8;
                rA16[p] = *reinterpret_cast<const short8*>(
                    A + (size_t)(bm + row) * lda + k0 + c8);
            }
        }
    };
    auto writeA = [&](short* As) {
        if constexpr (sizeof(TA) == 4) {
            #pragma unroll
            for (int p = 0; p < 4; ++p) {
                int row = (t >> 3) + p * 32, c4 = (t & 7) * 4;
                short4 s4 = make_short4(f2bf(rA[p].x), f2bf(rA[p].y),
                                        f2bf(rA[p].z), f2bf(rA[p].w));
                *reinterpret_cast<short4*>(&As[row * 40 + c4]) = s4;
            }
        } else {
            #pragma unroll
            for (int p = 0; p < 2; ++p) {
                int row = (t >> 2) + p * 64, c8 = (t & 3) * 8;
                *reinterpret_cast<short8*>(&As[row * 40 + c8]) = rA16[p];
            }
        }
    };
    auto loadB = [&](int k0) {
        if constexpr (sizeof(TB) == 4) {
            #pragma unroll
            for (int p = 0; p < 4; ++p) {
                int row = (t >> 3) + p * 32, c4 = (t & 7) * 4;
                rB[p] = *reinterpret_cast<const float4*>(
                    B + (size_t)(bn + row) * ldb + k0 + c4);
            }
        } else {
            #pragma unroll
            for (int p = 0; p < 2; ++p) {
                int row = (t >> 2) + p * 64, c8 = (t & 3) * 8;
                rB16[p] = *reinterpret_cast<const short8*>(
                    B + (size_t)(bn + row) * ldb + k0 + c8);
            }
        }
    };
    auto writeB = [&](short* Bs) {
        if constexpr (sizeof(TB) == 4) {
            #pragma unroll
            for (int p = 0; p < 4; ++p) {
                int row = (t >> 3) + p * 32, c4 = (t & 7) * 4;
                short4 s4 = make_short4(f2bf(rB[p].x), f2bf(rB[p].y),
                                        f2bf(rB[p].z), f2bf(rB[p].w));
                *reinterpret_cast<short4*>(&Bs[row * 40 + c4]) = s4;
            }
        } else {
            #pragma unroll
            for (int p = 0; p < 2; ++p) {
                int row = (t >> 2) + p * 64, c8 = (t & 3) * 8;
                *reinterpret_cast<short8*>(&Bs[row * 40 + c8]) = rB16[p];
            }
        }
    };

    const int NS = K >> 5;
    loadA(0); loadB(0);
    writeA(AsB[0]); writeB(BsB[0]);
    loadA(32); loadB(32);
    __syncthreads();

    for (int s = 0; s < NS; ++s) {
        const bf16x8* Ap = reinterpret_cast<const bf16x8*>(AsB[s & 1]);
        const bf16x8* Bp = reinterpret_cast<const bf16x8*>(BsB[s & 1]);
        bf16x8 af[4], bfr[4];
        #pragma unroll
        for (int mi = 0; mi < 4; ++mi)
            af[mi] = Ap[(wm * 64 + mi * 16 + l15) * 5 + l4];
        #pragma unroll
        for (int ni = 0; ni < 4; ++ni)
            bfr[ni] = Bp[(wn * 64 + ni * 16 + l15) * 5 + l4];
        if (s + 1 < NS) { writeA(AsB[(s + 1) & 1]); writeB(BsB[(s + 1) & 1]); }
        #pragma unroll
        for (int mi = 0; mi < 4; ++mi)
            #pragma unroll
            for (int ni = 0; ni < 4; ++ni)
                acc[mi][ni] = __builtin_amdgcn_mfma_f32_16x16x32_bf16(
                    af[mi], bfr[ni], acc[mi][ni], 0, 0, 0);
        if (s + 2 < NS) { loadA((s + 2) * 32); loadB((s + 2) * 32); }
        __syncthreads();
    }

    const float* bias = bp.bias[blockIdx.z];
    short* __restrict__ C = (short*)bp.C[blockIdx.z];
    #pragma unroll
    for (int mi = 0; mi < 4; ++mi) {
        #pragma unroll
        for (int ni = 0; ni < 4; ++ni) {
            int col = bn + wn * 64 + ni * 16 + l15;
            #pragma unroll
            for (int r = 0; r < 4; ++r) {
                int row = bm + wm * 64 + mi * 16 + l4 * 4 + r;
                float v = acc[mi][ni][r] * scale;
                if (EPI == 1) v += bias[col];
                C[(size_t)row * ldc + col] = f2bf(v);
            }
        }
    }
}

// ---------------- 64x64 batched MFMA GEMM, double-buffered pipeline ----------
template<typename TA, typename TB, typename TC, bool TRA, bool TRB, int EPI,
         bool WS = false, bool SUMB = false, int APART = 0>
__global__ __launch_bounds__(256) void gemm_b_k(Batch8 bp, int lda, int ldb, int ldc,
                                                int K, float scale,
                                                const float* __restrict__ wsc = nullptr)
{
    __shared__ __align__(16) short AsB[2][64 * 40];
    __shared__ __align__(16) short BsB[2][64 * 40];
    const int t = threadIdx.x;
    const int lane = t & 63;
    const int w = t >> 6, wm = w >> 1, wn = w & 1;
    const int bm = blockIdx.y * 64, bn = blockIdx.x * 64;
    const int l15 = lane & 15, l4 = lane >> 4;
    const TA* __restrict__ A = (const TA*)bp.A[blockIdx.z];
    const TB* __restrict__ B = (const TB*)bp.B[blockIdx.z];

    f32x4 acc[2][2];
    #pragma unroll
    for (int i = 0; i < 2; ++i)
        #pragma unroll
        for (int j = 0; j < 2; ++j)
            #pragma unroll
            for (int r = 0; r < 4; ++r) acc[i][j][r] = 0.f;

    float4 rA[2][APART > 0 ? APART : 1];
    short8 rA16;
    float4 rB[2], rB2[2];
    short8 rB16;

    auto loadA = [&](int k0) {
        if constexpr (APART > 0) {
            #pragma unroll
            for (int p = 0; p < 2; ++p) {
                int row = (t >> 3) + p * 32, c4 = (t & 7) * 4;
                const float* basep = (const float*)A + (size_t)(bm + row) * lda + k0 + c4;
                #pragma unroll
                for (int j = 0; j < APART; ++j)
                    rA[p][j] = *reinterpret_cast<const float4*>(basep + (size_t)j * 262144);
            }
        } else if constexpr (!TRA) {
            if constexpr (sizeof(TA) == 4) {
                #pragma unroll
                for (int p = 0; p < 2; ++p) {
                    int row = (t >> 3) + p * 32, c4 = (t & 7) * 4;
                    rA[p][0] = *reinterpret_cast<const float4*>(
                        A + (size_t)(bm + row) * lda + k0 + c4);
                }
            } else {
                rA16 = *reinterpret_cast<const short8*>(
                    A + (size_t)(bm + (t >> 2)) * lda + k0 + (t & 3) * 8);
            }
        } else {
            #pragma unroll
            for (int p = 0; p < 2; ++p) {
                int kk = (t >> 4) + p * 16, m4 = (t & 15) * 4;
                rA[p][0] = *reinterpret_cast<const float4*>(
                    (const float*)A + (size_t)(k0 + kk) * lda + bm + m4);
            }
        }
    };
    auto writeA = [&](int k0, short* As) {
        if constexpr (APART > 0) {
            const float* ba = bp.biasA[blockIdx.z];
            #pragma unroll
            for (int p = 0; p < 2; ++p) {
                int row = (t >> 3) + p * 32, c4 = (t & 7) * 4;
                float4 v = rA[p][0];
                #pragma unroll
                for (int j = 1; j < APART; ++j) {
                    v.x += rA[p][j].x; v.y += rA[p][j].y;
                    v.z += rA[p][j].z; v.w += rA[p][j].w;
                }
                v.x = fmaxf(v.x + ba[k0 + c4 + 0], 0.f);
                v.y = fmaxf(v.y + ba[k0 + c4 + 1], 0.f);
                v.z = fmaxf(v.z + ba[k0 + c4 + 2], 0.f);
                v.w = fmaxf(v.w + ba[k0 + c4 + 3], 0.f);
                short4 s4 = make_short4(f2bf(v.x), f2bf(v.y), f2bf(v.z), f2bf(v.w));
                *reinterpret_cast<short4*>(&As[row * 40 + c4]) = s4;
            }
        } else if constexpr (!TRA) {
            if constexpr (sizeof(TA) == 4) {
                #pragma unroll
                for (int p = 0; p < 2; ++p) {
                    int row = (t >> 3) + p * 32, c4 = (t & 7) * 4;
                    float4 v = rA[p][0];
                    if constexpr (WS) {
                        v.x *= wsc[k0 + c4 + 0]; v.y *= wsc[k0 + c4 + 1];
                        v.z *= wsc[k0 + c4 + 2]; v.w *= wsc[k0 + c4 + 3];
                    }
                    short4 s4 = make_short4(f2bf(v.x), f2bf(v.y), f2bf(v.z), f2bf(v.w));
                    *reinterpret_cast<short4*>(&As[row * 40 + c4]) = s4;
                }
            } else {
                *reinterpret_cast<short8*>(&As[(t >> 2) * 40 + (t & 3) * 8]) = rA16;
            }
        } else {
            #pragma unroll
            for (int p = 0; p < 2; ++p) {
                int kk = (t >> 4) + p * 16, m4 = (t & 15) * 4;
                As[(m4 + 0) * 40 + kk] = f2bf(rA[p][0].x);
                As[(m4 + 1) * 40 + kk] = f2bf(rA[p][0].y);
                As[(m4 + 2) * 40 + kk] = f2bf(rA[p][0].z);
                As[(m4 + 3) * 40 + kk] = f2bf(rA[p][0].w);
            }
        }
    };
    auto loadB = [&](int k0) {
        if constexpr (!TRB) {
            if constexpr (sizeof(TB) == 4) {
                #pragma unroll
                for (int p = 0; p < 2; ++p) {
                    int row = (t >> 3) + p * 32, c4 = (t & 7) * 4;
                    rB[p] = *reinterpret_cast<const float4*>(
                        B + (size_t)(bn + row) * ldb + k0 + c4);
                }
            } else {
                rB16 = *reinterpret_cast<const short8*>(
                    B + (size_t)(bn + (t >> 2)) * ldb + k0 + (t & 3) * 8);
            }
        } else {
            #pragma unroll
            for (int p = 0; p < 2; ++p) {
                int kk = (t >> 4) + p * 16, n4 = (t & 15) * 4;
                rB[p] = *reinterpret_cast<const float4*>(
                    (const float*)B + (size_t)(k0 + kk) * ldb + bn + n4);
                if constexpr (SUMB)
                    rB2[p] = *reinterpret_cast<const float4*>(
                        (const float*)bp.add[blockIdx.z] + (size_t)(k0 + kk) * ldb + bn + n4);
            }
        }
    };
    auto writeB = [&](short* Bs) {
        if constexpr (!TRB) {
            if constexpr (sizeof(TB) == 4) {
                #pragma unroll
                for (int p = 0; p < 2; ++p) {
                    int row = (t >> 3) + p * 32, c4 = (t & 7) * 4;
                    short4 s4 = make_short4(f2bf(rB[p].x), f2bf(rB[p].y),
                                            f2bf(rB[p].z), f2bf(rB[p].w));
                    *reinterpret_cast<short4*>(&Bs[row * 40 + c4]) = s4;
                }
            } else {
                *reinterpret_cast<short8*>(&Bs[(t >> 2) * 40 + (t & 3) * 8]) = rB16;
            }
        } else {
            #pragma unroll
            for (int p = 0; p < 2; ++p) {
                int kk = (t >> 4) + p * 16, n4 = (t & 15) * 4;
                float4 v = rB[p];
                if constexpr (SUMB) {
                    v.x += rB2[p].x; v.y += rB2[p].y; v.z += rB2[p].z; v.w += rB2[p].w;
                }
                Bs[(n4 + 0) * 40 + kk] = f2bf(v.x);
                Bs[(n4 + 1) * 40 + kk] = f2bf(v.y);
                Bs[(n4 + 2) * 40 + kk] = f2bf(v.z);
                Bs[(n4 + 3) * 40 + kk] = f2bf(v.w);
            }
        }
    };

    const int NS = K >> 5;
    loadA(0); loadB(0);
    writeA(0, AsB[0]); writeB(BsB[0]);
    loadA(32); loadB(32);
    __syncthreads();

    for (int s = 0; s < NS; ++s) {
        const bf16x8* Ap = reinterpret_cast<const bf16x8*>(AsB[s & 1]);
        const bf16x8* Bp = reinterpret_cast<const bf16x8*>(BsB[s & 1]);
        bf16x8 af[2], bfr[2];
        #pragma unroll
        for (int mi = 0; mi < 2; ++mi)
            af[mi] = Ap[(wm * 32 + mi * 16 + l15) * 5 + l4];
        #pragma unroll
        for (int ni = 0; ni < 2; ++ni)
            bfr[ni] = Bp[(wn * 32 + ni * 16 + l15) * 5 + l4];
        if (s + 1 < NS) { writeA((s + 1) * 32, AsB[(s + 1) & 1]); writeB(BsB[(s + 1) & 1]); }
        #pragma unroll
        for (int mi = 0; mi < 2; ++mi)
            #pragma unroll
            for (int ni = 0; ni < 2; ++ni)
                acc[mi][ni] = __builtin_amdgcn_mfma_f32_16x16x32_bf16(
                    af[mi], bfr[ni], acc[mi][ni], 0, 0, 0);
        if (s + 2 < NS) { loadA((s + 2) * 32); loadB((s + 2) * 32); }
        __syncthreads();
    }

    const float* bias = bp.bias[blockIdx.z];
    const float* add = bp.add[blockIdx.z];
    TC* __restrict__ C = (TC*)bp.C[blockIdx.z];
    #pragma unroll
    for (int mi = 0; mi < 2; ++mi) {
        #pragma unroll
        for (int ni = 0; ni < 2; ++ni) {
            int col = bn + wn * 32 + ni * 16 + l15;
            #pragma unroll
            for (int r = 0; r < 4; ++r) {
                int row = bm + wm * 32 + mi * 16 + l4 * 4 + r;
                float v = acc[mi][ni][r] * scale;
                if (EPI == 1) v += bias[col];
                if (EPI == 2) v = fmaxf(v + bias[col], 0.f);
                if (EPI == 3) {
                    float e = v > 0.f ? v : (__expf(v) - 1.f);
                    v = add[(size_t)row * ldc + col] + e;
                }
                if constexpr (sizeof(TC) == 4) C[(size_t)row * ldc + col] = v;
                else C[(size_t)row * ldc + col] = f2bf(v);
            }
        }
    }
}

// ---------------- P-GEMM with inline jmw (fast reductions), pipelined --------
__global__ __launch_bounds__(256) void pgemm_k(const float* __restrict__ H,
                                               const float* __restrict__ Gpart,
                                               const float* __restrict__ cmv,
                                               const float* __restrict__ rmv,
                                               const float* __restrict__ entv,
                                               float* __restrict__ Pbuf)
{
    __shared__ __align__(16) short AsB[2][64 * 40];
    __shared__ __align__(16) short BsB[2][64 * 40];
    __shared__ float red4[4];
    __shared__ float swv[256];
    const int t = threadIdx.x;

    {
        const int k = t;
        float e = entv[k];
        float esum = bsum1(e, red4);
        float jm = 0.5f * (esum * (1.f / 256.f) + e - (cmv[k] + rmv[k]) * (1.f / 256.f));
        float mean = bsum1(jm, red4) * (1.f / 256.f);
        float d = jm - mean;
        float var = bsum1(d * d, red4) * (1.f / 255.f);
        float v = d / (sqrtf(var) + 1e-6f);
        float mx = bmax1(v, red4);
        float ex = __expf(v - mx);
        float s = bsum1(ex, red4);
        swv[k] = ex / s;
        __syncthreads();
    }

    const int c = blockIdx.z;
    const int bm = blockIdx.y * 64, bn = blockIdx.x * 64;
    const int lane = t & 63;
    const int w = t >> 6, wm = w >> 1, wn = w & 1;
    const int l15 = lane & 15, l4 = lane >> 4;
    const float* __restrict__ B0 = Gpart + (size_t)(c * 2 + 0) * 131072;
    const float* __restrict__ B1 = Gpart + (size_t)(c * 2 + 1) * 131072;
    float* __restrict__ C = Pbuf + (size_t)c * 524288;

    f32x4 acc[2][2];
    #pragma unroll
    for (int i = 0; i < 2; ++i)
        #pragma unroll
        for (int j = 0; j < 2; ++j)
            #pragma unroll
            for (int r = 0; r < 4; ++r) acc[i][j][r] = 0.f;

    float4 rA[2], rB[2], rB2[2];
    auto loadA = [&](int k0) {
        #pragma unroll
        for (int p = 0; p < 2; ++p) {
            int row = (t >> 3) + p * 32, c4 = (t & 7) * 4;
            rA[p] = *reinterpret_cast<const float4*>(
                H + (size_t)(bm + row) * 256 + k0 + c4);
        }
    };
    auto writeA = [&](int k0, short* As) {
        #pragma unroll
        for (int p = 0; p < 2; ++p) {
            int row = (t >> 3) + p * 32, c4 = (t & 7) * 4;
            float4 v = rA[p];
            v.x *= swv[k0 + c4 + 0]; v.y *= swv[k0 + c4 + 1];
            v.z *= swv[k0 + c4 + 2]; v.w *= swv[k0 + c4 + 3];
            short4 s4 = make_short4(f2bf(v.x), f2bf(v.y), f2bf(v.z), f2bf(v.w));
            *reinterpret_cast<short4*>(&As[row * 40 + c4]) = s4;
        }
    };
    auto loadB = [&](int k0) {
        #pragma unroll
        for (int p = 0; p < 2; ++p) {
            int kk = (t >> 4) + p * 16, n4 = (t & 15) * 4;
            rB[p]  = *reinterpret_cast<const float4*>(B0 + (size_t)(k0 + kk) * 512 + bn + n4);
            rB2[p] = *reinterpret_cast<const float4*>(B1 + (size_t)(k0 + kk) * 512 + bn + n4);
        }
    };
    auto writeB = [&](short* Bs) {
        #pragma unroll
        for (int p = 0; p < 2; ++p) {
            int kk = (t >> 4) + p * 16, n4 = (t & 15) * 4;
            float4 v = rB[p];
            v.x += rB2[p].x; v.y += rB2[p].y; v.z += rB2[p].z; v.w += rB2[p].w;
            Bs[(n4 + 0) * 40 + kk] = f2bf(v.x);
            Bs[(n4 + 1) * 40 + kk] = f2bf(v.y);
            Bs[(n4 + 2) * 40 + kk] = f2bf(v.z);
            Bs[(n4 + 3) * 40 + kk] = f2bf(v.w);
        }
    };

    const int NS = 8;
    loadA(0); loadB(0);
    writeA(0, AsB[0]); writeB(BsB[0]);
    loadA(32); loadB(32);
    __syncthreads();

    for (int s = 0; s < NS; ++s) {
        const bf16x8* Ap = reinterpret_cast<const bf16x8*>(AsB[s & 1]);
        const bf16x8* Bp = reinterpret_cast<const bf16x8*>(BsB[s & 1]);
        bf16x8 af[2], bfr[2];
        #pragma unroll
        for (int mi = 0; mi < 2; ++mi)
            af[mi] = Ap[(wm * 32 + mi * 16 + l15) * 5 + l4];
        #pragma unroll
        for (int ni = 0; ni < 2; ++ni)
            bfr[ni] = Bp[(wn * 32 + ni * 16 + l15) * 5 + l4];
        if (s + 1 < NS) { writeA((s + 1) * 32, AsB[(s + 1) & 1]); writeB(BsB[(s + 1) & 1]); }
        #pragma unroll
        for (int mi = 0; mi < 2; ++mi)
            #pragma unroll
            for (int ni = 0; ni < 2; ++ni)
                acc[mi][ni] = __builtin_amdgcn_mfma_f32_16x16x32_bf16(
                    af[mi], bfr[ni], acc[mi][ni], 0, 0, 0);
        if (s + 2 < NS) { loadA((s + 2) * 32); loadB((s + 2) * 32); }
        __syncthreads();
    }

    #pragma unroll
    for (int mi = 0; mi < 2; ++mi)
        #pragma unroll
        for (int ni = 0; ni < 2; ++ni) {
            int col = bn + wn * 32 + ni * 16 + l15;
            #pragma unroll
            for (int r = 0; r < 4; ++r) {
                int row = bm + wm * 32 + mi * 16 + l4 * 4 + r;
                C[(size_t)row * 512 + col] = acc[mi][ni][r];
            }
        }
}

// ---------------- attention softmax + head-mean (fast reductions) -----------
__global__ __launch_bounds__(256) void softmax_mean_b(const short* __restrict__ S,
                                                      short* __restrict__ a)
{
    __shared__ float red[2][4];
    const int g = blockIdx.x, t = threadIdx.x;
    const int tag = g >> 10, row = g & 1023;
    const short* s0 = S + ((size_t)(tag * 2 + 0) << 20) + (size_t)row * 1024 + t * 4;
    const short* s1 = S + ((size_t)(tag * 2 + 1) << 20) + (size_t)row * 1024 + t * 4;

    short4 r0 = *reinterpret_cast<const short4*>(s0);
    short4 r1 = *reinterpret_cast<const short4*>(s1);
    float v0[4] = {bf2f(r0.x), bf2f(r0.y), bf2f(r0.z), bf2f(r0.w)};
    float v1[4] = {bf2f(r1.x), bf2f(r1.y), bf2f(r1.z), bf2f(r1.w)};

    float m0 = fmaxf(fmaxf(v0[0], v0[1]), fmaxf(v0[2], v0[3]));
    float m1 = fmaxf(fmaxf(v1[0], v1[1]), fmaxf(v1[2], v1[3]));
    bmax2(m0, m1, red);

    float e0[4], e1[4], sum0 = 0.f, sum1 = 0.f;
    #pragma unroll
    for (int j = 0; j < 4; ++j) {
        e0[j] = __expf(v0[j] - m0); sum0 += e0[j];
        e1[j] = __expf(v1[j] - m1); sum1 += e1[j];
    }
    bsum2(sum0, sum1, red);
    float i0 = 0.5f / sum0, i1 = 0.5f / sum1;

    short4 o;
    o.x = f2bf(e0[0] * i0 + e1[0] * i1);
    o.y = f2bf(e0[1] * i0 + e1[1] * i1);
    o.z = f2bf(e0[2] * i0 + e1[2] * i1);
    o.w = f2bf(e0[3] * i0 + e1[3] * i1);
    *reinterpret_cast<short4*>(a + ((size_t)tag << 20) + (size_t)row * 1024 + t * 4) = o;
}

// ---------------- column standardize + softmax (fast reductions) ------------
template<typename TOUT>
__global__ __launch_bounds__(256) void norm_softmax_b(const float* __restrict__ Zbase,
                                                      int zstride,
                                                      TOUT* __restrict__ Hout, int ldh,
                                                      int joffmul,
                                                      float* __restrict__ out2)
{
    __shared__ float red4[4];
    const int j = blockIdx.x, t = threadIdx.x;
    const float* Z = Zbase + (size_t)blockIdx.y * zstride;
    const int joff = blockIdx.y * joffmul;

    float x[4];
    #pragma unroll
    for (int i = 0; i < 4; ++i) x[i] = Z[(size_t)(t + i * 256) * 256 + j];

    float mean = bsum1(x[0] + x[1] + x[2] + x[3], red4) * (1.f / 1024.f);

    float ss = 0.f;
    #pragma unroll
    for (int i = 0; i < 4; ++i) { float d = x[i] - mean; ss += d * d; }
    float var = bsum1(ss, red4) * (1.f / 1023.f);
    float inv = 1.f / (sqrtf(var) + 1e-6f);

    float v[4];
    float mx = -3.4e38f;
    #pragma unroll
    for (int i = 0; i < 4; ++i) { v[i] = (x[i] - mean) * inv; mx = fmaxf(mx, v[i]); }
    mx = bmax1(mx, red4);

    float e[4], es = 0.f;
    #pragma unroll
    for (int i = 0; i < 4; ++i) { e[i] = __expf(v[i] - mx); es += e[i]; }
    es = bsum1(es, red4);
    float invs = 1.f / es;

    #pragma unroll
    for (int i = 0; i < 4; ++i) {
        float o = e[i] * invs;
        if constexpr (sizeof(TOUT) == 4)
            Hout[(size_t)(t + i * 256) * ldh + joff + j] = o;
        else
            Hout[(size_t)(t + i * 256) * ldh + joff + j] = f2bf(o);
        if (out2) out2[(size_t)(t + i * 256) * 256 + joff + j] = o;
    }
}

// ---------------- fused: jsd_part (0..1023) || pipelined G-GEMM (1024..1151) -
__global__ __launch_bounds__(256) void jsdg_k(const float* __restrict__ H,
                                              float* __restrict__ Cpart,
                                              const float* __restrict__ xt,
                                              const float* __restrict__ xn,
                                              float* __restrict__ Gpart)
{
    __shared__ __align__(16) short As[2][64 * 40];
    __shared__ __align__(16) short Bs[2][64 * 40];
    const int t = threadIdx.x;
    const int job = blockIdx.x;

    if (job < 1024) {
        float (*hj)[33] = (float(*)[33])&As[0][0];
        float (*hk)[33] = (float(*)[33])&Bs[0][0];
        const int tx = t & 15, ty = t >> 4;
        const int k0 = (job & 7) * 32, j0 = ((job >> 3) & 7) * 32;
        const int slab = job >> 6, nbase = slab * 64;
        float acc[2][2] = {};
        for (int c = 0; c < 8; ++c) {
            int n0 = nbase + c * 8;
            int nl = t >> 5, cc = t & 31;
            hj[nl][cc] = H[(size_t)(n0 + nl) * 256 + j0 + cc];
            hk[nl][cc] = H[(size_t)(n0 + nl) * 256 + k0 + cc];
            __syncthreads();
            #pragma unroll
            for (int nn = 0; nn < 8; ++nn) {
                float a0 = hj[nn][ty * 2], a1 = hj[nn][ty * 2 + 1];
                float b0 = hk[nn][tx * 2], b1 = hk[nn][tx * 2 + 1];
                acc[0][0] += a0 * __logf(0.5f * (a0 + b0));
                acc[0][1] += a0 * __logf(0.5f * (a0 + b1));
                acc[1][0] += a1 * __logf(0.5f * (a1 + b0));
                acc[1][1] += a1 * __logf(0.5f * (a1 + b1));
            }
            __syncthreads();
        }
        float* Cp = Cpart + (size_t)slab * 65536;
        #pragma unroll
        for (int i = 0; i < 2; ++i)
            #pragma unroll
            for (int jj = 0; jj < 2; ++jj)
                Cp[(size_t)(j0 + ty * 2 + i) * 256 + k0 + tx * 2 + jj] = acc[i][jj];
    } else {
        const int gg = job - 1024;
        const int z = gg >> 5, tile = gg & 31;
        const int chain = z >> 1, slab = z & 1;
        const float* A = H + (size_t)slab * 131072;
        const float* B = (chain ? xn : xt) + (size_t)slab * 262144;
        float* C = Gpart + (size_t)z * 131072;
        const int bm = (tile >> 3) * 64, bn = (tile & 7) * 64;
        const int lane = t & 63;
        const int w = t >> 6, wm = w >> 1, wn = w & 1;
        const int l15 = lane & 15, l4 = lane >> 4;

        f32x4 acc[2][2];
        #pragma unroll
        for (int i = 0; i < 2; ++i)
            #pragma unroll
            for (int j = 0; j < 2; ++j)
                #pragma unroll
                for (int r = 0; r < 4; ++r) acc[i][j][r] = 0.f;

        float4 rA[2], rB[2];
        auto loadAB = [&](int k0) {
            #pragma unroll
            for (int p = 0; p < 2; ++p) {
                int kk = (t >> 4) + p * 16;
                rA[p] = *reinterpret_cast<const float4*>(
                    A + (size_t)(k0 + kk) * 256 + bm + (t & 15) * 4);
                rB[p] = *reinterpret_cast<const float4*>(
                    B + (size_t)(k0 + kk) * 512 + bn + (t & 15) * 4);
            }
        };
        auto writeAB = [&](int buf) {
            #pragma unroll
            for (int p = 0; p < 2; ++p) {
                int kk = (t >> 4) + p * 16, m4 = (t & 15) * 4;
                As[buf][(m4 + 0) * 40 + kk] = f2bf(rA[p].x);
                As[buf][(m4 + 1) * 40 + kk] = f2bf(rA[p].y);
                As[buf][(m4 + 2) * 40 + kk] = f2bf(rA[p].z);
                As[buf][(m4 + 3) * 40 + kk] = f2bf(rA[p].w);
                Bs[buf][(m4 + 0) * 40 + kk] = f2bf(rB[p].x);
                Bs[buf][(m4 + 1) * 40 + kk] = f2bf(rB[p].y);
                Bs[buf][(m4 + 2) * 40 + kk] = f2bf(rB[p].z);
                Bs[buf][(m4 + 3) * 40 + kk] = f2bf(rB[p].w);
            }
        };

        const int NS = 16;
        loadAB(0); writeAB(0); loadAB(32);
        __syncthreads();

        for (int s = 0; s < NS; ++s) {
            const bf16x8* Ap = reinterpret_cast<const bf16x8*>(As[s & 1]);
            const bf16x8* Bp = reinterpret_cast<const bf16x8*>(Bs[s & 1]);
            bf16x8 af[2], bfr[2];
            #pragma unroll
            for (int mi = 0; mi < 2; ++mi)
                af[mi] = Ap[(wm * 32 + mi * 16 + l15) * 5 + l4];
            #pragma unroll
            for (int ni = 0; ni < 2; ++ni)
                bfr[ni] = Bp[(wn * 32 + ni * 16 + l15) * 5 + l4];
            if (s + 1 < NS) writeAB((s + 1) & 1);
            #pragma unroll
            for (int mi = 0; mi < 2; ++mi)
                #pragma unroll
                for (int ni = 0; ni < 2; ++ni)
                    acc[mi][ni] = __builtin_amdgcn_mfma_f32_16x16x32_bf16(
                        af[mi], bfr[ni], acc[mi][ni], 0, 0, 0);
            if (s + 2 < NS) loadAB((s + 2) * 32);
            __syncthreads();
        }

        #pragma unroll
        for (int mi = 0; mi < 2; ++mi)
            #pragma unroll
            for (int ni = 0; ni < 2; ++ni) {
                int col = bn + wn * 32 + ni * 16 + l15;
                #pragma unroll
                for (int r = 0; r < 4; ++r) {
                    int row = bm + wm * 32 + mi * 16 + l4 * 4 + r;
                    C[(size_t)row * 512 + col] = acc[mi][ni][r];
                }
            }
    }
}

// ---------------- per-k row/col sums over 16 slabs; ent[k] = diag(C) --------
__global__ __launch_bounds__(256) void rc_k(const float* __restrict__ Cpart,
                                            float* __restrict__ cmv,
                                            float* __restrict__ rmv,
                                            float* __restrict__ entv)
{
    __shared__ float red[2][4];
    const int k = blockIdx.x, j = threadIdx.x;
    float cm = 0.f, rm = 0.f;
    #pragma unroll
    for (int s = 0; s < 16; ++s) {
        cm += Cpart[(size_t)s * 65536 + (size_t)j * 256 + k];
        rm += Cpart[(size_t)s * 65536 + (size_t)k * 256 + j];
    }
    if (j == k) entv[k] = cm;
    bsum2(cm, rm, red);
    if (j == 0) { cmv[k] = cm; rmv[k] = rm; }
}

// ---------------- launch ----------------
extern "C" void kernel_launch(void* const* d_in, const int* in_sizes, int n_in,
                              void* d_out, int out_size, void* d_ws, size_t ws_size,
                              hipStream_t stream) {
    const float* x_time = (const float*)d_in[0];
    const float* x_news = (const float*)d_in[1];
    const float* f1w = (const float*)d_in[34];
    const float* f1b = (const float*)d_in[35];
    const float* f2w = (const float*)d_in[36];
    const float* f2b = (const float*)d_in[37];
    const float* theta_t = (const float*)d_in[38];
    const float* theta_n = (const float*)d_in[39];
    float* out = (float*)d_out;

    float* ws = (float*)d_ws;
    short* s_qk = (short*)ws;
    short* s_a  = (short*)ws;
    short* s_Hc = (short*)ws;
    short* s_S    = (short*)(ws + 2097152);
    float* zpart  = ws + 2097152;
    float* z2b    = ws + 4718592;
    float* Cpartf = ws + 2097152;
    float* z2f    = z2b;
    float* Cpart  = ws + 2097152;
    float* entv   = ws + 3145728;
    float* cmv    = entv + 256;
    float* rmv    = cmv + 256;
    float* Gpart  = ws + 3407872;
    float* Pbuf   = ws + 4194304;
    float* Hbuf   = ws + 6291456;

    const float* qsrc[4]  = {x_time, x_news, x_time, x_news};
    const float* kvsrc[4] = {x_time, x_news, x_news, x_time};
    const int    base[4]  = {2, 10, 18, 26};

    Batch8 bp{};

    // ======== projections: z=8 ========
    for (int tg = 0; tg < 4; ++tg) {
        bp.A[tg] = qsrc[tg];      bp.B[tg] = d_in[base[tg] + 0];
        bp.bias[tg] = (const float*)d_in[base[tg] + 2];
        bp.C[tg] = s_qk + (size_t)tg * 524288;
        bp.A[4 + tg] = kvsrc[tg]; bp.B[4 + tg] = d_in[base[tg] + 1];
        bp.bias[4 + tg] = (const float*)d_in[base[tg] + 3];
        bp.C[4 + tg] = s_qk + (size_t)(4 + tg) * 524288;
    }
    gemm_big_k<float, float, 1>
        <<<dim3(4, 8, 8), 256, 0, stream>>>(bp, 512, 512, 512, 512, 1.f);

    // ======== scores: z=8, scale 1/16 ========
    for (int i = 0; i < 8; ++i) {
        int tg = i >> 1, h = i & 1;
        bp.A[i] = s_qk + (size_t)tg * 524288 + h * 256;
        bp.B[i] = s_qk + (size_t)(4 + tg) * 524288 + h * 256;
        bp.bias[i] = nullptr;
        bp.C[i] = s_S + ((size_t)i << 20);
    }
    gemm_big_k<short, short, 0>
        <<<dim3(8, 8, 8), 256, 0, stream>>>(bp, 512, 512, 1024, 256, 0.0625f);

    // ======== softmax + head mean -> a ========
    softmax_mean_b<<<4096, 256, 0, stream>>>(s_S, s_a);

    // ======== incidence MLP1: split-K z=8 -> zpart fp32 ========
    for (int i = 0; i < 8; ++i) {
        int tg = i >> 1, hf = i & 1;
        bp.A[i] = s_a + ((size_t)tg << 20) + hf * 512;
        bp.B[i] = (const float*)d_in[base[tg] + 4] + hf * 512;
        bp.bias[i] = nullptr;
        bp.C[i] = zpart + (size_t)i * 262144;
    }
    gemm_b_k<short, float, float, false, false, 0>
        <<<dim3(4, 16, 8), 256, 0, stream>>>(bp, 1024, 1024, 256, 512, 1.f);

    // ======== incidence MLP2 z=4 (APART=2) ========
    for (int tg = 0; tg < 4; ++tg) {
        bp.A[tg] = zpart + (size_t)tg * 2 * 262144;
        bp.biasA[tg] = (const float*)d_in[base[tg] + 5];
        bp.B[tg] = d_in[base[tg] + 6];
        bp.bias[tg] = (const float*)d_in[base[tg] + 7];
        bp.C[tg] = z2b + (size_t)tg * 262144;
    }
    gemm_b_k<float, float, float, false, false, 1, false, false, 2>
        <<<dim3(4, 16, 4), 256, 0, stream>>>(bp, 256, 256, 256, 256, 1.f);

    // norm_softmax over 4 tags -> Hcat (bf16)
    norm_softmax_b<short><<<dim3(256, 4), 256, 0, stream>>>(z2b, 262144, s_Hc, 1024, 256, nullptr);

    // ======== fusion MLP1 split-K z=4 -> Cpartf ========
    for (int z = 0; z < 4; ++z) {
        bp.A[z] = s_Hc + z * 256;
        bp.B[z] = f1w + z * 256;
        bp.bias[z] = nullptr;
        bp.C[z] = Cpartf + (size_t)z * 262144;
    }
    gemm_b_k<short, float, float, false, false, 0>
        <<<dim3(4, 16, 4), 256, 0, stream>>>(bp, 1024, 1024, 256, 256, 1.f);

    // ======== fusion MLP2 (APART=4) ========
    bp.A[0] = Cpartf; bp.biasA[0] = f1b; bp.B[0] = f2w; bp.bias[0] = f2b; bp.C[0] = z2f;
    gemm_b_k<float, float, float, false, false, 1, false, false, 4>
        <<<dim3(4, 16, 1), 256, 0, stream>>>(bp, 256, 256, 256, 256, 1.f);
    norm_softmax_b<float><<<dim3(256, 1), 256, 0, stream>>>(z2f, 0, Hbuf, 256, 0,
                                                            out + 1048576);

    // ======== JSD || G-GEMM (fused) ========
    jsdg_k<<<1152, 256, 0, stream>>>(Hbuf, Cpart, x_time, x_news, Gpart);
    rc_k<<<256, 256, 0, stream>>>(Cpart, cmv, rmv, entv);

    // ======== P = (H*w)(G0+G1) with inline jmw ========
    pgemm_k<<<dim3(8, 16, 2), 256, 0, stream>>>(Hbuf, Gpart, cmv, rmv, entv, Pbuf);

    // ======== out = x + elu(P theta) ========
    const float* xc[2] = {x_time, x_news};
    const float* th[2] = {theta_t, theta_n};
    for (int c = 0; c < 2; ++c) {
        bp.A[c] = Pbuf + (size_t)c * 524288;
        bp.B[c] = th[c];
        bp.bias[c] = nullptr;
        bp.add[c] = xc[c];
        bp.C[c] = out + (size_t)c * 524288;
    }
    gemm_b_k<float, float, float, false, true, 3>
        <<<dim3(8, 16, 2), 256, 0, stream>>>(bp, 512, 512, 512, 512, 1.f);
}

// Round 14
// 171.013 us; speedup vs baseline: 5.8781x; 1.0668x over previous
//
#include <hip/hip_runtime.h>
#include <hip/hip_bf16.h>
#include <math.h>

typedef __attribute__((ext_vector_type(8))) short bf16x8;
typedef __attribute__((ext_vector_type(8))) short short8;
typedef __attribute__((ext_vector_type(4))) float f32x4;

__device__ __forceinline__ short f2bf(float f) {
    unsigned u = __float_as_uint(f);
    u += 0x7fffu + ((u >> 16) & 1u);
    return (short)(u >> 16);
}
__device__ __forceinline__ float bf2f(short s) {
    return __uint_as_float(((unsigned)(unsigned short)s) << 16);
}

// ---------------- fast reductions: wave shfl + 4-entry LDS combine ----------
__device__ __forceinline__ float wsum(float v) {
    #pragma unroll
    for (int off = 32; off >= 1; off >>= 1) v += __shfl_xor(v, off);
    return v;
}
__device__ __forceinline__ float wmax(float v) {
    #pragma unroll
    for (int off = 32; off >= 1; off >>= 1) v = fmaxf(v, __shfl_xor(v, off));
    return v;
}
__device__ __forceinline__ float bsum1(float v, float* red4) {
    v = wsum(v);
    if ((threadIdx.x & 63) == 0) red4[threadIdx.x >> 6] = v;
    __syncthreads();
    float r = red4[0] + red4[1] + red4[2] + red4[3];
    __syncthreads();
    return r;
}
__device__ __forceinline__ float bmax1(float v, float* red4) {
    v = wmax(v);
    if ((threadIdx.x & 63) == 0) red4[threadIdx.x >> 6] = v;
    __syncthreads();
    float r = fmaxf(fmaxf(red4[0], red4[1]), fmaxf(red4[2], red4[3]));
    __syncthreads();
    return r;
}
__device__ __forceinline__ void bsum2(float& a, float& b, float (*red)[4]) {
    a = wsum(a); b = wsum(b);
    int wv = threadIdx.x >> 6;
    if ((threadIdx.x & 63) == 0) { red[0][wv] = a; red[1][wv] = b; }
    __syncthreads();
    a = red[0][0] + red[0][1] + red[0][2] + red[0][3];
    b = red[1][0] + red[1][1] + red[1][2] + red[1][3];
    __syncthreads();
}
__device__ __forceinline__ void bmax2(float& a, float& b, float (*red)[4]) {
    a = wmax(a); b = wmax(b);
    int wv = threadIdx.x >> 6;
    if ((threadIdx.x & 63) == 0) { red[0][wv] = a; red[1][wv] = b; }
    __syncthreads();
    a = fmaxf(fmaxf(red[0][0], red[0][1]), fmaxf(red[0][2], red[0][3]));
    b = fmaxf(fmaxf(red[1][0], red[1][1]), fmaxf(red[1][2], red[1][3]));
    __syncthreads();
}

struct Batch8 {
    const void* A[8];
    const void* B[8];
    const float* bias[8];
    const float* biasA[8];
    const float* add[8];
    void* C[8];
};

// ---------------- prep: fp32 -> bf16 casts (22 segments, 2048 elems/block) ---
struct PrepArgs {
    const float* src[22];
    short* dst[22];
    int bstart[23];
};
__global__ __launch_bounds__(256) void prep_k(PrepArgs pa)
{
    const int bid = blockIdx.x, t = threadIdx.x;
    int seg = 0;
    while (pa.bstart[seg + 1] <= bid) ++seg;
    int idx = (bid - pa.bstart[seg]) * 2048 + t * 8;
    const float4 v0 = *reinterpret_cast<const float4*>(pa.src[seg] + idx);
    const float4 v1 = *reinterpret_cast<const float4*>(pa.src[seg] + idx + 4);
    short8 o;
    o[0] = f2bf(v0.x); o[1] = f2bf(v0.y); o[2] = f2bf(v0.z); o[3] = f2bf(v0.w);
    o[4] = f2bf(v1.x); o[5] = f2bf(v1.y); o[6] = f2bf(v1.z); o[7] = f2bf(v1.w);
    *reinterpret_cast<short8*>(pa.dst[seg] + idx) = o;
}

// ---------------- BIG 128x128 MFMA GEMM, double-buffered pipeline ----------
template<typename TA, typename TB, int EPI>
__global__ __launch_bounds__(256) void gemm_big_k(Batch8 bp, int lda, int ldb, int ldc,
                                                  int K, float scale)
{
    __shared__ __align__(16) short AsB[2][128 * 40];
    __shared__ __align__(16) short BsB[2][128 * 40];
    const int t = threadIdx.x;
    const int lane = t & 63;
    const int w = t >> 6, wm = w >> 1, wn = w & 1;
    const int bm = blockIdx.y * 128, bn = blockIdx.x * 128;
    const int l15 = lane & 15, l4 = lane >> 4;
    const TA* __restrict__ A = (const TA*)bp.A[blockIdx.z];
    const TB* __restrict__ B = (const TB*)bp.B[blockIdx.z];

    f32x4 acc[4][4];
    #pragma unroll
    for (int i = 0; i < 4; ++i)
        #pragma unroll
        for (int j = 0; j < 4; ++j)
            #pragma unroll
            for (int r = 0; r < 4; ++r) acc[i][j][r] = 0.f;

    float4 rA[4]; short8 rA16[2];
    float4 rB[4]; short8 rB16[2];

    auto loadA = [&](int k0) {
        if constexpr (sizeof(TA) == 4) {
            #pragma unroll
            for (int p = 0; p < 4; ++p) {
                int row = (t >> 3) + p * 32, c4 = (t & 7) * 4;
                rA[p] = *reinterpret_cast<const float4*>(
                    A + (size_t)(bm + row) * lda + k0 + c4);
            }
        } else {
            #pragma unroll
            for (int p = 0; p < 2; ++p) {
                int row = (t >> 2) + p * 64, c8 = (t & 3) * 8;
                rA16[p] = *reinterpret_cast<const short8*>(
                    A + (size_t)(bm + row) * lda + k0 + c8);
            }
        }
    };
    auto writeA = [&](short* As) {
        if constexpr (sizeof(TA) == 4) {
            #pragma unroll
            for (int p = 0; p < 4; ++p) {
                int row = (t >> 3) + p * 32, c4 = (t & 7) * 4;
                short4 s4 = make_short4(f2bf(rA[p].x), f2bf(rA[p].y),
                                        f2bf(rA[p].z), f2bf(rA[p].w));
                *reinterpret_cast<short4*>(&As[row * 40 + c4]) = s4;
            }
        } else {
            #pragma unroll
            for (int p = 0; p < 2; ++p) {
                int row = (t >> 2) + p * 64, c8 = (t & 3) * 8;
                *reinterpret_cast<short8*>(&As[row * 40 + c8]) = rA16[p];
            }
        }
    };
    auto loadB = [&](int k0) {
        if constexpr (sizeof(TB) == 4) {
            #pragma unroll
            for (int p = 0; p < 4; ++p) {
                int row = (t >> 3) + p * 32, c4 = (t & 7) * 4;
                rB[p] = *reinterpret_cast<const float4*>(
                    B + (size_t)(bn + row) * ldb + k0 + c4);
            }
        } else {
            #pragma unroll
            for (int p = 0; p < 2; ++p) {
                int row = (t >> 2) + p * 64, c8 = (t & 3) * 8;
                rB16[p] = *reinterpret_cast<const short8*>(
                    B + (size_t)(bn + row) * ldb + k0 + c8);
            }
        }
    };
    auto writeB = [&](short* Bs) {
        if constexpr (sizeof(TB) == 4) {
            #pragma unroll
            for (int p = 0; p < 4; ++p) {
                int row = (t >> 3) + p * 32, c4 = (t & 7) * 4;
                short4 s4 = make_short4(f2bf(rB[p].x), f2bf(rB[p].y),
                                        f2bf(rB[p].z), f2bf(rB[p].w));
                *reinterpret_cast<short4*>(&Bs[row * 40 + c4]) = s4;
            }
        } else {
            #pragma unroll
            for (int p = 0; p < 2; ++p) {
                int row = (t >> 2) + p * 64, c8 = (t & 3) * 8;
                *reinterpret_cast<short8*>(&Bs[row * 40 + c8]) = rB16[p];
            }
        }
    };

    const int NS = K >> 5;
    loadA(0); loadB(0);
    writeA(AsB[0]); writeB(BsB[0]);
    loadA(32); loadB(32);
    __syncthreads();

    for (int s = 0; s < NS; ++s) {
        const bf16x8* Ap = reinterpret_cast<const bf16x8*>(AsB[s & 1]);
        const bf16x8* Bp = reinterpret_cast<const bf16x8*>(BsB[s & 1]);
        bf16x8 af[4], bfr[4];
        #pragma unroll
        for (int mi = 0; mi < 4; ++mi)
            af[mi] = Ap[(wm * 64 + mi * 16 + l15) * 5 + l4];
        #pragma unroll
        for (int ni = 0; ni < 4; ++ni)
            bfr[ni] = Bp[(wn * 64 + ni * 16 + l15) * 5 + l4];
        if (s + 1 < NS) { writeA(AsB[(s + 1) & 1]); writeB(BsB[(s + 1) & 1]); }
        #pragma unroll
        for (int mi = 0; mi < 4; ++mi)
            #pragma unroll
            for (int ni = 0; ni < 4; ++ni)
                acc[mi][ni] = __builtin_amdgcn_mfma_f32_16x16x32_bf16(
                    af[mi], bfr[ni], acc[mi][ni], 0, 0, 0);
        if (s + 2 < NS) { loadA((s + 2) * 32); loadB((s + 2) * 32); }
        __syncthreads();
    }

    const float* bias = bp.bias[blockIdx.z];
    short* __restrict__ C = (short*)bp.C[blockIdx.z];
    #pragma unroll
    for (int mi = 0; mi < 4; ++mi) {
        #pragma unroll
        for (int ni = 0; ni < 4; ++ni) {
            int col = bn + wn * 64 + ni * 16 + l15;
            #pragma unroll
            for (int r = 0; r < 4; ++r) {
                int row = bm + wm * 64 + mi * 16 + l4 * 4 + r;
                float v = acc[mi][ni][r] * scale;
                if (EPI == 1) v += bias[col];
                C[(size_t)row * ldc + col] = f2bf(v);
            }
        }
    }
}

// ---------------- 64x64 batched MFMA GEMM, double-buffered pipeline ----------
// EPI: 0 none, 1 +bias, 2 +bias+relu, 3 out = add + elu(v)
// APART(N): A = relu(sum_{j<N} Apart[j] + biasA[k]) (fp32, slab stride 262144).
// TRB supports fp32 (with optional SUMB) and bf16.
template<typename TA, typename TB, typename TC, bool TRA, bool TRB, int EPI,
         bool WS = false, bool SUMB = false, int APART = 0>
__global__ __launch_bounds__(256) void gemm_b_k(Batch8 bp, int lda, int ldb, int ldc,
                                                int K, float scale,
                                                const float* __restrict__ wsc = nullptr)
{
    __shared__ __align__(16) short AsB[2][64 * 40];
    __shared__ __align__(16) short BsB[2][64 * 40];
    const int t = threadIdx.x;
    const int lane = t & 63;
    const int w = t >> 6, wm = w >> 1, wn = w & 1;
    const int bm = blockIdx.y * 64, bn = blockIdx.x * 64;
    const int l15 = lane & 15, l4 = lane >> 4;
    const TA* __restrict__ A = (const TA*)bp.A[blockIdx.z];
    const TB* __restrict__ B = (const TB*)bp.B[blockIdx.z];

    f32x4 acc[2][2];
    #pragma unroll
    for (int i = 0; i < 2; ++i)
        #pragma unroll
        for (int j = 0; j < 2; ++j)
            #pragma unroll
            for (int r = 0; r < 4; ++r) acc[i][j][r] = 0.f;

    float4 rA[2][APART > 0 ? APART : 1];
    short8 rA16;
    float4 rB[2], rB2[2];
    short8 rB16;
    short4 rBs[2];

    auto loadA = [&](int k0) {
        if constexpr (APART > 0) {
            #pragma unroll
            for (int p = 0; p < 2; ++p) {
                int row = (t >> 3) + p * 32, c4 = (t & 7) * 4;
                const float* basep = (const float*)A + (size_t)(bm + row) * lda + k0 + c4;
                #pragma unroll
                for (int j = 0; j < APART; ++j)
                    rA[p][j] = *reinterpret_cast<const float4*>(basep + (size_t)j * 262144);
            }
        } else if constexpr (!TRA) {
            if constexpr (sizeof(TA) == 4) {
                #pragma unroll
                for (int p = 0; p < 2; ++p) {
                    int row = (t >> 3) + p * 32, c4 = (t & 7) * 4;
                    rA[p][0] = *reinterpret_cast<const float4*>(
                        A + (size_t)(bm + row) * lda + k0 + c4);
                }
            } else {
                rA16 = *reinterpret_cast<const short8*>(
                    A + (size_t)(bm + (t >> 2)) * lda + k0 + (t & 3) * 8);
            }
        } else {
            #pragma unroll
            for (int p = 0; p < 2; ++p) {
                int kk = (t >> 4) + p * 16, m4 = (t & 15) * 4;
                rA[p][0] = *reinterpret_cast<const float4*>(
                    (const float*)A + (size_t)(k0 + kk) * lda + bm + m4);
            }
        }
    };
    auto writeA = [&](int k0, short* As) {
        if constexpr (APART > 0) {
            const float* ba = bp.biasA[blockIdx.z];
            #pragma unroll
            for (int p = 0; p < 2; ++p) {
                int row = (t >> 3) + p * 32, c4 = (t & 7) * 4;
                float4 v = rA[p][0];
                #pragma unroll
                for (int j = 1; j < APART; ++j) {
                    v.x += rA[p][j].x; v.y += rA[p][j].y;
                    v.z += rA[p][j].z; v.w += rA[p][j].w;
                }
                v.x = fmaxf(v.x + ba[k0 + c4 + 0], 0.f);
                v.y = fmaxf(v.y + ba[k0 + c4 + 1], 0.f);
                v.z = fmaxf(v.z + ba[k0 + c4 + 2], 0.f);
                v.w = fmaxf(v.w + ba[k0 + c4 + 3], 0.f);
                short4 s4 = make_short4(f2bf(v.x), f2bf(v.y), f2bf(v.z), f2bf(v.w));
                *reinterpret_cast<short4*>(&As[row * 40 + c4]) = s4;
            }
        } else if constexpr (!TRA) {
            if constexpr (sizeof(TA) == 4) {
                #pragma unroll
                for (int p = 0; p < 2; ++p) {
                    int row = (t >> 3) + p * 32, c4 = (t & 7) * 4;
                    float4 v = rA[p][0];
                    if constexpr (WS) {
                        v.x *= wsc[k0 + c4 + 0]; v.y *= wsc[k0 + c4 + 1];
                        v.z *= wsc[k0 + c4 + 2]; v.w *= wsc[k0 + c4 + 3];
                    }
                    short4 s4 = make_short4(f2bf(v.x), f2bf(v.y), f2bf(v.z), f2bf(v.w));
                    *reinterpret_cast<short4*>(&As[row * 40 + c4]) = s4;
                }
            } else {
                *reinterpret_cast<short8*>(&As[(t >> 2) * 40 + (t & 3) * 8]) = rA16;
            }
        } else {
            #pragma unroll
            for (int p = 0; p < 2; ++p) {
                int kk = (t >> 4) + p * 16, m4 = (t & 15) * 4;
                As[(m4 + 0) * 40 + kk] = f2bf(rA[p][0].x);
                As[(m4 + 1) * 40 + kk] = f2bf(rA[p][0].y);
                As[(m4 + 2) * 40 + kk] = f2bf(rA[p][0].z);
                As[(m4 + 3) * 40 + kk] = f2bf(rA[p][0].w);
            }
        }
    };
    auto loadB = [&](int k0) {
        if constexpr (!TRB) {
            if constexpr (sizeof(TB) == 4) {
                #pragma unroll
                for (int p = 0; p < 2; ++p) {
                    int row = (t >> 3) + p * 32, c4 = (t & 7) * 4;
                    rB[p] = *reinterpret_cast<const float4*>(
                        B + (size_t)(bn + row) * ldb + k0 + c4);
                }
            } else {
                rB16 = *reinterpret_cast<const short8*>(
                    B + (size_t)(bn + (t >> 2)) * ldb + k0 + (t & 3) * 8);
            }
        } else {
            if constexpr (sizeof(TB) == 4) {
                #pragma unroll
                for (int p = 0; p < 2; ++p) {
                    int kk = (t >> 4) + p * 16, n4 = (t & 15) * 4;
                    rB[p] = *reinterpret_cast<const float4*>(
                        (const float*)B + (size_t)(k0 + kk) * ldb + bn + n4);
                    if constexpr (SUMB)
                        rB2[p] = *reinterpret_cast<const float4*>(
                            (const float*)bp.add[blockIdx.z] + (size_t)(k0 + kk) * ldb + bn + n4);
                }
            } else {
                #pragma unroll
                for (int p = 0; p < 2; ++p) {
                    int kk = (t >> 4) + p * 16, n4 = (t & 15) * 4;
                    rBs[p] = *reinterpret_cast<const short4*>(
                        (const short*)B + (size_t)(k0 + kk) * ldb + bn + n4);
                }
            }
        }
    };
    auto writeB = [&](short* Bs) {
        if constexpr (!TRB) {
            if constexpr (sizeof(TB) == 4) {
                #pragma unroll
                for (int p = 0; p < 2; ++p) {
                    int row = (t >> 3) + p * 32, c4 = (t & 7) * 4;
                    short4 s4 = make_short4(f2bf(rB[p].x), f2bf(rB[p].y),
                                            f2bf(rB[p].z), f2bf(rB[p].w));
                    *reinterpret_cast<short4*>(&Bs[row * 40 + c4]) = s4;
                }
            } else {
                *reinterpret_cast<short8*>(&Bs[(t >> 2) * 40 + (t & 3) * 8]) = rB16;
            }
        } else {
            if constexpr (sizeof(TB) == 4) {
                #pragma unroll
                for (int p = 0; p < 2; ++p) {
                    int kk = (t >> 4) + p * 16, n4 = (t & 15) * 4;
                    float4 v = rB[p];
                    if constexpr (SUMB) {
                        v.x += rB2[p].x; v.y += rB2[p].y; v.z += rB2[p].z; v.w += rB2[p].w;
                    }
                    Bs[(n4 + 0) * 40 + kk] = f2bf(v.x);
                    Bs[(n4 + 1) * 40 + kk] = f2bf(v.y);
                    Bs[(n4 + 2) * 40 + kk] = f2bf(v.z);
                    Bs[(n4 + 3) * 40 + kk] = f2bf(v.w);
                }
            } else {
                #pragma unroll
                for (int p = 0; p < 2; ++p) {
                    int kk = (t >> 4) + p * 16, n4 = (t & 15) * 4;
                    Bs[(n4 + 0) * 40 + kk] = rBs[p].x;
                    Bs[(n4 + 1) * 40 + kk] = rBs[p].y;
                    Bs[(n4 + 2) * 40 + kk] = rBs[p].z;
                    Bs[(n4 + 3) * 40 + kk] = rBs[p].w;
                }
            }
        }
    };

    const int NS = K >> 5;
    loadA(0); loadB(0);
    writeA(0, AsB[0]); writeB(BsB[0]);
    loadA(32); loadB(32);
    __syncthreads();

    for (int s = 0; s < NS; ++s) {
        const bf16x8* Ap = reinterpret_cast<const bf16x8*>(AsB[s & 1]);
        const bf16x8* Bp = reinterpret_cast<const bf16x8*>(BsB[s & 1]);
        bf16x8 af[2], bfr[2];
        #pragma unroll
        for (int mi = 0; mi < 2; ++mi)
            af[mi] = Ap[(wm * 32 + mi * 16 + l15) * 5 + l4];
        #pragma unroll
        for (int ni = 0; ni < 2; ++ni)
            bfr[ni] = Bp[(wn * 32 + ni * 16 + l15) * 5 + l4];
        if (s + 1 < NS) { writeA((s + 1) * 32, AsB[(s + 1) & 1]); writeB(BsB[(s + 1) & 1]); }
        #pragma unroll
        for (int mi = 0; mi < 2; ++mi)
            #pragma unroll
            for (int ni = 0; ni < 2; ++ni)
                acc[mi][ni] = __builtin_amdgcn_mfma_f32_16x16x32_bf16(
                    af[mi], bfr[ni], acc[mi][ni], 0, 0, 0);
        if (s + 2 < NS) { loadA((s + 2) * 32); loadB((s + 2) * 32); }
        __syncthreads();
    }

    const float* bias = bp.bias[blockIdx.z];
    const float* add = bp.add[blockIdx.z];
    TC* __restrict__ C = (TC*)bp.C[blockIdx.z];
    #pragma unroll
    for (int mi = 0; mi < 2; ++mi) {
        #pragma unroll
        for (int ni = 0; ni < 2; ++ni) {
            int col = bn + wn * 32 + ni * 16 + l15;
            #pragma unroll
            for (int r = 0; r < 4; ++r) {
                int row = bm + wm * 32 + mi * 16 + l4 * 4 + r;
                float v = acc[mi][ni][r] * scale;
                if (EPI == 1) v += bias[col];
                if (EPI == 2) v = fmaxf(v + bias[col], 0.f);
                if (EPI == 3) {
                    float e = v > 0.f ? v : (__expf(v) - 1.f);
                    v = add[(size_t)row * ldc + col] + e;
                }
                if constexpr (sizeof(TC) == 4) C[(size_t)row * ldc + col] = v;
                else C[(size_t)row * ldc + col] = f2bf(v);
            }
        }
    }
}

// ---------------- P-GEMM with inline jmw, pipelined; P out bf16 -------------
__global__ __launch_bounds__(256) void pgemm_k(const float* __restrict__ H,
                                               const float* __restrict__ Gpart,
                                               const float* __restrict__ cmv,
                                               const float* __restrict__ rmv,
                                               const float* __restrict__ entv,
                                               short* __restrict__ Pbuf)
{
    __shared__ __align__(16) short AsB[2][64 * 40];
    __shared__ __align__(16) short BsB[2][64 * 40];
    __shared__ float red4[4];
    __shared__ float swv[256];
    const int t = threadIdx.x;

    {
        const int k = t;
        float e = entv[k];
        float esum = bsum1(e, red4);
        float jm = 0.5f * (esum * (1.f / 256.f) + e - (cmv[k] + rmv[k]) * (1.f / 256.f));
        float mean = bsum1(jm, red4) * (1.f / 256.f);
        float d = jm - mean;
        float var = bsum1(d * d, red4) * (1.f / 255.f);
        float v = d / (sqrtf(var) + 1e-6f);
        float mx = bmax1(v, red4);
        float ex = __expf(v - mx);
        float s = bsum1(ex, red4);
        swv[k] = ex / s;
        __syncthreads();
    }

    const int c = blockIdx.z;
    const int bm = blockIdx.y * 64, bn = blockIdx.x * 64;
    const int lane = t & 63;
    const int w = t >> 6, wm = w >> 1, wn = w & 1;
    const int l15 = lane & 15, l4 = lane >> 4;
    const float* __restrict__ B0 = Gpart + (size_t)(c * 2 + 0) * 131072;
    const float* __restrict__ B1 = Gpart + (size_t)(c * 2 + 1) * 131072;
    short* __restrict__ C = Pbuf + (size_t)c * 524288;

    f32x4 acc[2][2];
    #pragma unroll
    for (int i = 0; i < 2; ++i)
        #pragma unroll
        for (int j = 0; j < 2; ++j)
            #pragma unroll
            for (int r = 0; r < 4; ++r) acc[i][j][r] = 0.f;

    float4 rA[2], rB[2], rB2[2];
    auto loadA = [&](int k0) {
        #pragma unroll
        for (int p = 0; p < 2; ++p) {
            int row = (t >> 3) + p * 32, c4 = (t & 7) * 4;
            rA[p] = *reinterpret_cast<const float4*>(
                H + (size_t)(bm + row) * 256 + k0 + c4);
        }
    };
    auto writeA = [&](int k0, short* As) {
        #pragma unroll
        for (int p = 0; p < 2; ++p) {
            int row = (t >> 3) + p * 32, c4 = (t & 7) * 4;
            float4 v = rA[p];
            v.x *= swv[k0 + c4 + 0]; v.y *= swv[k0 + c4 + 1];
            v.z *= swv[k0 + c4 + 2]; v.w *= swv[k0 + c4 + 3];
            short4 s4 = make_short4(f2bf(v.x), f2bf(v.y), f2bf(v.z), f2bf(v.w));
            *reinterpret_cast<short4*>(&As[row * 40 + c4]) = s4;
        }
    };
    auto loadB = [&](int k0) {
        #pragma unroll
        for (int p = 0; p < 2; ++p) {
            int kk = (t >> 4) + p * 16, n4 = (t & 15) * 4;
            rB[p]  = *reinterpret_cast<const float4*>(B0 + (size_t)(k0 + kk) * 512 + bn + n4);
            rB2[p] = *reinterpret_cast<const float4*>(B1 + (size_t)(k0 + kk) * 512 + bn + n4);
        }
    };
    auto writeB = [&](short* Bs) {
        #pragma unroll
        for (int p = 0; p < 2; ++p) {
            int kk = (t >> 4) + p * 16, n4 = (t & 15) * 4;
            float4 v = rB[p];
            v.x += rB2[p].x; v.y += rB2[p].y; v.z += rB2[p].z; v.w += rB2[p].w;
            Bs[(n4 + 0) * 40 + kk] = f2bf(v.x);
            Bs[(n4 + 1) * 40 + kk] = f2bf(v.y);
            Bs[(n4 + 2) * 40 + kk] = f2bf(v.z);
            Bs[(n4 + 3) * 40 + kk] = f2bf(v.w);
        }
    };

    const int NS = 8;
    loadA(0); loadB(0);
    writeA(0, AsB[0]); writeB(BsB[0]);
    loadA(32); loadB(32);
    __syncthreads();

    for (int s = 0; s < NS; ++s) {
        const bf16x8* Ap = reinterpret_cast<const bf16x8*>(AsB[s & 1]);
        const bf16x8* Bp = reinterpret_cast<const bf16x8*>(BsB[s & 1]);
        bf16x8 af[2], bfr[2];
        #pragma unroll
        for (int mi = 0; mi < 2; ++mi)
            af[mi] = Ap[(wm * 32 + mi * 16 + l15) * 5 + l4];
        #pragma unroll
        for (int ni = 0; ni < 2; ++ni)
            bfr[ni] = Bp[(wn * 32 + ni * 16 + l15) * 5 + l4];
        if (s + 1 < NS) { writeA((s + 1) * 32, AsB[(s + 1) & 1]); writeB(BsB[(s + 1) & 1]); }
        #pragma unroll
        for (int mi = 0; mi < 2; ++mi)
            #pragma unroll
            for (int ni = 0; ni < 2; ++ni)
                acc[mi][ni] = __builtin_amdgcn_mfma_f32_16x16x32_bf16(
                    af[mi], bfr[ni], acc[mi][ni], 0, 0, 0);
        if (s + 2 < NS) { loadA((s + 2) * 32); loadB((s + 2) * 32); }
        __syncthreads();
    }

    #pragma unroll
    for (int mi = 0; mi < 2; ++mi)
        #pragma unroll
        for (int ni = 0; ni < 2; ++ni) {
            int col = bn + wn * 32 + ni * 16 + l15;
            #pragma unroll
            for (int r = 0; r < 4; ++r) {
                int row = bm + wm * 32 + mi * 16 + l4 * 4 + r;
                C[(size_t)row * 512 + col] = f2bf(acc[mi][ni][r]);
            }
        }
}

// ---------------- attention softmax + head-mean (fast reductions) -----------
__global__ __launch_bounds__(256) void softmax_mean_b(const short* __restrict__ S,
                                                      short* __restrict__ a)
{
    __shared__ float red[2][4];
    const int g = blockIdx.x, t = threadIdx.x;
    const int tag = g >> 10, row = g & 1023;
    const short* s0 = S + ((size_t)(tag * 2 + 0) << 20) + (size_t)row * 1024 + t * 4;
    const short* s1 = S + ((size_t)(tag * 2 + 1) << 20) + (size_t)row * 1024 + t * 4;

    short4 r0 = *reinterpret_cast<const short4*>(s0);
    short4 r1 = *reinterpret_cast<const short4*>(s1);
    float v0[4] = {bf2f(r0.x), bf2f(r0.y), bf2f(r0.z), bf2f(r0.w)};
    float v1[4] = {bf2f(r1.x), bf2f(r1.y), bf2f(r1.z), bf2f(r1.w)};

    float m0 = fmaxf(fmaxf(v0[0], v0[1]), fmaxf(v0[2], v0[3]));
    float m1 = fmaxf(fmaxf(v1[0], v1[1]), fmaxf(v1[2], v1[3]));
    bmax2(m0, m1, red);

    float e0[4], e1[4], sum0 = 0.f, sum1 = 0.f;
    #pragma unroll
    for (int j = 0; j < 4; ++j) {
        e0[j] = __expf(v0[j] - m0); sum0 += e0[j];
        e1[j] = __expf(v1[j] - m1); sum1 += e1[j];
    }
    bsum2(sum0, sum1, red);
    float i0 = 0.5f / sum0, i1 = 0.5f / sum1;

    short4 o;
    o.x = f2bf(e0[0] * i0 + e1[0] * i1);
    o.y = f2bf(e0[1] * i0 + e1[1] * i1);
    o.z = f2bf(e0[2] * i0 + e1[2] * i1);
    o.w = f2bf(e0[3] * i0 + e1[3] * i1);
    *reinterpret_cast<short4*>(a + ((size_t)tag << 20) + (size_t)row * 1024 + t * 4) = o;
}

// ---------------- column standardize + softmax (fast reductions) ------------
template<typename TOUT>
__global__ __launch_bounds__(256) void norm_softmax_b(const float* __restrict__ Zbase,
                                                      int zstride,
                                                      TOUT* __restrict__ Hout, int ldh,
                                                      int joffmul,
                                                      float* __restrict__ out2)
{
    __shared__ float red4[4];
    const int j = blockIdx.x, t = threadIdx.x;
    const float* Z = Zbase + (size_t)blockIdx.y * zstride;
    const int joff = blockIdx.y * joffmul;

    float x[4];
    #pragma unroll
    for (int i = 0; i < 4; ++i) x[i] = Z[(size_t)(t + i * 256) * 256 + j];

    float mean = bsum1(x[0] + x[1] + x[2] + x[3], red4) * (1.f / 1024.f);

    float ss = 0.f;
    #pragma unroll
    for (int i = 0; i < 4; ++i) { float d = x[i] - mean; ss += d * d; }
    float var = bsum1(ss, red4) * (1.f / 1023.f);
    float inv = 1.f / (sqrtf(var) + 1e-6f);

    float v[4];
    float mx = -3.4e38f;
    #pragma unroll
    for (int i = 0; i < 4; ++i) { v[i] = (x[i] - mean) * inv; mx = fmaxf(mx, v[i]); }
    mx = bmax1(mx, red4);

    float e[4], es = 0.f;
    #pragma unroll
    for (int i = 0; i < 4; ++i) { e[i] = __expf(v[i] - mx); es += e[i]; }
    es = bsum1(es, red4);
    float invs = 1.f / es;

    #pragma unroll
    for (int i = 0; i < 4; ++i) {
        float o = e[i] * invs;
        if constexpr (sizeof(TOUT) == 4)
            Hout[(size_t)(t + i * 256) * ldh + joff + j] = o;
        else
            Hout[(size_t)(t + i * 256) * ldh + joff + j] = f2bf(o);
        if (out2) out2[(size_t)(t + i * 256) * 256 + joff + j] = o;
    }
}

// ---------------- fused: jsd_part (0..1023) || pipelined G-GEMM (1024..1151) -
__global__ __launch_bounds__(256) void jsdg_k(const float* __restrict__ H,
                                              float* __restrict__ Cpart,
                                              const float* __restrict__ xt,
                                              const float* __restrict__ xn,
                                              float* __restrict__ Gpart)
{
    __shared__ __align__(16) short As[2][64 * 40];
    __shared__ __align__(16) short Bs[2][64 * 40];
    const int t = threadIdx.x;
    const int job = blockIdx.x;

    if (job < 1024) {
        float (*hj)[33] = (float(*)[33])&As[0][0];
        float (*hk)[33] = (float(*)[33])&Bs[0][0];
        const int tx = t & 15, ty = t >> 4;
        const int k0 = (job & 7) * 32, j0 = ((job >> 3) & 7) * 32;
        const int slab = job >> 6, nbase = slab * 64;
        float acc[2][2] = {};
        for (int c = 0; c < 8; ++c) {
            int n0 = nbase + c * 8;
            int nl = t >> 5, cc = t & 31;
            hj[nl][cc] = H[(size_t)(n0 + nl) * 256 + j0 + cc];
            hk[nl][cc] = H[(size_t)(n0 + nl) * 256 + k0 + cc];
            __syncthreads();
            #pragma unroll
            for (int nn = 0; nn < 8; ++nn) {
                float a0 = hj[nn][ty * 2], a1 = hj[nn][ty * 2 + 1];
                float b0 = hk[nn][tx * 2], b1 = hk[nn][tx * 2 + 1];
                acc[0][0] += a0 * __logf(0.5f * (a0 + b0));
                acc[0][1] += a0 * __logf(0.5f * (a0 + b1));
                acc[1][0] += a1 * __logf(0.5f * (a1 + b0));
                acc[1][1] += a1 * __logf(0.5f * (a1 + b1));
            }
            __syncthreads();
        }
        float* Cp = Cpart + (size_t)slab * 65536;
        #pragma unroll
        for (int i = 0; i < 2; ++i)
            #pragma unroll
            for (int jj = 0; jj < 2; ++jj)
                Cp[(size_t)(j0 + ty * 2 + i) * 256 + k0 + tx * 2 + jj] = acc[i][jj];
    } else {
        const int gg = job - 1024;
        const int z = gg >> 5, tile = gg & 31;
        const int chain = z >> 1, slab = z & 1;
        const float* A = H + (size_t)slab * 131072;
        const float* B = (chain ? xn : xt) + (size_t)slab * 262144;
        float* C = Gpart + (size_t)z * 131072;
        const int bm = (tile >> 3) * 64, bn = (tile & 7) * 64;
        const int lane = t & 63;
        const int w = t >> 6, wm = w >> 1, wn = w & 1;
        const int l15 = lane & 15, l4 = lane >> 4;

        f32x4 acc[2][2];
        #pragma unroll
        for (int i = 0; i < 2; ++i)
            #pragma unroll
            for (int j = 0; j < 2; ++j)
                #pragma unroll
                for (int r = 0; r < 4; ++r) acc[i][j][r] = 0.f;

        float4 rA[2], rB[2];
        auto loadAB = [&](int k0) {
            #pragma unroll
            for (int p = 0; p < 2; ++p) {
                int kk = (t >> 4) + p * 16;
                rA[p] = *reinterpret_cast<const float4*>(
                    A + (size_t)(k0 + kk) * 256 + bm + (t & 15) * 4);
                rB[p] = *reinterpret_cast<const float4*>(
                    B + (size_t)(k0 + kk) * 512 + bn + (t & 15) * 4);
            }
        };
        auto writeAB = [&](int buf) {
            #pragma unroll
            for (int p = 0; p < 2; ++p) {
                int kk = (t >> 4) + p * 16, m4 = (t & 15) * 4;
                As[buf][(m4 + 0) * 40 + kk] = f2bf(rA[p].x);
                As[buf][(m4 + 1) * 40 + kk] = f2bf(rA[p].y);
                As[buf][(m4 + 2) * 40 + kk] = f2bf(rA[p].z);
                As[buf][(m4 + 3) * 40 + kk] = f2bf(rA[p].w);
                Bs[buf][(m4 + 0) * 40 + kk] = f2bf(rB[p].x);
                Bs[buf][(m4 + 1) * 40 + kk] = f2bf(rB[p].y);
                Bs[buf][(m4 + 2) * 40 + kk] = f2bf(rB[p].z);
                Bs[buf][(m4 + 3) * 40 + kk] = f2bf(rB[p].w);
            }
        };

        const int NS = 16;
        loadAB(0); writeAB(0); loadAB(32);
        __syncthreads();

        for (int s = 0; s < NS; ++s) {
            const bf16x8* Ap = reinterpret_cast<const bf16x8*>(As[s & 1]);
            const bf16x8* Bp = reinterpret_cast<const bf16x8*>(Bs[s & 1]);
            bf16x8 af[2], bfr[2];
            #pragma unroll
            for (int mi = 0; mi < 2; ++mi)
                af[mi] = Ap[(wm * 32 + mi * 16 + l15) * 5 + l4];
            #pragma unroll
            for (int ni = 0; ni < 2; ++ni)
                bfr[ni] = Bp[(wn * 32 + ni * 16 + l15) * 5 + l4];
            if (s + 1 < NS) writeAB((s + 1) & 1);
            #pragma unroll
            for (int mi = 0; mi < 2; ++mi)
                #pragma unroll
                for (int ni = 0; ni < 2; ++ni)
                    acc[mi][ni] = __builtin_amdgcn_mfma_f32_16x16x32_bf16(
                        af[mi], bfr[ni], acc[mi][ni], 0, 0, 0);
            if (s + 2 < NS) loadAB((s + 2) * 32);
            __syncthreads();
        }

        #pragma unroll
        for (int mi = 0; mi < 2; ++mi)
            #pragma unroll
            for (int ni = 0; ni < 2; ++ni) {
                int col = bn + wn * 32 + ni * 16 + l15;
                #pragma unroll
                for (int r = 0; r < 4; ++r) {
                    int row = bm + wm * 32 + mi * 16 + l4 * 4 + r;
                    C[(size_t)row * 512 + col] = acc[mi][ni][r];
                }
            }
    }
}

// ---------------- per-k row/col sums over 16 slabs; ent[k] = diag(C) --------
__global__ __launch_bounds__(256) void rc_k(const float* __restrict__ Cpart,
                                            float* __restrict__ cmv,
                                            float* __restrict__ rmv,
                                            float* __restrict__ entv)
{
    __shared__ float red[2][4];
    const int k = blockIdx.x, j = threadIdx.x;
    float cm = 0.f, rm = 0.f;
    #pragma unroll
    for (int s = 0; s < 16; ++s) {
        cm += Cpart[(size_t)s * 65536 + (size_t)j * 256 + k];
        rm += Cpart[(size_t)s * 65536 + (size_t)k * 256 + j];
    }
    if (j == k) entv[k] = cm;
    bsum2(cm, rm, red);
    if (j == 0) { cmv[k] = cm; rmv[k] = rm; }
}

// ---------------- launch ----------------
extern "C" void kernel_launch(void* const* d_in, const int* in_sizes, int n_in,
                              void* d_out, int out_size, void* d_ws, size_t ws_size,
                              hipStream_t stream) {
    const float* x_time = (const float*)d_in[0];
    const float* x_news = (const float*)d_in[1];
    const float* f1b = (const float*)d_in[35];
    const float* f2b = (const float*)d_in[37];
    float* out = (float*)d_out;

    float* ws = (float*)d_ws;
    short* s_qk = (short*)ws;
    short* s_a  = (short*)ws;
    short* s_Hc = (short*)ws;
    short* s_S    = (short*)(ws + 2097152);
    float* zpart  = ws + 2097152;
    float* z2b    = ws + 4718592;
    float* Cpartf = ws + 2097152;
    float* z2f    = z2b;
    float* Cpart  = ws + 2097152;
    float* entv   = ws + 3145728;
    float* cmv    = entv + 256;
    float* rmv    = cmv + 256;
    float* Gpart  = ws + 3407872;
    short* Pbuf   = (short*)(ws + 4194304);      // 2 x 524288 halves (bf16 now)
    float* Hbuf   = ws + 6291456;
    // bf16 pool (ws is ~268 MB, plenty):
    short* xbf    = (short*)(ws + 6553600);      // 2 x 524288
    short* wqkbf  = (short*)(ws + 7077888);      // 8 x 262144
    short* h1wbf  = (short*)(ws + 8126464);      // 4 x 262144
    short* h2wbf  = (short*)(ws + 8650752);      // 4 x 65536
    short* f1wbf  = (short*)(ws + 8781824);      // 262144
    short* f2wbf  = (short*)(ws + 8912896);      // 65536
    short* thbf   = (short*)(ws + 8945664);      // 2 x 262144

    const int base[4] = {2, 10, 18, 26};
    const int qidx[4]  = {0, 1, 0, 1};           // qsrc = {xt, xn, xt, xn}
    const int kvidx[4] = {0, 1, 1, 0};           // kvsrc = {xt, xn, xn, xt}

    // ======== prep: fp32 -> bf16 casts ========
    {
        PrepArgs pa{};
        int seg = 0, cum = 0;
        auto addseg = [&](const void* s, short* d, int cnt) {
            pa.src[seg] = (const float*)s; pa.dst[seg] = d;
            pa.bstart[seg] = cum; cum += cnt / 2048; ++seg;
        };
        addseg(x_time, xbf, 524288);
        addseg(x_news, xbf + 524288, 524288);
        for (int tg = 0; tg < 4; ++tg) addseg(d_in[base[tg] + 0], wqkbf + (size_t)tg * 262144, 262144);
        for (int tg = 0; tg < 4; ++tg) addseg(d_in[base[tg] + 1], wqkbf + (size_t)(4 + tg) * 262144, 262144);
        for (int tg = 0; tg < 4; ++tg) addseg(d_in[base[tg] + 4], h1wbf + (size_t)tg * 262144, 262144);
        for (int tg = 0; tg < 4; ++tg) addseg(d_in[base[tg] + 6], h2wbf + (size_t)tg * 65536, 65536);
        addseg(d_in[34], f1wbf, 262144);
        addseg(d_in[36], f2wbf, 65536);
        addseg(d_in[38], thbf, 262144);
        addseg(d_in[39], thbf + 262144, 262144);
        pa.bstart[seg] = cum;                    // 2592 total
        prep_k<<<cum, 256, 0, stream>>>(pa);
    }

    Batch8 bp{};

    // ======== projections: z=8, all-bf16 operands ========
    for (int tg = 0; tg < 4; ++tg) {
        bp.A[tg] = xbf + (size_t)qidx[tg] * 524288;
        bp.B[tg] = wqkbf + (size_t)tg * 262144;
        bp.bias[tg] = (const float*)d_in[base[tg] + 2];
        bp.C[tg] = s_qk + (size_t)tg * 524288;
        bp.A[4 + tg] = xbf + (size_t)kvidx[tg] * 524288;
        bp.B[4 + tg] = wqkbf + (size_t)(4 + tg) * 262144;
        bp.bias[4 + tg] = (const float*)d_in[base[tg] + 3];
        bp.C[4 + tg] = s_qk + (size_t)(4 + tg) * 524288;
    }
    gemm_big_k<short, short, 1>
        <<<dim3(4, 8, 8), 256, 0, stream>>>(bp, 512, 512, 512, 512, 1.f);

    // ======== scores: z=8, scale 1/16 ========
    for (int i = 0; i < 8; ++i) {
        int tg = i >> 1, h = i & 1;
        bp.A[i] = s_qk + (size_t)tg * 524288 + h * 256;
        bp.B[i] = s_qk + (size_t)(4 + tg) * 524288 + h * 256;
        bp.bias[i] = nullptr;
        bp.C[i] = s_S + ((size_t)i << 20);
    }
    gemm_big_k<short, short, 0>
        <<<dim3(8, 8, 8), 256, 0, stream>>>(bp, 512, 512, 1024, 256, 0.0625f);

    // ======== softmax + head mean -> a ========
    softmax_mean_b<<<4096, 256, 0, stream>>>(s_S, s_a);

    // ======== incidence MLP1: split-K z=8 -> zpart fp32 (bf16 B) ========
    for (int i = 0; i < 8; ++i) {
        int tg = i >> 1, hf = i & 1;
        bp.A[i] = s_a + ((size_t)tg << 20) + hf * 512;
        bp.B[i] = h1wbf + (size_t)tg * 262144 + hf * 512;
        bp.bias[i] = nullptr;
        bp.C[i] = zpart + (size_t)i * 262144;
    }
    gemm_b_k<short, short, float, false, false, 0>
        <<<dim3(4, 16, 8), 256, 0, stream>>>(bp, 1024, 1024, 256, 512, 1.f);

    // ======== incidence MLP2 z=4 (APART=2, bf16 B) ========
    for (int tg = 0; tg < 4; ++tg) {
        bp.A[tg] = zpart + (size_t)tg * 2 * 262144;
        bp.biasA[tg] = (const float*)d_in[base[tg] + 5];
        bp.B[tg] = h2wbf + (size_t)tg * 65536;
        bp.bias[tg] = (const float*)d_in[base[tg] + 7];
        bp.C[tg] = z2b + (size_t)tg * 262144;
    }
    gemm_b_k<float, short, float, false, false, 1, false, false, 2>
        <<<dim3(4, 16, 4), 256, 0, stream>>>(bp, 256, 256, 256, 256, 1.f);

    // norm_softmax over 4 tags -> Hcat (bf16)
    norm_softmax_b<short><<<dim3(256, 4), 256, 0, stream>>>(z2b, 262144, s_Hc, 1024, 256, nullptr);

    // ======== fusion MLP1 split-K z=4 -> Cpartf (bf16 B) ========
    for (int z = 0; z < 4; ++z) {
        bp.A[z] = s_Hc + z * 256;
        bp.B[z] = f1wbf + z * 256;
        bp.bias[z] = nullptr;
        bp.C[z] = Cpartf + (size_t)z * 262144;
    }
    gemm_b_k<short, short, float, false, false, 0>
        <<<dim3(4, 16, 4), 256, 0, stream>>>(bp, 1024, 1024, 256, 256, 1.f);

    // ======== fusion MLP2 (APART=4, bf16 B) ========
    bp.A[0] = Cpartf; bp.biasA[0] = f1b; bp.B[0] = f2wbf; bp.bias[0] = f2b; bp.C[0] = z2f;
    gemm_b_k<float, short, float, false, false, 1, false, false, 4>
        <<<dim3(4, 16, 1), 256, 0, stream>>>(bp, 256, 256, 256, 256, 1.f);
    norm_softmax_b<float><<<dim3(256, 1), 256, 0, stream>>>(z2f, 0, Hbuf, 256, 0,
                                                            out + 1048576);

    // ======== JSD || G-GEMM (fused) ========
    jsdg_k<<<1152, 256, 0, stream>>>(Hbuf, Cpart, x_time, x_news, Gpart);
    rc_k<<<256, 256, 0, stream>>>(Cpart, cmv, rmv, entv);

    // ======== P = (H*w)(G0+G1) with inline jmw -> Pbuf bf16 ========
    pgemm_k<<<dim3(8, 16, 2), 256, 0, stream>>>(Hbuf, Gpart, cmv, rmv, entv, Pbuf);

    // ======== out = x + elu(P theta): bf16 A, bf16 TRB theta ========
    const float* xc[2] = {x_time, x_news};
    for (int c = 0; c < 2; ++c) {
        bp.A[c] = Pbuf + (size_t)c * 524288;
        bp.B[c] = thbf + (size_t)c * 262144;
        bp.bias[c] = nullptr;
        bp.add[c] = xc[c];
        bp.C[c] = out + (size_t)c * 524288;
    }
    gemm_b_k<short, short, float, false, true, 3>
        <<<dim3(8, 16, 2), 256, 0, stream>>>(bp, 512, 512, 512, 512, 1.f);
}